// Round 8
// baseline (989.292 us; speedup 1.0000x reference)
//
#include <hip/hip_runtime.h>

// Problem constants (fixed by the reference)
#define NN 8192
#define EE 131072
#define MUL 128
#define AA 10
#define RB 8
#define DEF 264          // RB + 2*MUL
#define INV_SQRT3 0.5773502691896258f
#define INV_SQRT128 0.08838834764831845f
#define INV_SQRT10 0.31622776601683794f
#define INV_SQRT264 0.06154574548966636f

typedef __attribute__((ext_vector_type(8))) short short8;
typedef __attribute__((ext_vector_type(4))) float floatx4;

// ---------------------------------------------------------------------------
// Workspace layout (float offsets). ~182 MB total.
// WS_TPW now holds h2 (E x 64 bf16, 16.8 MB) instead of tpw (E x 512 bf16).
// ---------------------------------------------------------------------------
#define WS_XQ     ((size_t)0)                       // N*128 uint2 {us,uvx,uvy,uvz} bf16
#define WS_USB    (WS_XQ    + (size_t)NN*256)       // N*128 bf16
#define WS_UVB    (WS_USB   + (size_t)NN*64)        // 3*N*128 bf16 channel-major
#define WS_SRC    (WS_UVB   + (size_t)NN*192)       // N*128 bf16
#define WS_TGT    (WS_SRC   + (size_t)NN*64)        // N*128 bf16
#define WS_MSGSB  (WS_TGT   + (size_t)NN*64)        // N*256 bf16 (invden applied)
#define WS_MSGVB  (WS_MSGSB + (size_t)NN*128)       // 3*N*256 bf16 channel-major
#define WS_GATE   (WS_MSGVB + (size_t)NN*384)       // N*128 f32 (unused)
#define WS_COUNTS (WS_GATE  + (size_t)NN*128)       // N ints
#define WS_OFFS   (WS_COUNTS+ (size_t)NN)           // N+4 ints
#define WS_CURSOR (WS_OFFS  + (size_t)(NN+4))       // N ints
#define WS_POS    (WS_CURSOR+ (size_t)NN)           // E ints
#define WS_META   (WS_POS   + (size_t)EE)           // E*8 f32 {snd,y1x,y1y,y1z,dn,y0,-,-}
#define WS_TPW    (WS_META  + (size_t)EE*8)         // h2: E*64 bf16 (region sized E*512)
#define WS_WB     (WS_TPW   + (size_t)EE*256)       // edge wfrags 152*512 bf16
#define WS_WP     (WS_WB    + (size_t)152*256)      // post wfrags 352*512 bf16
#define WS_WN     (WS_WP    + (size_t)352*256)      // node wfrags 144*512 bf16

__device__ __forceinline__ float silu_f(float x) {
    return x * __builtin_amdgcn_rcpf(1.f + __expf(-x));
}
__device__ __forceinline__ float sigm_f(float x) {
    return __builtin_amdgcn_rcpf(1.f + __expf(-x));
}

__device__ __forceinline__ unsigned short f2bf(float x) {
    union { float f; unsigned u; } uf; uf.f = x;
    unsigned r = uf.u + 0x7FFFu + ((uf.u >> 16) & 1u);   // RNE
    return (unsigned short)(r >> 16);
}

// ---------------------------------------------------------------------------
// CSR build: count -> scan -> scatter   (receiver-sorted edge slots)
// ---------------------------------------------------------------------------
__global__ __launch_bounds__(256) void csr_count(
    const int* __restrict__ edge_index, int* __restrict__ counts)
{
    int e = blockIdx.x * 256 + threadIdx.x;
    atomicAdd(&counts[edge_index[EE + e]], 1);
}

__global__ __launch_bounds__(1024) void csr_scan(
    const int* __restrict__ counts, int* __restrict__ offs, int* __restrict__ cursor)
{
    __shared__ int sums[1024];
    const int t = threadIdx.x;
    int local[8];
    int s = 0;
#pragma unroll
    for (int k = 0; k < 8; ++k) { local[k] = s; s += counts[t * 8 + k]; }
    sums[t] = s;
    __syncthreads();
    for (int d = 1; d < 1024; d <<= 1) {
        int v = (t >= d) ? sums[t - d] : 0;
        __syncthreads();
        sums[t] += v;
        __syncthreads();
    }
    int base = (t > 0) ? sums[t - 1] : 0;
#pragma unroll
    for (int k = 0; k < 8; ++k) {
        offs[t * 8 + k] = base + local[k];
        cursor[t * 8 + k] = base + local[k];
    }
    if (t == 1023) offs[8192] = sums[1023];
}

__global__ __launch_bounds__(256) void csr_scatter(
    const int* __restrict__ edge_index, int* __restrict__ cursor, int* __restrict__ pos)
{
    int e = blockIdx.x * 256 + threadIdx.x;
    pos[e] = atomicAdd(&cursor[edge_index[EE + e]], 1);
}

// ---------------------------------------------------------------------------
// Edge weight pre-swizzle into MFMA B-fragment order (bf16, scales folded).
// ---------------------------------------------------------------------------
__global__ __launch_bounds__(256) void swizzle_weights(
    const float* __restrict__ Wr0, const float* __restrict__ Wd0,
    const float* __restrict__ Wr1, const float* __restrict__ Wr2,
    const float* __restrict__ Wr3, unsigned short* __restrict__ WBall)
{
    int fid = blockIdx.x * 256 + threadIdx.x;
    int lane = fid & 63;
    int frag = fid >> 6;
    int k0 = (lane >> 4) * 8;
    int n0 = lane & 15;
    unsigned short o[8];

    if (frag < 72) {
        int kt = frag >> 3, nt = frag & 7;
        int n = nt * 16 + n0;
#pragma unroll
        for (int j = 0; j < 8; ++j) {
            int k = kt * 32 + k0 + j;
            float v = 0.f;
            if (k < 264) v = ((n < 64) ? Wr0[k * 64 + n] : Wd0[k * 64 + (n - 64)]) * INV_SQRT264;
            o[j] = f2bf(v);
        }
    } else if (frag < 80) {
        int fl = frag - 72;
        int kt = fl >> 2, nt = fl & 3;
        int n = nt * 16 + n0;
#pragma unroll
        for (int j = 0; j < 8; ++j)
            o[j] = f2bf(Wr1[(kt * 32 + k0 + j) * 64 + n] * 0.125f);
    } else if (frag < 88) {
        int fl = frag - 80;
        int kt = fl >> 2, nt = fl & 3;
        int n = nt * 16 + n0;
#pragma unroll
        for (int j = 0; j < 8; ++j)
            o[j] = f2bf(Wr2[(kt * 32 + k0 + j) * 64 + n] * 0.125f);
    } else {
        int fl = frag - 88;
        int kt = fl >> 5, nt = fl & 31;
        int n = nt * 16 + n0;
        int q = n >> 6;
        float sc = (q < 2) ? 0.125f : 0.125f * INV_SQRT3;
#pragma unroll
        for (int j = 0; j < 8; ++j)
            o[j] = f2bf(Wr3[(kt * 32 + k0 + j) * 512 + n] * sc);
    }
    uint4 pk;
    pk.x = (unsigned)o[0] | ((unsigned)o[1] << 16);
    pk.y = (unsigned)o[2] | ((unsigned)o[3] << 16);
    pk.z = (unsigned)o[4] | ((unsigned)o[5] << 16);
    pk.w = (unsigned)o[6] | ((unsigned)o[7] << 16);
    *(uint4*)(WBall + (size_t)fid * 8) = pk;
}

// ---------------------------------------------------------------------------
// Post weight pre-swizzle (unchanged).
// ---------------------------------------------------------------------------
__global__ __launch_bounds__(256) void swizzle_post(
    const float* __restrict__ W1s, const float* __restrict__ W1v,
    const float* __restrict__ Wrs, const float* __restrict__ Wrv,
    const float* __restrict__ W2s, const float* __restrict__ W2v,
    unsigned short* __restrict__ WPall)
{
    int fid = blockIdx.x * 256 + threadIdx.x;
    int lane = fid & 63;
    int frag = fid >> 6;
    int k0 = (lane >> 4) * 8;
    int n0 = lane & 15;
    unsigned short o[8];

    if (frag < 192) {
        int kt = frag >> 4, nt = frag & 15;
        int n = nt * 16 + n0;
#pragma unroll
        for (int j = 0; j < 8; ++j) {
            int k = kt * 32 + k0 + j;
            float v = (k < 256) ? W1s[k * 256 + n] * 0.0625f
                                : Wrs[(k - 256) * 256 + n] * INV_SQRT128;
            o[j] = f2bf(v);
        }
    } else if (frag < 288) {
        int fl = frag - 192;
        int kt = fl >> 3, nt = fl & 7;
        int n = nt * 16 + n0;
#pragma unroll
        for (int j = 0; j < 8; ++j) {
            int k = kt * 32 + k0 + j;
            float v = (k < 256) ? W1v[k * 128 + n] * 0.0625f
                                : Wrv[(k - 256) * 128 + n] * INV_SQRT128;
            o[j] = f2bf(v);
        }
    } else if (frag < 320) {
        int fl = frag - 288;
        int kt = fl >> 3, nt = fl & 7;
        int n = nt * 16 + n0;
#pragma unroll
        for (int j = 0; j < 8; ++j)
            o[j] = f2bf(W2s[(kt * 32 + k0 + j) * 128 + n] * INV_SQRT128);
    } else {
        int fl = frag - 320;
        int kt = fl >> 3, nt = fl & 7;
        int n = nt * 16 + n0;
#pragma unroll
        for (int j = 0; j < 8; ++j)
            o[j] = f2bf(W2v[(kt * 32 + k0 + j) * 128 + n] * INV_SQRT128);
    }
    uint4 pk;
    pk.x = (unsigned)o[0] | ((unsigned)o[1] << 16);
    pk.y = (unsigned)o[2] | ((unsigned)o[3] << 16);
    pk.z = (unsigned)o[4] | ((unsigned)o[5] << 16);
    pk.w = (unsigned)o[6] | ((unsigned)o[7] << 16);
    *(uint4*)(WPall + (size_t)fid * 8) = pk;
}

// ---------------------------------------------------------------------------
// Node weight pre-swizzle (A-operand layout for the transposed node GEMM).
// ---------------------------------------------------------------------------
__global__ __launch_bounds__(256) void swizzle_node(
    const float* __restrict__ Wss, const float* __restrict__ Wus,
    const float* __restrict__ Wsv, const float* __restrict__ Wuv,
    const float* __restrict__ Wsrc, const float* __restrict__ Wtgt,
    unsigned short* __restrict__ WN)
{
    int fid = blockIdx.x * 256 + threadIdx.x;   // 144*64 = 9216 = 36*256
    int lane = fid & 63;
    int frag = fid >> 6;
    int k0 = (lane >> 4) * 8;
    int m0 = lane & 15;
    unsigned short o[8];

    if (frag < 128) {
        int g = frag >> 5;
        int fl = frag & 31;
        int kt = fl >> 3, mt = fl & 7;
        const float* W = (g == 0) ? Wss : (g == 1) ? Wus : (g == 2) ? Wsv : Wuv;
        int m = mt * 16 + m0;
#pragma unroll
        for (int j = 0; j < 8; ++j)
            o[j] = f2bf(W[(kt * 32 + k0 + j) * 128 + m] * INV_SQRT128);
    } else {
        int g = (frag - 128) >> 3;
        int mt = frag & 7;
        const float* W = g ? Wtgt : Wsrc;
        int m = mt * 16 + m0;
#pragma unroll
        for (int j = 0; j < 8; ++j) {
            int k = k0 + j;
            o[j] = f2bf((k < AA) ? W[k * 128 + m] * INV_SQRT10 : 0.f);
        }
    }
    uint4 pk;
    pk.x = (unsigned)o[0] | ((unsigned)o[1] << 16);
    pk.y = (unsigned)o[2] | ((unsigned)o[3] << 16);
    pk.z = (unsigned)o[4] | ((unsigned)o[5] << 16);
    pk.w = (unsigned)o[6] | ((unsigned)o[7] << 16);
    *(uint4*)(WN + (size_t)fid * 8) = pk;
}

// ---------------------------------------------------------------------------
// Kernel A: per-node precompute on MFMA (unchanged).
// ---------------------------------------------------------------------------
#define PNB 16
__global__ __launch_bounds__(256) void node_pre_mfma(
    const float* __restrict__ node_attrs, const float* __restrict__ node_feats,
    const unsigned short* __restrict__ WN,
    float* __restrict__ sc_out, uint2* __restrict__ xq,
    unsigned short* __restrict__ us_b, unsigned short* __restrict__ uv_b,
    unsigned short* __restrict__ srcEb, unsigned short* __restrict__ tgtEb)
{
    __shared__ __align__(16) unsigned short Xs[PNB][136];
    __shared__ __align__(16) unsigned short Xv[3][PNB][136];
    __shared__ __align__(16) unsigned short Xa[PNB][40];
    const int t = threadIdx.x;
    const int l = t & 63, w = t >> 6;
    const int quad = l >> 4, lr = l & 15;
    const int n0 = blockIdx.x * PNB;

    // ---- stage node_feats (f32 -> bf16): thread (r=t>>4, m=t&15)
    {
        const int r = t >> 4, m = t & 15;
        const float* src = node_feats + (size_t)(n0 + r) * 512;
        float4 s0 = *(const float4*)(src + 8 * m);
        float4 s1 = *(const float4*)(src + 8 * m + 4);
        uint4 sp;
        sp.x = (unsigned)f2bf(s0.x) | ((unsigned)f2bf(s0.y) << 16);
        sp.y = (unsigned)f2bf(s0.z) | ((unsigned)f2bf(s0.w) << 16);
        sp.z = (unsigned)f2bf(s1.x) | ((unsigned)f2bf(s1.y) << 16);
        sp.w = (unsigned)f2bf(s1.z) | ((unsigned)f2bf(s1.w) << 16);
        *(uint4*)&Xs[r][8 * m] = sp;

        float4 q[6];
#pragma unroll
        for (int jj = 0; jj < 6; ++jj)
            q[jj] = *(const float4*)(src + 128 + 24 * m + 4 * jj);
        const float* qf = &q[0].x;
        unsigned short vb[3][8];
#pragma unroll
        for (int u = 0; u < 8; ++u) {
#pragma unroll
            for (int c = 0; c < 3; ++c)
                vb[c][u] = f2bf(qf[u * 3 + c]);
        }
#pragma unroll
        for (int c = 0; c < 3; ++c) {
            uint4 vp;
            vp.x = (unsigned)vb[c][0] | ((unsigned)vb[c][1] << 16);
            vp.y = (unsigned)vb[c][2] | ((unsigned)vb[c][3] << 16);
            vp.z = (unsigned)vb[c][4] | ((unsigned)vb[c][5] << 16);
            vp.w = (unsigned)vb[c][6] | ((unsigned)vb[c][7] << 16);
            *(uint4*)&Xv[c][r][8 * m] = vp;
        }
    }
    // ---- stage attrs (padded K=32)
    for (int idx = t; idx < PNB * 32; idx += 256) {
        int r = idx >> 5, k = idx & 31;
        float v = (k < AA) ? node_attrs[(size_t)(n0 + r) * AA + k] : 0.f;
        Xa[r][k] = f2bf(v);
    }
    __syncthreads();

    const short8* WNf = (const short8*)WN;
    const int n = n0 + lr;

#pragma unroll
    for (int mi = 0; mi < 2; ++mi) {
        const int mt = w * 2 + mi;
        const int j0 = mt * 16 + quad * 4;

        // attr GEMM (K=32): srcE / tgtE
        floatx4 cSrc = (floatx4){0.f, 0.f, 0.f, 0.f};
        floatx4 cTgt = (floatx4){0.f, 0.f, 0.f, 0.f};
        {
            short8 ba = *(const short8*)&Xa[lr][quad * 8];
            cSrc = __builtin_amdgcn_mfma_f32_16x16x32_bf16(WNf[(size_t)(128 + mt) * 64 + l], ba, cSrc, 0, 0, 0);
            cTgt = __builtin_amdgcn_mfma_f32_16x16x32_bf16(WNf[(size_t)(136 + mt) * 64 + l], ba, cTgt, 0, 0, 0);
        }
        // s GEMMs (K=128): sc_s / us
        floatx4 cS = (floatx4){0.f, 0.f, 0.f, 0.f};
        floatx4 cU = (floatx4){0.f, 0.f, 0.f, 0.f};
#pragma unroll
        for (int kt = 0; kt < 4; ++kt) {
            short8 bs = *(const short8*)&Xs[lr][kt * 32 + quad * 8];
            cS = __builtin_amdgcn_mfma_f32_16x16x32_bf16(WNf[(size_t)(kt * 8 + mt) * 64 + l], bs, cS, 0, 0, 0);
            cU = __builtin_amdgcn_mfma_f32_16x16x32_bf16(WNf[(size_t)(32 + kt * 8 + mt) * 64 + l], bs, cU, 0, 0, 0);
        }
        // v GEMMs (K=128 x 3 channels): sc_v / uv
        floatx4 cSV[3], cUV[3];
#pragma unroll
        for (int c = 0; c < 3; ++c) {
            cSV[c] = (floatx4){0.f, 0.f, 0.f, 0.f};
            cUV[c] = (floatx4){0.f, 0.f, 0.f, 0.f};
#pragma unroll
            for (int kt = 0; kt < 4; ++kt) {
                short8 bv = *(const short8*)&Xv[c][lr][kt * 32 + quad * 8];
                cSV[c] = __builtin_amdgcn_mfma_f32_16x16x32_bf16(WNf[(size_t)(64 + kt * 8 + mt) * 64 + l], bv, cSV[c], 0, 0, 0);
                cUV[c] = __builtin_amdgcn_mfma_f32_16x16x32_bf16(WNf[(size_t)(96 + kt * 8 + mt) * 64 + l], bv, cUV[c], 0, 0, 0);
            }
        }

        // ---- epilogue: packed stores (node n, outputs j0..j0+3)
        {
            float4 o;
            o.x = cS[0]; o.y = cS[1]; o.z = cS[2]; o.w = cS[3];
            *(float4*)(sc_out + (size_t)n * 512 + j0) = o;
        }
        {
            float vv[12];
#pragma unroll
            for (int reg = 0; reg < 4; ++reg)
#pragma unroll
                for (int c = 0; c < 3; ++c) vv[reg * 3 + c] = cSV[c][reg];
            float* dst = sc_out + (size_t)n * 512 + 128 + j0 * 3;
#pragma unroll
            for (int qq = 0; qq < 3; ++qq) {
                float4 o;
                o.x = vv[qq * 4]; o.y = vv[qq * 4 + 1]; o.z = vv[qq * 4 + 2]; o.w = vv[qq * 4 + 3];
                *(float4*)(dst + qq * 4) = o;
            }
        }
        unsigned short ub[4], vxb[4], vyb[4], vzb[4];
#pragma unroll
        for (int reg = 0; reg < 4; ++reg) {
            ub[reg] = f2bf(cU[reg]);
            vxb[reg] = f2bf(cUV[0][reg]);
            vyb[reg] = f2bf(cUV[1][reg]);
            vzb[reg] = f2bf(cUV[2][reg]);
        }
        {
            uint2 p;
            p.x = (unsigned)ub[0] | ((unsigned)ub[1] << 16);
            p.y = (unsigned)ub[2] | ((unsigned)ub[3] << 16);
            *(uint2*)(us_b + (size_t)n * 128 + j0) = p;
        }
        {
            uint2 p;
            p.x = (unsigned)vxb[0] | ((unsigned)vxb[1] << 16);
            p.y = (unsigned)vxb[2] | ((unsigned)vxb[3] << 16);
            *(uint2*)(uv_b + ((size_t)0 * NN + n) * 128 + j0) = p;
            p.x = (unsigned)vyb[0] | ((unsigned)vyb[1] << 16);
            p.y = (unsigned)vyb[2] | ((unsigned)vyb[3] << 16);
            *(uint2*)(uv_b + ((size_t)1 * NN + n) * 128 + j0) = p;
            p.x = (unsigned)vzb[0] | ((unsigned)vzb[1] << 16);
            p.y = (unsigned)vzb[2] | ((unsigned)vzb[3] << 16);
            *(uint2*)(uv_b + ((size_t)2 * NN + n) * 128 + j0) = p;
        }
        {
            uint4 x0, x1;
            x0.x = (unsigned)ub[0] | ((unsigned)vxb[0] << 16);
            x0.y = (unsigned)vyb[0] | ((unsigned)vzb[0] << 16);
            x0.z = (unsigned)ub[1] | ((unsigned)vxb[1] << 16);
            x0.w = (unsigned)vyb[1] | ((unsigned)vzb[1] << 16);
            x1.x = (unsigned)ub[2] | ((unsigned)vxb[2] << 16);
            x1.y = (unsigned)vyb[2] | ((unsigned)vzb[2] << 16);
            x1.z = (unsigned)ub[3] | ((unsigned)vxb[3] << 16);
            x1.w = (unsigned)vyb[3] | ((unsigned)vzb[3] << 16);
            uint4* xp = (uint4*)(xq + (size_t)n * 128 + j0);
            xp[0] = x0; xp[1] = x1;
        }
        {
            uint2 p;
            p.x = (unsigned)f2bf(cSrc[0]) | ((unsigned)f2bf(cSrc[1]) << 16);
            p.y = (unsigned)f2bf(cSrc[2]) | ((unsigned)f2bf(cSrc[3]) << 16);
            *(uint2*)(srcEb + (size_t)n * 128 + j0) = p;
            p.x = (unsigned)f2bf(cTgt[0]) | ((unsigned)f2bf(cTgt[1]) << 16);
            p.y = (unsigned)f2bf(cTgt[2]) | ((unsigned)f2bf(cTgt[3]) << 16);
            *(uint2*)(tgtEb + (size_t)n * 128 + j0) = p;
        }
    }
}

// ---------------------------------------------------------------------------
// Kernel B: per-edge MLP on MFMA — round 15: phase 3 REMOVED.
// Writes h2 (64 bf16/edge, by slot) + y0 into meta[5]; the 64->512 GEMM
// moves into gather_mfma where its output is consumed in registers.
// Cuts per-wave work: 152->88 MFMAs, 152->88 KB L2 B-traffic, and the
// 16 KB/wave tpw scatter becomes a 2 KB h2 store.
// ---------------------------------------------------------------------------
#define EBK 64
#define H1OFF 80
#define HLD 152   // LDS row stride (u16): 304B = odd multiple of 16B
__global__ __launch_bounds__(256, 4) void edge_mlp(
    const float* __restrict__ edge_attrs, const float* __restrict__ edge_feats,
    const int* __restrict__ edge_index,
    const unsigned short* __restrict__ srcEb, const unsigned short* __restrict__ tgtEb,
    const unsigned short* __restrict__ WB0, const unsigned short* __restrict__ WB1,
    const unsigned short* __restrict__ WB2,
    const float* __restrict__ Wd1, const int* __restrict__ pos,
    unsigned short* __restrict__ h2P, float* __restrict__ metaP)
{
    __shared__ __align__(16) unsigned short Hb[4][16][HLD];

    const int t = threadIdx.x;
    const int l = t & 63;
    const int w = t >> 6;
    const int quad = l >> 4;
    const int lr = l & 15;
    const int e0 = blockIdx.x * EBK + w * 16;   // this wave's 16 edges

    // Row-edge for this lane's A-fragments (A row = lane&15).
    const int eA = e0 + lr;
    const int sndA = edge_index[eA];
    const int rcvA = edge_index[EE + eA];
    const int slotA = pos[eA];
    const unsigned short* spp = srcEb + (size_t)sndA * 128;
    const unsigned short* tpp = tgtEb + (size_t)rcvA * 128;

    // meta m0 + y0: one lane per edge (quad 0 covers the wave's 16 edges)
    if (quad == 0) {
        float4 ya = *(const float4*)(edge_attrs + (size_t)eA * 4);
        float4 m;
        m.x = __int_as_float(sndA); m.y = ya.y; m.z = ya.z; m.w = ya.w;
        *(float4*)(metaP + (size_t)slotA * 8) = m;
        metaP[(size_t)slotA * 8 + 5] = ya.x;   // y0
    }

    // ---- load all 9 A-fragments for ef row eA (cols kt*32 + quad*8 .. +8)
    short8 afr[9];
    {
        const int cq = quad * 8;
        if (quad == 0) {
            float4 f0 = *(const float4*)(edge_feats + (size_t)eA * 8);
            float4 f1 = *(const float4*)(edge_feats + (size_t)eA * 8 + 4);
            union { short8 v; unsigned u[4]; } pk;
            pk.u[0] = (unsigned)f2bf(f0.x) | ((unsigned)f2bf(f0.y) << 16);
            pk.u[1] = (unsigned)f2bf(f0.z) | ((unsigned)f2bf(f0.w) << 16);
            pk.u[2] = (unsigned)f2bf(f1.x) | ((unsigned)f2bf(f1.y) << 16);
            pk.u[3] = (unsigned)f2bf(f1.z) | ((unsigned)f2bf(f1.w) << 16);
            afr[0] = pk.v;
        } else {
            afr[0] = *(const short8*)(spp + (cq - 8));
        }
#pragma unroll
        for (int kt = 1; kt < 9; ++kt) {
            const int c = kt * 32 + cq;
            if (c < 136) {
                afr[kt] = *(const short8*)(spp + (c - 8));
            } else if (c < 264) {
                afr[kt] = *(const short8*)(tpp + (c - 136));
            } else {
                short8 z = {0, 0, 0, 0, 0, 0, 0, 0};
                afr[kt] = z;
            }
        }
    }

    unsigned short (*H)[HLD] = Hb[w];

    // ---- phase 0: first layer, r-path AND d-path in ONE K=288 pass
    {
        floatx4 c0[8];
#pragma unroll
        for (int nt = 0; nt < 8; ++nt) c0[nt] = (floatx4){0.f, 0.f, 0.f, 0.f};
#pragma unroll
        for (int kt = 0; kt < 9; ++kt) {
            const short8* bp = (const short8*)WB0 + (size_t)(kt * 8) * 64 + l;
#pragma unroll
            for (int nt = 0; nt < 8; ++nt)
                c0[nt] = __builtin_amdgcn_mfma_f32_16x16x32_bf16(afr[kt], bp[nt * 64], c0[nt], 0, 0, 0);
        }

        // r-path (nt 0..3): silu -> LDS h0
#pragma unroll
        for (int nt = 0; nt < 4; ++nt)
#pragma unroll
            for (int reg = 0; reg < 4; ++reg)
                H[quad * 4 + reg][nt * 16 + lr] = f2bf(silu_f(c0[nt][reg]));

        // d-path (nt 4..7): dot(Wd1) via shfl reduce -> meta
        float wd1v[4];
#pragma unroll
        for (int q2 = 0; q2 < 4; ++q2) wd1v[q2] = Wd1[q2 * 16 + lr] * 0.125f;
        float dp[4] = {0.f, 0.f, 0.f, 0.f};
#pragma unroll
        for (int nt = 0; nt < 4; ++nt)
#pragma unroll
            for (int reg = 0; reg < 4; ++reg)
                dp[reg] += silu_f(c0[nt + 4][reg]) * wd1v[nt];
#pragma unroll
        for (int m2 = 1; m2 < 16; m2 <<= 1) {
#pragma unroll
            for (int reg = 0; reg < 4; ++reg) dp[reg] += __shfl_xor(dp[reg], m2);
        }
        if (lr == 0) {
#pragma unroll
            for (int reg = 0; reg < 4; ++reg)
                metaP[(size_t)pos[e0 + quad * 4 + reg] * 8 + 4] = tanhf(dp[reg] * dp[reg]);
        }
    }

    const unsigned short* hrow0 = &H[lr][quad * 8];
    const unsigned short* hrow1 = &H[lr][H1OFF + quad * 8];

    // ---- phase 1: h0 -> h1 (64->64), silu -> LDS h1
    {
        floatx4 c1[4];
#pragma unroll
        for (int nt = 0; nt < 4; ++nt) c1[nt] = (floatx4){0.f, 0.f, 0.f, 0.f};
#pragma unroll
        for (int kt = 0; kt < 2; ++kt) {
            short8 af = *(const short8*)(hrow0 + kt * 32);
            const short8* bp = (const short8*)WB1 + (size_t)(kt * 4) * 64 + l;
#pragma unroll
            for (int nt = 0; nt < 4; ++nt)
                c1[nt] = __builtin_amdgcn_mfma_f32_16x16x32_bf16(af, bp[nt * 64], c1[nt], 0, 0, 0);
        }
#pragma unroll
        for (int nt = 0; nt < 4; ++nt)
#pragma unroll
            for (int reg = 0; reg < 4; ++reg)
                H[quad * 4 + reg][H1OFF + nt * 16 + lr] = f2bf(silu_f(c1[nt][reg]));
    }

    // ---- phase 2: h1 -> h2 (64->64), silu -> LDS h0 (overwrite)
    {
        floatx4 c2[4];
#pragma unroll
        for (int nt = 0; nt < 4; ++nt) c2[nt] = (floatx4){0.f, 0.f, 0.f, 0.f};
#pragma unroll
        for (int kt = 0; kt < 2; ++kt) {
            short8 af = *(const short8*)(hrow1 + kt * 32);
            const short8* bp = (const short8*)WB2 + (size_t)(kt * 4) * 64 + l;
#pragma unroll
            for (int nt = 0; nt < 4; ++nt)
                c2[nt] = __builtin_amdgcn_mfma_f32_16x16x32_bf16(af, bp[nt * 64], c2[nt], 0, 0, 0);
        }
#pragma unroll
        for (int nt = 0; nt < 4; ++nt)
#pragma unroll
            for (int reg = 0; reg < 4; ++reg)
                H[quad * 4 + reg][nt * 16 + lr] = f2bf(silu_f(c2[nt][reg]));
    }

    // ---- write h2 by slot: lane (quad,lr) stores row lr, cols quad*16..+15
    {
        const unsigned short* src = &H[lr][quad * 16];
        uint4 v0 = *(const uint4*)(src);
        uint4 v1 = *(const uint4*)(src + 8);
        uint4* dst = (uint4*)(h2P + (size_t)slotA * 64 + quad * 16);
        dst[0] = v0;
        dst[1] = v1;
    }
}

// ---------------------------------------------------------------------------
// Kernel C (round 15): gather on MFMA. One wave per block, RCVB receivers
// (contiguous slot range). Per 16-slot chunk: A = h2 rows, B = WB3 frags
// (identical indexing to old phase 3); lane holds w1..w4 for edge
// chunk+quad*4+reg at u=j2*16+lr; gathers xq[snd][u]; ds_add_f32 into an
// 8 KB LDS accumulator. Block owns its receivers -> no global atomics,
// invden + bf16 write done in-block. Replaces the 134 MB tpw round-trip
// with 16.8 MB of h2.
// ---------------------------------------------------------------------------
#define RCVB 2
__global__ __launch_bounds__(64) void gather_mfma(
    const unsigned short* __restrict__ h2P, const float* __restrict__ metaP,
    const int* __restrict__ offs, const uint2* __restrict__ xq,
    const unsigned short* __restrict__ WB3,
    const float* __restrict__ alpha_p, const float* __restrict__ beta_p,
    unsigned short* __restrict__ msgs_b, unsigned short* __restrict__ msgv_b)
{
    __shared__ float acc[RCVB][1024];
    const int l = threadIdx.x;
    const int quad = l >> 4, lr = l & 15;
    const int r0 = blockIdx.x * RCVB;

    for (int k = l; k < RCVB * 1024; k += 64) ((float*)acc)[k] = 0.f;

    const int sB = offs[r0];
    const int sM = offs[r0 + 1];
    const int sE = offs[r0 + 2];
    __syncthreads();

    for (int chunk = sB; chunk < sE; chunk += 16) {
        // A-frags for C-row lr (clamped; masked rows' C output is discarded)
        int srow = chunk + lr;
        if (srow >= sE) srow = sE - 1;
        const unsigned short* hr = h2P + (size_t)srow * 64;
        short8 af0 = *(const short8*)(hr + quad * 8);
        short8 af1 = *(const short8*)(hr + 32 + quad * 8);

        // per-C-row edge data (rows chunk + quad*4 + reg)
        int sndr[4], rcb[4];
        float y0r[4], y1x[4], y1y[4], y1z[4];
        bool mk[4];
#pragma unroll
        for (int reg = 0; reg < 4; ++reg) {
            int e = chunk + quad * 4 + reg;
            mk[reg] = (e < sE);
            int em = mk[reg] ? e : (sE - 1);
            const float* mp = metaP + (size_t)em * 8;
            float4 m0 = *(const float4*)mp;
            sndr[reg] = __float_as_int(m0.x);
            y1x[reg] = m0.y; y1y[reg] = m0.z; y1z[reg] = m0.w;
            y0r[reg] = mp[5];
            rcb[reg] = (em >= sM) ? 1 : 0;
        }

#pragma unroll
        for (int j2 = 0; j2 < 8; ++j2) {
            floatx4 c3[4];
#pragma unroll
            for (int g = 0; g < 4; ++g) c3[g] = (floatx4){0.f, 0.f, 0.f, 0.f};
#pragma unroll
            for (int g = 0; g < 4; ++g) {
                const short8* b0 = (const short8*)WB3 + (size_t)(g * 8 + j2) * 64 + l;
                const short8* b1 = (const short8*)WB3 + (size_t)(32 + g * 8 + j2) * 64 + l;
                c3[g] = __builtin_amdgcn_mfma_f32_16x16x32_bf16(af0, *b0, c3[g], 0, 0, 0);
                c3[g] = __builtin_amdgcn_mfma_f32_16x16x32_bf16(af1, *b1, c3[g], 0, 0, 0);
            }
            const int u = j2 * 16 + lr;
#pragma unroll
            for (int reg = 0; reg < 4; ++reg) {
                if (!mk[reg]) continue;
                uint2 xv = xq[(size_t)sndr[reg] * 128 + u];
                const float xs  = __uint_as_float(xv.x << 16);
                const float xvx = __uint_as_float(xv.x & 0xffff0000u);
                const float xvy = __uint_as_float(xv.y << 16);
                const float xvz = __uint_as_float(xv.y & 0xffff0000u);
                const float w1 = c3[0][reg] * y0r[reg];
                const float w2 = c3[1][reg];
                const float w3 = c3[2][reg] * y0r[reg];
                const float w4 = c3[3][reg];
                float* a = acc[rcb[reg]];
                const float b2 = w2 * xs;
                atomicAdd(&a[u],        w1 * xs);
                atomicAdd(&a[128 + u],  w4 * (xvx * y1x[reg] + xvy * y1y[reg] + xvz * y1z[reg]));
                atomicAdd(&a[256 + u],  b2 * y1x[reg]);
                atomicAdd(&a[384 + u],  w3 * xvx);
                atomicAdd(&a[512 + u],  b2 * y1y[reg]);
                atomicAdd(&a[640 + u],  w3 * xvy);
                atomicAdd(&a[768 + u],  b2 * y1z[reg]);
                atomicAdd(&a[896 + u],  w3 * xvz);
            }
        }
    }
    __syncthreads();

    // ---- per-receiver: dsum -> invden -> bf16 writeout
    const float alpha = *alpha_p, beta = *beta_p;
#pragma unroll
    for (int kr = 0; kr < RCVB; ++kr) {
        const int n = r0 + kr;
        const int s0 = offs[n], s1 = offs[n + 1];
        float ds = 0.f;
        for (int s = s0 + l; s < s1; s += 64) ds += metaP[(size_t)s * 8 + 4];
#pragma unroll
        for (int m2 = 1; m2 < 64; m2 <<= 1) ds += __shfl_xor(ds, m2);
        const float invden = 1.f / (ds * beta + alpha);

        for (int idx = l; idx < 1024; idx += 64) {
            const float v = acc[kr][idx] * invden;
            const int region = idx >> 7, u = idx & 127;
            const unsigned short bv = f2bf(v);
            if (region == 0)      msgs_b[(size_t)n * 256 + u] = bv;
            else if (region == 1) msgs_b[(size_t)n * 256 + 128 + u] = bv;
            else {
                const int c  = (region - 2) >> 1;
                const int hi = (region - 2) & 1;
                msgv_b[((size_t)c * NN + n) * 256 + hi * 128 + u] = bv;
            }
        }
    }
}

// ---------------------------------------------------------------------------
// Kernel D: FUSED post epilogue (round-7 verified version, unchanged).
// ---------------------------------------------------------------------------
#define DNP 16
__global__ __launch_bounds__(256) void post_fused(
    const unsigned short* __restrict__ msgs_b, const unsigned short* __restrict__ us_b,
    const unsigned short* __restrict__ msgv_b, const unsigned short* __restrict__ uv_b,
    const unsigned short* __restrict__ WPs, const unsigned short* __restrict__ WPv,
    const unsigned short* __restrict__ W2ss, const unsigned short* __restrict__ W2vs,
    float* __restrict__ out)
{
    __shared__ __align__(16) unsigned short osb[DNP][136];
    __shared__ __align__(16) unsigned short ovb[3][DNP][136];
    __shared__ float gateL[DNP][128];

    const int t = threadIdx.x;
    const int l = t & 63, w = t >> 6;         // 4 waves
    const int quad = l >> 4, lr = l & 15;
    const int n0 = blockIdx.x * DNP;
    const int nh = w;                         // 0..3 N-quarter
    const int n = n0 + lr;                    // this lane's A-row node

    const int cLo = (nh * 6) >> 3;
    const int cHi = (nh * 6 + 5) >> 3;

    const unsigned short* sRow  = msgs_b + (size_t)n * 256;
    const unsigned short* uRow  = us_b   + (size_t)n * 128;
    const unsigned short* vRowL = msgv_b + ((size_t)cLo * NN + n) * 256;
    const unsigned short* uRowL = uv_b   + ((size_t)cLo * NN + n) * 128;
    const unsigned short* vRowH = msgv_b + ((size_t)cHi * NN + n) * 256;
    const unsigned short* uRowH = uv_b   + ((size_t)cHi * NN + n) * 128;

    // ---- first layer: K=384 (12 kt), s: 4 N-tiles, v: 6 N-tiles
    floatx4 accS[4], accV[6];
#pragma unroll
    for (int i = 0; i < 4; ++i) accS[i] = (floatx4){0.f, 0.f, 0.f, 0.f};
#pragma unroll
    for (int i = 0; i < 6; ++i) accV[i] = (floatx4){0.f, 0.f, 0.f, 0.f};

#pragma unroll
    for (int kt = 0; kt < 12; ++kt) {
        const int col = kt * 32 + quad * 8;
        short8 aS = (col < 256) ? *(const short8*)(sRow + col)
                                : *(const short8*)(uRow + col - 256);
        short8 aV0 = (col < 256) ? *(const short8*)(vRowL + col)
                                 : *(const short8*)(uRowL + col - 256);
        short8 aV1;
        if (cHi != cLo)
            aV1 = (col < 256) ? *(const short8*)(vRowH + col)
                              : *(const short8*)(uRowH + col - 256);
        else
            aV1 = aV0;

        const short8* bpS = (const short8*)WPs + (size_t)(kt * 16 + nh * 4) * 64 + l;
#pragma unroll
        for (int i = 0; i < 4; ++i)
            accS[i] = __builtin_amdgcn_mfma_f32_16x16x32_bf16(aS, bpS[i * 64], accS[i], 0, 0, 0);
#pragma unroll
        for (int i = 0; i < 6; ++i) {
            const int vt = nh * 6 + i;
            const short8* bpV = (const short8*)WPv + (size_t)(kt * 8 + (vt & 7)) * 64 + l;
            short8 a = ((vt >> 3) == cLo) ? aV0 : aV1;
            accV[i] = __builtin_amdgcn_mfma_f32_16x16x32_bf16(a, *bpV, accV[i], 0, 0, 0);
        }
    }

    // ---- s outputs: tiles 0..7 -> silu -> osb; 8..15 -> sigmoid -> gateL
#pragma unroll
    for (int i = 0; i < 4; ++i) {
        const int tile = nh * 4 + i;
#pragma unroll
        for (int reg = 0; reg < 4; ++reg) {
            const int row = quad * 4 + reg;
            const float v = accS[i][reg];
            if (tile < 8) osb[row][tile * 16 + lr] = f2bf(silu_f(v));
            else          gateL[row][(tile - 8) * 16 + lr] = sigm_f(v);
        }
    }
    __syncthreads();

    // ---- gate the v accumulators -> ovb
#pragma unroll
    for (int i = 0; i < 6; ++i) {
        const int vt = nh * 6 + i;
        const int c = vt >> 3;
        const int colv = (vt & 7) * 16 + lr;
#pragma unroll
        for (int reg = 0; reg < 4; ++reg) {
            const int row = quad * 4 + reg;
            ovb[c][row][colv] = f2bf(accV[i][reg] * gateL[row][colv]);
        }
    }
    __syncthreads();

    // ---- second layer: K=128 (4 kt); s: 2 N-tiles, v: 6 N-tiles
    floatx4 c2s[2], c2v[6];
#pragma unroll
    for (int i = 0; i < 2; ++i) c2s[i] = (floatx4){0.f, 0.f, 0.f, 0.f};
#pragma unroll
    for (int i = 0; i < 6; ++i) c2v[i] = (floatx4){0.f, 0.f, 0.f, 0.f};

    const unsigned short* arowS = &osb[lr][quad * 8];
#pragma unroll
    for (int kt = 0; kt < 4; ++kt) {
        short8 afS = *(const short8*)(arowS + kt * 32);
        const short8* bpS = (const short8*)W2ss + (size_t)(kt * 8 + nh * 2) * 64 + l;
#pragma unroll
        for (int i = 0; i < 2; ++i)
            c2s[i] = __builtin_amdgcn_mfma_f32_16x16x32_bf16(afS, bpS[i * 64], c2s[i], 0, 0, 0);
#pragma unroll
        for (int i = 0; i < 6; ++i) {
            const int vt = nh * 6 + i;
            const int c = vt >> 3;
            short8 afV = *(const short8*)(&ovb[c][lr][quad * 8] + kt * 32);
            const short8* bpV = (const short8*)W2vs + (size_t)(kt * 8 + (vt & 7)) * 64 + l;
            c2v[i] = __builtin_amdgcn_mfma_f32_16x16x32_bf16(afV, *bpV, c2v[i], 0, 0, 0);
        }
    }

    // ---- epilogue
#pragma unroll
    for (int i = 0; i < 2; ++i) {
        const int col = (nh * 2 + i) * 16 + lr;
#pragma unroll
        for (int reg = 0; reg < 4; ++reg)
            out[(size_t)(n0 + quad * 4 + reg) * 512 + col * 4] = c2s[i][reg];
    }
#pragma unroll
    for (int i = 0; i < 6; ++i) {
        const int vt = nh * 6 + i;
        const int c = vt >> 3;
        const int col = (vt & 7) * 16 + lr;
#pragma unroll
        for (int reg = 0; reg < 4; ++reg)
            out[(size_t)(n0 + quad * 4 + reg) * 512 + col * 4 + 1 + c] = c2v[i][reg];
    }
}

// ---------------------------------------------------------------------------
extern "C" void kernel_launch(void* const* d_in, const int* in_sizes, int n_in,
                              void* d_out, int out_size, void* d_ws, size_t ws_size,
                              hipStream_t stream)
{
    const float* node_attrs = (const float*)d_in[0];
    const float* node_feats = (const float*)d_in[1];
    const float* edge_attrs = (const float*)d_in[2];
    const float* edge_feats = (const float*)d_in[3];
    const int*   edge_index = (const int*)d_in[4];
    const float* W_skip_s = (const float*)d_in[5];
    const float* W_skip_v = (const float*)d_in[6];
    const float* W_up_s   = (const float*)d_in[7];
    const float* W_up_v   = (const float*)d_in[8];
    const float* W_src    = (const float*)d_in[9];
    const float* W_tgt    = (const float*)d_in[10];
    const float* W_r0     = (const float*)d_in[11];
    const float* W_r1     = (const float*)d_in[12];
    const float* W_r2     = (const float*)d_in[13];
    const float* W_r3     = (const float*)d_in[14];
    const float* W_d0     = (const float*)d_in[15];
    const float* W_d1     = (const float*)d_in[16];
    const float* W1_s     = (const float*)d_in[17];
    const float* W1_v     = (const float*)d_in[18];
    const float* Wres_s   = (const float*)d_in[19];
    const float* Wres_v   = (const float*)d_in[20];
    const float* W2_s     = (const float*)d_in[21];
    const float* W2_v     = (const float*)d_in[22];
    const float* alpha_p  = (const float*)d_in[23];
    const float* beta_p   = (const float*)d_in[24];

    float* out = (float*)d_out;
    float* sc_out = out + (size_t)NN * 512;
    float* ws = (float*)d_ws;

    uint2* xq = (uint2*)(ws + WS_XQ);
    unsigned short* us_b  = (unsigned short*)(ws + WS_USB);
    unsigned short* uv_b  = (unsigned short*)(ws + WS_UVB);
    unsigned short* srcEb = (unsigned short*)(ws + WS_SRC);
    unsigned short* tgtEb = (unsigned short*)(ws + WS_TGT);
    unsigned short* msgs_b = (unsigned short*)(ws + WS_MSGSB);
    unsigned short* msgv_b = (unsigned short*)(ws + WS_MSGVB);
    int*   counts = (int*)(ws + WS_COUNTS);
    int*   offs   = (int*)(ws + WS_OFFS);
    int*   cursor = (int*)(ws + WS_CURSOR);
    int*   pos    = (int*)(ws + WS_POS);
    float* metaP  = ws + WS_META;
    unsigned short* h2P = (unsigned short*)(ws + WS_TPW);
    unsigned short* WBall = (unsigned short*)(ws + WS_WB);
    unsigned short* WB0 = WBall;
    unsigned short* WB1 = WB0 + (size_t)72 * 512;
    unsigned short* WB2 = WB1 + (size_t)8 * 512;
    unsigned short* WB3 = WB2 + (size_t)8 * 512;
    unsigned short* WPall = (unsigned short*)(ws + WS_WP);
    unsigned short* WPs  = WPall;
    unsigned short* WPv  = WPs + (size_t)192 * 512;
    unsigned short* W2ss = WPv + (size_t)96 * 512;
    unsigned short* W2vs = W2ss + (size_t)32 * 512;
    unsigned short* WN   = (unsigned short*)(ws + WS_WN);

    hipMemsetAsync(counts, 0, (size_t)NN * sizeof(int), stream);

    csr_count<<<EE / 256, 256, 0, stream>>>(edge_index, counts);
    csr_scan<<<1, 1024, 0, stream>>>(counts, offs, cursor);
    csr_scatter<<<EE / 256, 256, 0, stream>>>(edge_index, cursor, pos);

    swizzle_weights<<<38, 256, 0, stream>>>(W_r0, W_d0, W_r1, W_r2, W_r3, WBall);
    swizzle_post<<<88, 256, 0, stream>>>(W1_s, W1_v, Wres_s, Wres_v, W2_s, W2_v, WPall);
    swizzle_node<<<36, 256, 0, stream>>>(W_skip_s, W_up_s, W_skip_v, W_up_v,
                                         W_src, W_tgt, WN);

    node_pre_mfma<<<NN / PNB, 256, 0, stream>>>(
        node_attrs, node_feats, WN, sc_out, xq, us_b, uv_b, srcEb, tgtEb);

    edge_mlp<<<EE / EBK, 256, 0, stream>>>(
        edge_attrs, edge_feats, edge_index, srcEb, tgtEb,
        WB0, WB1, WB2, W_d1, pos, h2P, metaP);

    gather_mfma<<<NN / RCVB, 64, 0, stream>>>(
        h2P, metaP, offs, xq, WB3, alpha_p, beta_p, msgs_b, msgv_b);

    post_fused<<<NN / DNP, 256, 0, stream>>>(
        msgs_b, us_b, msgv_b, uv_b, WPs, WPv, W2ss, W2vs, out);
}

// Round 9
// 309.611 us; speedup vs baseline: 3.1953x; 3.1953x over previous
//
#include <hip/hip_runtime.h>

// Problem constants (fixed by the reference)
#define NN 8192
#define EE 131072
#define MUL 128
#define AA 10
#define RB 8
#define DEF 264          // RB + 2*MUL
#define INV_SQRT3 0.5773502691896258f
#define INV_SQRT128 0.08838834764831845f
#define INV_SQRT10 0.31622776601683794f
#define INV_SQRT264 0.06154574548966636f

typedef __attribute__((ext_vector_type(8))) short short8;
typedef __attribute__((ext_vector_type(4))) float floatx4;

// ---------------------------------------------------------------------------
// Workspace layout (float offsets). ~182 MB total.
// ---------------------------------------------------------------------------
#define WS_XQ     ((size_t)0)                       // N*128 uint2 {us,uvx,uvy,uvz} bf16
#define WS_USB    (WS_XQ    + (size_t)NN*256)       // N*128 bf16
#define WS_UVB    (WS_USB   + (size_t)NN*64)        // 3*N*128 bf16 channel-major
#define WS_SRC    (WS_UVB   + (size_t)NN*192)       // N*128 bf16
#define WS_TGT    (WS_SRC   + (size_t)NN*64)        // N*128 bf16
#define WS_MSGSB  (WS_TGT   + (size_t)NN*64)        // N*256 bf16 (invden applied)
#define WS_MSGVB  (WS_MSGSB + (size_t)NN*128)       // 3*N*256 bf16 channel-major
#define WS_GATE   (WS_MSGVB + (size_t)NN*384)       // N*128 f32 (unused since post fusion)
#define WS_COUNTS (WS_GATE  + (size_t)NN*128)       // N ints
#define WS_OFFS   (WS_COUNTS+ (size_t)NN)           // N+4 ints
#define WS_CURSOR (WS_OFFS  + (size_t)(NN+4))       // N ints
#define WS_POS    (WS_CURSOR+ (size_t)NN)           // E ints
#define WS_META   (WS_POS   + (size_t)EE)           // E*8 f32
#define WS_TPW    (WS_META  + (size_t)EE*8)         // E*512 bf16, [slot][u][4] interleaved
#define WS_WB     (WS_TPW   + (size_t)EE*256)       // edge wfrags 152*512 bf16
#define WS_WP     (WS_WB    + (size_t)152*256)      // post wfrags 352*512 bf16
#define WS_WN     (WS_WP    + (size_t)352*256)      // node wfrags 144*512 bf16

__device__ __forceinline__ float silu_f(float x) {
    return x * __builtin_amdgcn_rcpf(1.f + __expf(-x));
}
__device__ __forceinline__ float sigm_f(float x) {
    return __builtin_amdgcn_rcpf(1.f + __expf(-x));
}

__device__ __forceinline__ unsigned short f2bf(float x) {
    union { float f; unsigned u; } uf; uf.f = x;
    unsigned r = uf.u + 0x7FFFu + ((uf.u >> 16) & 1u);   // RNE
    return (unsigned short)(r >> 16);
}

// ---------------------------------------------------------------------------
// CSR build: count -> scan -> scatter   (receiver-sorted edge slots)
// ---------------------------------------------------------------------------
__global__ __launch_bounds__(256) void csr_count(
    const int* __restrict__ edge_index, int* __restrict__ counts)
{
    int e = blockIdx.x * 256 + threadIdx.x;
    atomicAdd(&counts[edge_index[EE + e]], 1);
}

__global__ __launch_bounds__(1024) void csr_scan(
    const int* __restrict__ counts, int* __restrict__ offs, int* __restrict__ cursor)
{
    __shared__ int sums[1024];
    const int t = threadIdx.x;
    int local[8];
    int s = 0;
#pragma unroll
    for (int k = 0; k < 8; ++k) { local[k] = s; s += counts[t * 8 + k]; }
    sums[t] = s;
    __syncthreads();
    for (int d = 1; d < 1024; d <<= 1) {
        int v = (t >= d) ? sums[t - d] : 0;
        __syncthreads();
        sums[t] += v;
        __syncthreads();
    }
    int base = (t > 0) ? sums[t - 1] : 0;
#pragma unroll
    for (int k = 0; k < 8; ++k) {
        offs[t * 8 + k] = base + local[k];
        cursor[t * 8 + k] = base + local[k];
    }
    if (t == 1023) offs[8192] = sums[1023];
}

__global__ __launch_bounds__(256) void csr_scatter(
    const int* __restrict__ edge_index, int* __restrict__ cursor, int* __restrict__ pos)
{
    int e = blockIdx.x * 256 + threadIdx.x;
    pos[e] = atomicAdd(&cursor[edge_index[EE + e]], 1);
}

// ---------------------------------------------------------------------------
// Edge weight pre-swizzle into MFMA B-fragment order (bf16, scales folded).
// ---------------------------------------------------------------------------
__global__ __launch_bounds__(256) void swizzle_weights(
    const float* __restrict__ Wr0, const float* __restrict__ Wd0,
    const float* __restrict__ Wr1, const float* __restrict__ Wr2,
    const float* __restrict__ Wr3, unsigned short* __restrict__ WBall)
{
    int fid = blockIdx.x * 256 + threadIdx.x;
    int lane = fid & 63;
    int frag = fid >> 6;
    int k0 = (lane >> 4) * 8;
    int n0 = lane & 15;
    unsigned short o[8];

    if (frag < 72) {
        int kt = frag >> 3, nt = frag & 7;
        int n = nt * 16 + n0;
#pragma unroll
        for (int j = 0; j < 8; ++j) {
            int k = kt * 32 + k0 + j;
            float v = 0.f;
            if (k < 264) v = ((n < 64) ? Wr0[k * 64 + n] : Wd0[k * 64 + (n - 64)]) * INV_SQRT264;
            o[j] = f2bf(v);
        }
    } else if (frag < 80) {
        int fl = frag - 72;
        int kt = fl >> 2, nt = fl & 3;
        int n = nt * 16 + n0;
#pragma unroll
        for (int j = 0; j < 8; ++j)
            o[j] = f2bf(Wr1[(kt * 32 + k0 + j) * 64 + n] * 0.125f);
    } else if (frag < 88) {
        int fl = frag - 80;
        int kt = fl >> 2, nt = fl & 3;
        int n = nt * 16 + n0;
#pragma unroll
        for (int j = 0; j < 8; ++j)
            o[j] = f2bf(Wr2[(kt * 32 + k0 + j) * 64 + n] * 0.125f);
    } else {
        int fl = frag - 88;
        int kt = fl >> 5, nt = fl & 31;
        int n = nt * 16 + n0;
        int q = n >> 6;
        float sc = (q < 2) ? 0.125f : 0.125f * INV_SQRT3;
#pragma unroll
        for (int j = 0; j < 8; ++j)
            o[j] = f2bf(Wr3[(kt * 32 + k0 + j) * 512 + n] * sc);
    }
    uint4 pk;
    pk.x = (unsigned)o[0] | ((unsigned)o[1] << 16);
    pk.y = (unsigned)o[2] | ((unsigned)o[3] << 16);
    pk.z = (unsigned)o[4] | ((unsigned)o[5] << 16);
    pk.w = (unsigned)o[6] | ((unsigned)o[7] << 16);
    *(uint4*)(WBall + (size_t)fid * 8) = pk;
}

// ---------------------------------------------------------------------------
// Post weight pre-swizzle (unchanged).
// ---------------------------------------------------------------------------
__global__ __launch_bounds__(256) void swizzle_post(
    const float* __restrict__ W1s, const float* __restrict__ W1v,
    const float* __restrict__ Wrs, const float* __restrict__ Wrv,
    const float* __restrict__ W2s, const float* __restrict__ W2v,
    unsigned short* __restrict__ WPall)
{
    int fid = blockIdx.x * 256 + threadIdx.x;
    int lane = fid & 63;
    int frag = fid >> 6;
    int k0 = (lane >> 4) * 8;
    int n0 = lane & 15;
    unsigned short o[8];

    if (frag < 192) {
        int kt = frag >> 4, nt = frag & 15;
        int n = nt * 16 + n0;
#pragma unroll
        for (int j = 0; j < 8; ++j) {
            int k = kt * 32 + k0 + j;
            float v = (k < 256) ? W1s[k * 256 + n] * 0.0625f
                                : Wrs[(k - 256) * 256 + n] * INV_SQRT128;
            o[j] = f2bf(v);
        }
    } else if (frag < 288) {
        int fl = frag - 192;
        int kt = fl >> 3, nt = fl & 7;
        int n = nt * 16 + n0;
#pragma unroll
        for (int j = 0; j < 8; ++j) {
            int k = kt * 32 + k0 + j;
            float v = (k < 256) ? W1v[k * 128 + n] * 0.0625f
                                : Wrv[(k - 256) * 128 + n] * INV_SQRT128;
            o[j] = f2bf(v);
        }
    } else if (frag < 320) {
        int fl = frag - 288;
        int kt = fl >> 3, nt = fl & 7;
        int n = nt * 16 + n0;
#pragma unroll
        for (int j = 0; j < 8; ++j)
            o[j] = f2bf(W2s[(kt * 32 + k0 + j) * 128 + n] * INV_SQRT128);
    } else {
        int fl = frag - 320;
        int kt = fl >> 3, nt = fl & 7;
        int n = nt * 16 + n0;
#pragma unroll
        for (int j = 0; j < 8; ++j)
            o[j] = f2bf(W2v[(kt * 32 + k0 + j) * 128 + n] * INV_SQRT128);
    }
    uint4 pk;
    pk.x = (unsigned)o[0] | ((unsigned)o[1] << 16);
    pk.y = (unsigned)o[2] | ((unsigned)o[3] << 16);
    pk.z = (unsigned)o[4] | ((unsigned)o[5] << 16);
    pk.w = (unsigned)o[6] | ((unsigned)o[7] << 16);
    *(uint4*)(WPall + (size_t)fid * 8) = pk;
}

// ---------------------------------------------------------------------------
// Node weight pre-swizzle (A-operand layout for the transposed node GEMM).
// ---------------------------------------------------------------------------
__global__ __launch_bounds__(256) void swizzle_node(
    const float* __restrict__ Wss, const float* __restrict__ Wus,
    const float* __restrict__ Wsv, const float* __restrict__ Wuv,
    const float* __restrict__ Wsrc, const float* __restrict__ Wtgt,
    unsigned short* __restrict__ WN)
{
    int fid = blockIdx.x * 256 + threadIdx.x;   // 144*64 = 9216 = 36*256
    int lane = fid & 63;
    int frag = fid >> 6;
    int k0 = (lane >> 4) * 8;
    int m0 = lane & 15;
    unsigned short o[8];

    if (frag < 128) {
        int g = frag >> 5;
        int fl = frag & 31;
        int kt = fl >> 3, mt = fl & 7;
        const float* W = (g == 0) ? Wss : (g == 1) ? Wus : (g == 2) ? Wsv : Wuv;
        int m = mt * 16 + m0;
#pragma unroll
        for (int j = 0; j < 8; ++j)
            o[j] = f2bf(W[(kt * 32 + k0 + j) * 128 + m] * INV_SQRT128);
    } else {
        int g = (frag - 128) >> 3;
        int mt = frag & 7;
        const float* W = g ? Wtgt : Wsrc;
        int m = mt * 16 + m0;
#pragma unroll
        for (int j = 0; j < 8; ++j) {
            int k = k0 + j;
            o[j] = f2bf((k < AA) ? W[k * 128 + m] * INV_SQRT10 : 0.f);
        }
    }
    uint4 pk;
    pk.x = (unsigned)o[0] | ((unsigned)o[1] << 16);
    pk.y = (unsigned)o[2] | ((unsigned)o[3] << 16);
    pk.z = (unsigned)o[4] | ((unsigned)o[5] << 16);
    pk.w = (unsigned)o[6] | ((unsigned)o[7] << 16);
    *(uint4*)(WN + (size_t)fid * 8) = pk;
}

// ---------------------------------------------------------------------------
// Kernel A: per-node precompute on MFMA (unchanged).
// ---------------------------------------------------------------------------
#define PNB 16
__global__ __launch_bounds__(256) void node_pre_mfma(
    const float* __restrict__ node_attrs, const float* __restrict__ node_feats,
    const unsigned short* __restrict__ WN,
    float* __restrict__ sc_out, uint2* __restrict__ xq,
    unsigned short* __restrict__ us_b, unsigned short* __restrict__ uv_b,
    unsigned short* __restrict__ srcEb, unsigned short* __restrict__ tgtEb)
{
    __shared__ __align__(16) unsigned short Xs[PNB][136];
    __shared__ __align__(16) unsigned short Xv[3][PNB][136];
    __shared__ __align__(16) unsigned short Xa[PNB][40];
    const int t = threadIdx.x;
    const int l = t & 63, w = t >> 6;
    const int quad = l >> 4, lr = l & 15;
    const int n0 = blockIdx.x * PNB;

    // ---- stage node_feats (f32 -> bf16): thread (r=t>>4, m=t&15)
    {
        const int r = t >> 4, m = t & 15;
        const float* src = node_feats + (size_t)(n0 + r) * 512;
        float4 s0 = *(const float4*)(src + 8 * m);
        float4 s1 = *(const float4*)(src + 8 * m + 4);
        uint4 sp;
        sp.x = (unsigned)f2bf(s0.x) | ((unsigned)f2bf(s0.y) << 16);
        sp.y = (unsigned)f2bf(s0.z) | ((unsigned)f2bf(s0.w) << 16);
        sp.z = (unsigned)f2bf(s1.x) | ((unsigned)f2bf(s1.y) << 16);
        sp.w = (unsigned)f2bf(s1.z) | ((unsigned)f2bf(s1.w) << 16);
        *(uint4*)&Xs[r][8 * m] = sp;

        float4 q[6];
#pragma unroll
        for (int jj = 0; jj < 6; ++jj)
            q[jj] = *(const float4*)(src + 128 + 24 * m + 4 * jj);
        const float* qf = &q[0].x;
        unsigned short vb[3][8];
#pragma unroll
        for (int u = 0; u < 8; ++u) {
#pragma unroll
            for (int c = 0; c < 3; ++c)
                vb[c][u] = f2bf(qf[u * 3 + c]);
        }
#pragma unroll
        for (int c = 0; c < 3; ++c) {
            uint4 vp;
            vp.x = (unsigned)vb[c][0] | ((unsigned)vb[c][1] << 16);
            vp.y = (unsigned)vb[c][2] | ((unsigned)vb[c][3] << 16);
            vp.z = (unsigned)vb[c][4] | ((unsigned)vb[c][5] << 16);
            vp.w = (unsigned)vb[c][6] | ((unsigned)vb[c][7] << 16);
            *(uint4*)&Xv[c][r][8 * m] = vp;
        }
    }
    // ---- stage attrs (padded K=32)
    for (int idx = t; idx < PNB * 32; idx += 256) {
        int r = idx >> 5, k = idx & 31;
        float v = (k < AA) ? node_attrs[(size_t)(n0 + r) * AA + k] : 0.f;
        Xa[r][k] = f2bf(v);
    }
    __syncthreads();

    const short8* WNf = (const short8*)WN;
    const int n = n0 + lr;

#pragma unroll
    for (int mi = 0; mi < 2; ++mi) {
        const int mt = w * 2 + mi;
        const int j0 = mt * 16 + quad * 4;

        // attr GEMM (K=32): srcE / tgtE
        floatx4 cSrc = (floatx4){0.f, 0.f, 0.f, 0.f};
        floatx4 cTgt = (floatx4){0.f, 0.f, 0.f, 0.f};
        {
            short8 ba = *(const short8*)&Xa[lr][quad * 8];
            cSrc = __builtin_amdgcn_mfma_f32_16x16x32_bf16(WNf[(size_t)(128 + mt) * 64 + l], ba, cSrc, 0, 0, 0);
            cTgt = __builtin_amdgcn_mfma_f32_16x16x32_bf16(WNf[(size_t)(136 + mt) * 64 + l], ba, cTgt, 0, 0, 0);
        }
        // s GEMMs (K=128): sc_s / us
        floatx4 cS = (floatx4){0.f, 0.f, 0.f, 0.f};
        floatx4 cU = (floatx4){0.f, 0.f, 0.f, 0.f};
#pragma unroll
        for (int kt = 0; kt < 4; ++kt) {
            short8 bs = *(const short8*)&Xs[lr][kt * 32 + quad * 8];
            cS = __builtin_amdgcn_mfma_f32_16x16x32_bf16(WNf[(size_t)(kt * 8 + mt) * 64 + l], bs, cS, 0, 0, 0);
            cU = __builtin_amdgcn_mfma_f32_16x16x32_bf16(WNf[(size_t)(32 + kt * 8 + mt) * 64 + l], bs, cU, 0, 0, 0);
        }
        // v GEMMs (K=128 x 3 channels): sc_v / uv
        floatx4 cSV[3], cUV[3];
#pragma unroll
        for (int c = 0; c < 3; ++c) {
            cSV[c] = (floatx4){0.f, 0.f, 0.f, 0.f};
            cUV[c] = (floatx4){0.f, 0.f, 0.f, 0.f};
#pragma unroll
            for (int kt = 0; kt < 4; ++kt) {
                short8 bv = *(const short8*)&Xv[c][lr][kt * 32 + quad * 8];
                cSV[c] = __builtin_amdgcn_mfma_f32_16x16x32_bf16(WNf[(size_t)(64 + kt * 8 + mt) * 64 + l], bv, cSV[c], 0, 0, 0);
                cUV[c] = __builtin_amdgcn_mfma_f32_16x16x32_bf16(WNf[(size_t)(96 + kt * 8 + mt) * 64 + l], bv, cUV[c], 0, 0, 0);
            }
        }

        // ---- epilogue: packed stores (node n, outputs j0..j0+3)
        {
            float4 o;
            o.x = cS[0]; o.y = cS[1]; o.z = cS[2]; o.w = cS[3];
            *(float4*)(sc_out + (size_t)n * 512 + j0) = o;
        }
        {
            float vv[12];
#pragma unroll
            for (int reg = 0; reg < 4; ++reg)
#pragma unroll
                for (int c = 0; c < 3; ++c) vv[reg * 3 + c] = cSV[c][reg];
            float* dst = sc_out + (size_t)n * 512 + 128 + j0 * 3;
#pragma unroll
            for (int qq = 0; qq < 3; ++qq) {
                float4 o;
                o.x = vv[qq * 4]; o.y = vv[qq * 4 + 1]; o.z = vv[qq * 4 + 2]; o.w = vv[qq * 4 + 3];
                *(float4*)(dst + qq * 4) = o;
            }
        }
        unsigned short ub[4], vxb[4], vyb[4], vzb[4];
#pragma unroll
        for (int reg = 0; reg < 4; ++reg) {
            ub[reg] = f2bf(cU[reg]);
            vxb[reg] = f2bf(cUV[0][reg]);
            vyb[reg] = f2bf(cUV[1][reg]);
            vzb[reg] = f2bf(cUV[2][reg]);
        }
        {
            uint2 p;
            p.x = (unsigned)ub[0] | ((unsigned)ub[1] << 16);
            p.y = (unsigned)ub[2] | ((unsigned)ub[3] << 16);
            *(uint2*)(us_b + (size_t)n * 128 + j0) = p;
        }
        {
            uint2 p;
            p.x = (unsigned)vxb[0] | ((unsigned)vxb[1] << 16);
            p.y = (unsigned)vxb[2] | ((unsigned)vxb[3] << 16);
            *(uint2*)(uv_b + ((size_t)0 * NN + n) * 128 + j0) = p;
            p.x = (unsigned)vyb[0] | ((unsigned)vyb[1] << 16);
            p.y = (unsigned)vyb[2] | ((unsigned)vyb[3] << 16);
            *(uint2*)(uv_b + ((size_t)1 * NN + n) * 128 + j0) = p;
            p.x = (unsigned)vzb[0] | ((unsigned)vzb[1] << 16);
            p.y = (unsigned)vzb[2] | ((unsigned)vzb[3] << 16);
            *(uint2*)(uv_b + ((size_t)2 * NN + n) * 128 + j0) = p;
        }
        {
            uint4 x0, x1;
            x0.x = (unsigned)ub[0] | ((unsigned)vxb[0] << 16);
            x0.y = (unsigned)vyb[0] | ((unsigned)vzb[0] << 16);
            x0.z = (unsigned)ub[1] | ((unsigned)vxb[1] << 16);
            x0.w = (unsigned)vyb[1] | ((unsigned)vzb[1] << 16);
            x1.x = (unsigned)ub[2] | ((unsigned)vxb[2] << 16);
            x1.y = (unsigned)vyb[2] | ((unsigned)vzb[2] << 16);
            x1.z = (unsigned)ub[3] | ((unsigned)vxb[3] << 16);
            x1.w = (unsigned)vyb[3] | ((unsigned)vzb[3] << 16);
            uint4* xp = (uint4*)(xq + (size_t)n * 128 + j0);
            xp[0] = x0; xp[1] = x1;
        }
        {
            uint2 p;
            p.x = (unsigned)f2bf(cSrc[0]) | ((unsigned)f2bf(cSrc[1]) << 16);
            p.y = (unsigned)f2bf(cSrc[2]) | ((unsigned)f2bf(cSrc[3]) << 16);
            *(uint2*)(srcEb + (size_t)n * 128 + j0) = p;
            p.x = (unsigned)f2bf(cTgt[0]) | ((unsigned)f2bf(cTgt[1]) << 16);
            p.y = (unsigned)f2bf(cTgt[2]) | ((unsigned)f2bf(cTgt[3]) << 16);
            *(uint2*)(tgtEb + (size_t)n * 128 + j0) = p;
        }
    }
}

// ---------------------------------------------------------------------------
// Kernel B: per-edge MLP on MFMA (round-7 structure; round 16: launch bound
// bumped (256,4)->(256,5). Live set ~84 unified VGPR fits the 102 budget;
// +1 wave/SIMD of latency hiding for the L2 fragment gathers. If FETCH/WRITE
// jump >30% it spilled -> revert to 4.
// ---------------------------------------------------------------------------
#define EBK 64
#define H1OFF 80
#define HLD 152   // LDS row stride (u16): 304B = odd multiple of 16B
__global__ __launch_bounds__(256, 5) void edge_mlp(
    const float* __restrict__ edge_attrs, const float* __restrict__ edge_feats,
    const int* __restrict__ edge_index,
    const unsigned short* __restrict__ srcEb, const unsigned short* __restrict__ tgtEb,
    const unsigned short* __restrict__ WB0, const unsigned short* __restrict__ WB1,
    const unsigned short* __restrict__ WB2, const unsigned short* __restrict__ WB3,
    const float* __restrict__ Wd1, const int* __restrict__ pos,
    unsigned short* __restrict__ tpwP, float* __restrict__ metaP)
{
    __shared__ __align__(16) unsigned short Hb[4][16][HLD];

    const int t = threadIdx.x;
    const int l = t & 63;
    const int w = t >> 6;
    const int quad = l >> 4;
    const int lr = l & 15;
    const int e0 = blockIdx.x * EBK + w * 16;   // this wave's 16 edges

    // Row-edge for this lane's A-fragments (A row = lane&15).
    const int eA = e0 + lr;
    const int sndA = edge_index[eA];
    const int rcvA = edge_index[EE + eA];
    const unsigned short* spp = srcEb + (size_t)sndA * 128;
    const unsigned short* tpp = tgtEb + (size_t)rcvA * 128;

    // meta m0: one lane per edge (quad 0 covers the wave's 16 edges)
    if (quad == 0) {
        float4 ya = *(const float4*)(edge_attrs + (size_t)eA * 4);
        float4 m;
        m.x = __int_as_float(sndA); m.y = ya.y; m.z = ya.z; m.w = ya.w;
        *(float4*)(metaP + (size_t)pos[eA] * 8) = m;
    }

    // ---- load all 9 A-fragments for ef row eA (cols kt*32 + quad*8 .. +8)
    short8 afr[9];
    {
        const int cq = quad * 8;
        if (quad == 0) {
            float4 f0 = *(const float4*)(edge_feats + (size_t)eA * 8);
            float4 f1 = *(const float4*)(edge_feats + (size_t)eA * 8 + 4);
            union { short8 v; unsigned u[4]; } pk;
            pk.u[0] = (unsigned)f2bf(f0.x) | ((unsigned)f2bf(f0.y) << 16);
            pk.u[1] = (unsigned)f2bf(f0.z) | ((unsigned)f2bf(f0.w) << 16);
            pk.u[2] = (unsigned)f2bf(f1.x) | ((unsigned)f2bf(f1.y) << 16);
            pk.u[3] = (unsigned)f2bf(f1.z) | ((unsigned)f2bf(f1.w) << 16);
            afr[0] = pk.v;
        } else {
            afr[0] = *(const short8*)(spp + (cq - 8));
        }
#pragma unroll
        for (int kt = 1; kt < 9; ++kt) {
            const int c = kt * 32 + cq;
            if (c < 136) {
                afr[kt] = *(const short8*)(spp + (c - 8));
            } else if (c < 264) {
                afr[kt] = *(const short8*)(tpp + (c - 136));
            } else {
                short8 z = {0, 0, 0, 0, 0, 0, 0, 0};
                afr[kt] = z;
            }
        }
    }

    unsigned short (*H)[HLD] = Hb[w];

    // ---- phase 0: first layer, r-path AND d-path in ONE K=288 pass
    {
        floatx4 c0[8];
#pragma unroll
        for (int nt = 0; nt < 8; ++nt) c0[nt] = (floatx4){0.f, 0.f, 0.f, 0.f};
#pragma unroll
        for (int kt = 0; kt < 9; ++kt) {
            const short8* bp = (const short8*)WB0 + (size_t)(kt * 8) * 64 + l;
#pragma unroll
            for (int nt = 0; nt < 8; ++nt)
                c0[nt] = __builtin_amdgcn_mfma_f32_16x16x32_bf16(afr[kt], bp[nt * 64], c0[nt], 0, 0, 0);
        }

        // r-path (nt 0..3): silu -> LDS h0
#pragma unroll
        for (int nt = 0; nt < 4; ++nt)
#pragma unroll
            for (int reg = 0; reg < 4; ++reg)
                H[quad * 4 + reg][nt * 16 + lr] = f2bf(silu_f(c0[nt][reg]));

        // d-path (nt 4..7): dot(Wd1) via shfl reduce -> meta
        float wd1v[4];
#pragma unroll
        for (int q2 = 0; q2 < 4; ++q2) wd1v[q2] = Wd1[q2 * 16 + lr] * 0.125f;
        float dp[4] = {0.f, 0.f, 0.f, 0.f};
#pragma unroll
        for (int nt = 0; nt < 4; ++nt)
#pragma unroll
            for (int reg = 0; reg < 4; ++reg)
                dp[reg] += silu_f(c0[nt + 4][reg]) * wd1v[nt];
#pragma unroll
        for (int m2 = 1; m2 < 16; m2 <<= 1) {
#pragma unroll
            for (int reg = 0; reg < 4; ++reg) dp[reg] += __shfl_xor(dp[reg], m2);
        }
        if (lr == 0) {
#pragma unroll
            for (int reg = 0; reg < 4; ++reg)
                metaP[(size_t)pos[e0 + quad * 4 + reg] * 8 + 4] = tanhf(dp[reg] * dp[reg]);
        }
    }

    const unsigned short* hrow0 = &H[lr][quad * 8];
    const unsigned short* hrow1 = &H[lr][H1OFF + quad * 8];

    // ---- phase 1: h0 -> h1 (64->64), silu -> LDS h1
    {
        floatx4 c1[4];
#pragma unroll
        for (int nt = 0; nt < 4; ++nt) c1[nt] = (floatx4){0.f, 0.f, 0.f, 0.f};
#pragma unroll
        for (int kt = 0; kt < 2; ++kt) {
            short8 af = *(const short8*)(hrow0 + kt * 32);
            const short8* bp = (const short8*)WB1 + (size_t)(kt * 4) * 64 + l;
#pragma unroll
            for (int nt = 0; nt < 4; ++nt)
                c1[nt] = __builtin_amdgcn_mfma_f32_16x16x32_bf16(af, bp[nt * 64], c1[nt], 0, 0, 0);
        }
#pragma unroll
        for (int nt = 0; nt < 4; ++nt)
#pragma unroll
            for (int reg = 0; reg < 4; ++reg)
                H[quad * 4 + reg][H1OFF + nt * 16 + lr] = f2bf(silu_f(c1[nt][reg]));
    }

    // ---- phase 2: h1 -> h2 (64->64), silu -> LDS h0 (overwrite)
    {
        floatx4 c2[4];
#pragma unroll
        for (int nt = 0; nt < 4; ++nt) c2[nt] = (floatx4){0.f, 0.f, 0.f, 0.f};
#pragma unroll
        for (int kt = 0; kt < 2; ++kt) {
            short8 af = *(const short8*)(hrow1 + kt * 32);
            const short8* bp = (const short8*)WB2 + (size_t)(kt * 4) * 64 + l;
#pragma unroll
            for (int nt = 0; nt < 4; ++nt)
                c2[nt] = __builtin_amdgcn_mfma_f32_16x16x32_bf16(af, bp[nt * 64], c2[nt], 0, 0, 0);
        }
#pragma unroll
        for (int nt = 0; nt < 4; ++nt)
#pragma unroll
            for (int reg = 0; reg < 4; ++reg)
                H[quad * 4 + reg][nt * 16 + lr] = f2bf(silu_f(c2[nt][reg]));
    }

    // ---- phase 3: h2 -> tpw (64 -> 512), fold y0, scatter by slot
    {
        int slotr[4];
        float y0r[4];
#pragma unroll
        for (int reg = 0; reg < 4; ++reg) {
            const int er = e0 + quad * 4 + reg;
            slotr[reg] = pos[er];
            y0r[reg] = edge_attrs[(size_t)er * 4];
        }
        short8 af0 = *(const short8*)(hrow0);
        short8 af1 = *(const short8*)(hrow0 + 32);
        uint2* tpw2 = (uint2*)tpwP;
#pragma unroll
        for (int j2 = 0; j2 < 8; ++j2) {
            floatx4 c3[4];
#pragma unroll
            for (int g = 0; g < 4; ++g) c3[g] = (floatx4){0.f, 0.f, 0.f, 0.f};
#pragma unroll
            for (int g = 0; g < 4; ++g) {
                const short8* b0 = (const short8*)WB3 + (size_t)(g * 8 + j2) * 64 + l;
                const short8* b1 = (const short8*)WB3 + (size_t)(32 + g * 8 + j2) * 64 + l;
                c3[g] = __builtin_amdgcn_mfma_f32_16x16x32_bf16(af0, *b0, c3[g], 0, 0, 0);
                c3[g] = __builtin_amdgcn_mfma_f32_16x16x32_bf16(af1, *b1, c3[g], 0, 0, 0);
            }
            const int u = j2 * 16 + lr;
#pragma unroll
            for (int reg = 0; reg < 4; ++reg) {
                float w1v = c3[0][reg] * y0r[reg];
                float w2v = c3[1][reg];
                float w3v = c3[2][reg] * y0r[reg];
                float w4v = c3[3][reg];
                uint2 p;
                p.x = (unsigned)f2bf(w1v) | ((unsigned)f2bf(w2v) << 16);
                p.y = (unsigned)f2bf(w3v) | ((unsigned)f2bf(w4v) << 16);
                tpw2[(size_t)slotr[reg] * 128 + u] = p;
            }
        }
    }
}

// ---------------------------------------------------------------------------
// Kernel C: per-node gather, unrolled x4 for memory-level parallelism.
// ---------------------------------------------------------------------------
__global__ __launch_bounds__(128) void node_gather(
    const unsigned short* __restrict__ tpwP, const float* __restrict__ metaP,
    const int* __restrict__ offs, const uint2* __restrict__ xq,
    const float* __restrict__ alpha_p, const float* __restrict__ beta_p,
    unsigned short* __restrict__ msgs_b, unsigned short* __restrict__ msgv_b)
{
    const int n = blockIdx.x;
    const int j = threadIdx.x;
    const int s0 = offs[n], s1 = offs[n + 1];
    const uint2* tpw2 = (const uint2*)tpwP;

    float as0 = 0.f, as1 = 0.f;
    float av0x = 0.f, av0y = 0.f, av0z = 0.f;
    float av1x = 0.f, av1y = 0.f, av1z = 0.f;
    float dsum = 0.f;

    int s = s0;
    for (; s + 4 <= s1; s += 4) {
        float4 ma[4]; float dn[4]; uint2 wv[4]; uint2 xv[4];
#pragma unroll
        for (int k = 0; k < 4; ++k) {
            ma[k] = *(const float4*)&metaP[(size_t)(s + k) * 8];
            dn[k] = metaP[(size_t)(s + k) * 8 + 4];
            wv[k] = tpw2[(size_t)(s + k) * 128 + j];
        }
#pragma unroll
        for (int k = 0; k < 4; ++k)
            xv[k] = xq[(size_t)__float_as_int(ma[k].x) * 128 + j];
#pragma unroll
        for (int k = 0; k < 4; ++k) {
            const float y1x = ma[k].y, y1y = ma[k].z, y1z = ma[k].w;
            dsum += dn[k];
            const float w1  = __uint_as_float(wv[k].x << 16);
            const float w2  = __uint_as_float(wv[k].x & 0xffff0000u);
            const float w3  = __uint_as_float(wv[k].y << 16);
            const float w4  = __uint_as_float(wv[k].y & 0xffff0000u);
            const float xs  = __uint_as_float(xv[k].x << 16);
            const float xvx = __uint_as_float(xv[k].x & 0xffff0000u);
            const float xvy = __uint_as_float(xv[k].y << 16);
            const float xvz = __uint_as_float(xv[k].y & 0xffff0000u);
            as0 += w1 * xs;
            as1 += w4 * (xvx * y1x + xvy * y1y + xvz * y1z);
            const float b2 = w2 * xs;
            av0x += b2 * y1x; av0y += b2 * y1y; av0z += b2 * y1z;
            av1x += w3 * xvx; av1y += w3 * xvy; av1z += w3 * xvz;
        }
    }
    for (; s < s1; ++s) {
        const float4 m0 = *(const float4*)&metaP[(size_t)s * 8];
        const float dns = metaP[(size_t)s * 8 + 4];
        const int snd = __float_as_int(m0.x);
        const float y1x = m0.y, y1y = m0.z, y1z = m0.w;
        dsum += dns;
        uint2 wv = tpw2[(size_t)s * 128 + j];
        uint2 xv = xq[(size_t)snd * 128 + j];
        const float w1  = __uint_as_float(wv.x << 16);
        const float w2  = __uint_as_float(wv.x & 0xffff0000u);
        const float w3  = __uint_as_float(wv.y << 16);
        const float w4  = __uint_as_float(wv.y & 0xffff0000u);
        const float xs  = __uint_as_float(xv.x << 16);
        const float xvx = __uint_as_float(xv.x & 0xffff0000u);
        const float xvy = __uint_as_float(xv.y << 16);
        const float xvz = __uint_as_float(xv.y & 0xffff0000u);
        as0 += w1 * xs;
        as1 += w4 * (xvx * y1x + xvy * y1y + xvz * y1z);
        const float b2 = w2 * xs;
        av0x += b2 * y1x; av0y += b2 * y1y; av0z += b2 * y1z;
        av1x += w3 * xvx; av1y += w3 * xvy; av1z += w3 * xvz;
    }

    const float invden = 1.f / (dsum * (*beta_p) + (*alpha_p));

    msgs_b[(size_t)n * 256 + j]       = f2bf(as0 * invden);
    msgs_b[(size_t)n * 256 + 128 + j] = f2bf(as1 * invden);
    msgv_b[((size_t)0 * NN + n) * 256 + j]       = f2bf(av0x * invden);
    msgv_b[((size_t)0 * NN + n) * 256 + 128 + j] = f2bf(av1x * invden);
    msgv_b[((size_t)1 * NN + n) * 256 + j]       = f2bf(av0y * invden);
    msgv_b[((size_t)1 * NN + n) * 256 + 128 + j] = f2bf(av1y * invden);
    msgv_b[((size_t)2 * NN + n) * 256 + j]       = f2bf(av0z * invden);
    msgv_b[((size_t)2 * NN + n) * 256 + 128 + j] = f2bf(av1z * invden);
}

// ---------------------------------------------------------------------------
// Kernel D: FUSED post epilogue (round-7 verified version, unchanged).
// ---------------------------------------------------------------------------
#define DNP 16
__global__ __launch_bounds__(256) void post_fused(
    const unsigned short* __restrict__ msgs_b, const unsigned short* __restrict__ us_b,
    const unsigned short* __restrict__ msgv_b, const unsigned short* __restrict__ uv_b,
    const unsigned short* __restrict__ WPs, const unsigned short* __restrict__ WPv,
    const unsigned short* __restrict__ W2ss, const unsigned short* __restrict__ W2vs,
    float* __restrict__ out)
{
    __shared__ __align__(16) unsigned short osb[DNP][136];
    __shared__ __align__(16) unsigned short ovb[3][DNP][136];
    __shared__ float gateL[DNP][128];

    const int t = threadIdx.x;
    const int l = t & 63, w = t >> 6;         // 4 waves
    const int quad = l >> 4, lr = l & 15;
    const int n0 = blockIdx.x * DNP;
    const int nh = w;                         // 0..3 N-quarter
    const int n = n0 + lr;                    // this lane's A-row node

    const int cLo = (nh * 6) >> 3;
    const int cHi = (nh * 6 + 5) >> 3;

    const unsigned short* sRow  = msgs_b + (size_t)n * 256;
    const unsigned short* uRow  = us_b   + (size_t)n * 128;
    const unsigned short* vRowL = msgv_b + ((size_t)cLo * NN + n) * 256;
    const unsigned short* uRowL = uv_b   + ((size_t)cLo * NN + n) * 128;
    const unsigned short* vRowH = msgv_b + ((size_t)cHi * NN + n) * 256;
    const unsigned short* uRowH = uv_b   + ((size_t)cHi * NN + n) * 128;

    // ---- first layer: K=384 (12 kt), s: 4 N-tiles, v: 6 N-tiles
    floatx4 accS[4], accV[6];
#pragma unroll
    for (int i = 0; i < 4; ++i) accS[i] = (floatx4){0.f, 0.f, 0.f, 0.f};
#pragma unroll
    for (int i = 0; i < 6; ++i) accV[i] = (floatx4){0.f, 0.f, 0.f, 0.f};

#pragma unroll
    for (int kt = 0; kt < 12; ++kt) {
        const int col = kt * 32 + quad * 8;
        short8 aS = (col < 256) ? *(const short8*)(sRow + col)
                                : *(const short8*)(uRow + col - 256);
        short8 aV0 = (col < 256) ? *(const short8*)(vRowL + col)
                                 : *(const short8*)(uRowL + col - 256);
        short8 aV1;
        if (cHi != cLo)
            aV1 = (col < 256) ? *(const short8*)(vRowH + col)
                              : *(const short8*)(uRowH + col - 256);
        else
            aV1 = aV0;

        const short8* bpS = (const short8*)WPs + (size_t)(kt * 16 + nh * 4) * 64 + l;
#pragma unroll
        for (int i = 0; i < 4; ++i)
            accS[i] = __builtin_amdgcn_mfma_f32_16x16x32_bf16(aS, bpS[i * 64], accS[i], 0, 0, 0);
#pragma unroll
        for (int i = 0; i < 6; ++i) {
            const int vt = nh * 6 + i;
            const short8* bpV = (const short8*)WPv + (size_t)(kt * 8 + (vt & 7)) * 64 + l;
            short8 a = ((vt >> 3) == cLo) ? aV0 : aV1;
            accV[i] = __builtin_amdgcn_mfma_f32_16x16x32_bf16(a, *bpV, accV[i], 0, 0, 0);
        }
    }

    // ---- s outputs: tiles 0..7 -> silu -> osb; 8..15 -> sigmoid -> gateL
#pragma unroll
    for (int i = 0; i < 4; ++i) {
        const int tile = nh * 4 + i;
#pragma unroll
        for (int reg = 0; reg < 4; ++reg) {
            const int row = quad * 4 + reg;
            const float v = accS[i][reg];
            if (tile < 8) osb[row][tile * 16 + lr] = f2bf(silu_f(v));
            else          gateL[row][(tile - 8) * 16 + lr] = sigm_f(v);
        }
    }
    __syncthreads();

    // ---- gate the v accumulators -> ovb
#pragma unroll
    for (int i = 0; i < 6; ++i) {
        const int vt = nh * 6 + i;
        const int c = vt >> 3;
        const int colv = (vt & 7) * 16 + lr;
#pragma unroll
        for (int reg = 0; reg < 4; ++reg) {
            const int row = quad * 4 + reg;
            ovb[c][row][colv] = f2bf(accV[i][reg] * gateL[row][colv]);
        }
    }
    __syncthreads();

    // ---- second layer: K=128 (4 kt); s: 2 N-tiles, v: 6 N-tiles
    floatx4 c2s[2], c2v[6];
#pragma unroll
    for (int i = 0; i < 2; ++i) c2s[i] = (floatx4){0.f, 0.f, 0.f, 0.f};
#pragma unroll
    for (int i = 0; i < 6; ++i) c2v[i] = (floatx4){0.f, 0.f, 0.f, 0.f};

    const unsigned short* arowS = &osb[lr][quad * 8];
#pragma unroll
    for (int kt = 0; kt < 4; ++kt) {
        short8 afS = *(const short8*)(arowS + kt * 32);
        const short8* bpS = (const short8*)W2ss + (size_t)(kt * 8 + nh * 2) * 64 + l;
#pragma unroll
        for (int i = 0; i < 2; ++i)
            c2s[i] = __builtin_amdgcn_mfma_f32_16x16x32_bf16(afS, bpS[i * 64], c2s[i], 0, 0, 0);
#pragma unroll
        for (int i = 0; i < 6; ++i) {
            const int vt = nh * 6 + i;
            const int c = vt >> 3;
            short8 afV = *(const short8*)(&ovb[c][lr][quad * 8] + kt * 32);
            const short8* bpV = (const short8*)W2vs + (size_t)(kt * 8 + (vt & 7)) * 64 + l;
            c2v[i] = __builtin_amdgcn_mfma_f32_16x16x32_bf16(afV, *bpV, c2v[i], 0, 0, 0);
        }
    }

    // ---- epilogue
#pragma unroll
    for (int i = 0; i < 2; ++i) {
        const int col = (nh * 2 + i) * 16 + lr;
#pragma unroll
        for (int reg = 0; reg < 4; ++reg)
            out[(size_t)(n0 + quad * 4 + reg) * 512 + col * 4] = c2s[i][reg];
    }
#pragma unroll
    for (int i = 0; i < 6; ++i) {
        const int vt = nh * 6 + i;
        const int c = vt >> 3;
        const int col = (vt & 7) * 16 + lr;
#pragma unroll
        for (int reg = 0; reg < 4; ++reg)
            out[(size_t)(n0 + quad * 4 + reg) * 512 + col * 4 + 1 + c] = c2v[i][reg];
    }
}

// ---------------------------------------------------------------------------
extern "C" void kernel_launch(void* const* d_in, const int* in_sizes, int n_in,
                              void* d_out, int out_size, void* d_ws, size_t ws_size,
                              hipStream_t stream)
{
    const float* node_attrs = (const float*)d_in[0];
    const float* node_feats = (const float*)d_in[1];
    const float* edge_attrs = (const float*)d_in[2];
    const float* edge_feats = (const float*)d_in[3];
    const int*   edge_index = (const int*)d_in[4];
    const float* W_skip_s = (const float*)d_in[5];
    const float* W_skip_v = (const float*)d_in[6];
    const float* W_up_s   = (const float*)d_in[7];
    const float* W_up_v   = (const float*)d_in[8];
    const float* W_src    = (const float*)d_in[9];
    const float* W_tgt    = (const float*)d_in[10];
    const float* W_r0     = (const float*)d_in[11];
    const float* W_r1     = (const float*)d_in[12];
    const float* W_r2     = (const float*)d_in[13];
    const float* W_r3     = (const float*)d_in[14];
    const float* W_d0     = (const float*)d_in[15];
    const float* W_d1     = (const float*)d_in[16];
    const float* W1_s     = (const float*)d_in[17];
    const float* W1_v     = (const float*)d_in[18];
    const float* Wres_s   = (const float*)d_in[19];
    const float* Wres_v   = (const float*)d_in[20];
    const float* W2_s     = (const float*)d_in[21];
    const float* W2_v     = (const float*)d_in[22];
    const float* alpha_p  = (const float*)d_in[23];
    const float* beta_p   = (const float*)d_in[24];

    float* out = (float*)d_out;
    float* sc_out = out + (size_t)NN * 512;
    float* ws = (float*)d_ws;

    uint2* xq = (uint2*)(ws + WS_XQ);
    unsigned short* us_b  = (unsigned short*)(ws + WS_USB);
    unsigned short* uv_b  = (unsigned short*)(ws + WS_UVB);
    unsigned short* srcEb = (unsigned short*)(ws + WS_SRC);
    unsigned short* tgtEb = (unsigned short*)(ws + WS_TGT);
    unsigned short* msgs_b = (unsigned short*)(ws + WS_MSGSB);
    unsigned short* msgv_b = (unsigned short*)(ws + WS_MSGVB);
    int*   counts = (int*)(ws + WS_COUNTS);
    int*   offs   = (int*)(ws + WS_OFFS);
    int*   cursor = (int*)(ws + WS_CURSOR);
    int*   pos    = (int*)(ws + WS_POS);
    float* metaP  = ws + WS_META;
    unsigned short* tpwP = (unsigned short*)(ws + WS_TPW);
    unsigned short* WBall = (unsigned short*)(ws + WS_WB);
    unsigned short* WB0 = WBall;
    unsigned short* WB1 = WB0 + (size_t)72 * 512;
    unsigned short* WB2 = WB1 + (size_t)8 * 512;
    unsigned short* WB3 = WB2 + (size_t)8 * 512;
    unsigned short* WPall = (unsigned short*)(ws + WS_WP);
    unsigned short* WPs  = WPall;
    unsigned short* WPv  = WPs + (size_t)192 * 512;
    unsigned short* W2ss = WPv + (size_t)96 * 512;
    unsigned short* W2vs = W2ss + (size_t)32 * 512;
    unsigned short* WN   = (unsigned short*)(ws + WS_WN);

    hipMemsetAsync(counts, 0, (size_t)NN * sizeof(int), stream);

    csr_count<<<EE / 256, 256, 0, stream>>>(edge_index, counts);
    csr_scan<<<1, 1024, 0, stream>>>(counts, offs, cursor);
    csr_scatter<<<EE / 256, 256, 0, stream>>>(edge_index, cursor, pos);

    swizzle_weights<<<38, 256, 0, stream>>>(W_r0, W_d0, W_r1, W_r2, W_r3, WBall);
    swizzle_post<<<88, 256, 0, stream>>>(W1_s, W1_v, Wres_s, Wres_v, W2_s, W2_v, WPall);
    swizzle_node<<<36, 256, 0, stream>>>(W_skip_s, W_up_s, W_skip_v, W_up_v,
                                         W_src, W_tgt, WN);

    node_pre_mfma<<<NN / PNB, 256, 0, stream>>>(
        node_attrs, node_feats, WN, sc_out, xq, us_b, uv_b, srcEb, tgtEb);

    edge_mlp<<<EE / EBK, 256, 0, stream>>>(
        edge_attrs, edge_feats, edge_index, srcEb, tgtEb,
        WB0, WB1, WB2, WB3, W_d1, pos, tpwP, metaP);

    node_gather<<<NN, 128, 0, stream>>>(
        tpwP, metaP, offs, xq, alpha_p, beta_p, msgs_b, msgv_b);

    post_fused<<<NN / DNP, 256, 0, stream>>>(
        msgs_b, us_b, msgv_b, uv_b, WPs, WPv, W2ss, W2vs, out);
}

// Round 10
// 301.942 us; speedup vs baseline: 3.2764x; 1.0254x over previous
//
#include <hip/hip_runtime.h>

// Problem constants (fixed by the reference)
#define NN 8192
#define EE 131072
#define MUL 128
#define AA 10
#define RB 8
#define DEF 264          // RB + 2*MUL
#define INV_SQRT3 0.5773502691896258f
#define INV_SQRT128 0.08838834764831845f
#define INV_SQRT10 0.31622776601683794f
#define INV_SQRT264 0.06154574548966636f

typedef __attribute__((ext_vector_type(8))) short short8;
typedef __attribute__((ext_vector_type(4))) float floatx4;

// ---------------------------------------------------------------------------
// Workspace layout (float offsets). ~182 MB total.
// ---------------------------------------------------------------------------
#define WS_XQ     ((size_t)0)                       // N*128 uint2 {us,uvx,uvy,uvz} bf16
#define WS_USB    (WS_XQ    + (size_t)NN*256)       // N*128 bf16
#define WS_UVB    (WS_USB   + (size_t)NN*64)        // 3*N*128 bf16 channel-major
#define WS_SRC    (WS_UVB   + (size_t)NN*192)       // N*128 bf16
#define WS_TGT    (WS_SRC   + (size_t)NN*64)        // N*128 bf16
#define WS_MSGSB  (WS_TGT   + (size_t)NN*64)        // N*256 bf16 (invden applied)
#define WS_MSGVB  (WS_MSGSB + (size_t)NN*128)       // 3*N*256 bf16 channel-major
#define WS_GATE   (WS_MSGVB + (size_t)NN*384)       // N*128 f32 (unused since post fusion)
#define WS_COUNTS (WS_GATE  + (size_t)NN*128)       // N ints
#define WS_OFFS   (WS_COUNTS+ (size_t)NN)           // N+4 ints
#define WS_CURSOR (WS_OFFS  + (size_t)(NN+4))       // N ints
#define WS_POS    (WS_CURSOR+ (size_t)NN)           // E ints
#define WS_META   (WS_POS   + (size_t)EE)           // E*8 f32
#define WS_TPW    (WS_META  + (size_t)EE*8)         // E*512 bf16, [slot][u][4] interleaved
#define WS_WB     (WS_TPW   + (size_t)EE*256)       // edge wfrags 152*512 bf16
#define WS_WP     (WS_WB    + (size_t)152*256)      // post wfrags 352*512 bf16
#define WS_WN     (WS_WP    + (size_t)352*256)      // node wfrags 144*512 bf16

__device__ __forceinline__ float silu_f(float x) {
    return x * __builtin_amdgcn_rcpf(1.f + __expf(-x));
}
__device__ __forceinline__ float sigm_f(float x) {
    return __builtin_amdgcn_rcpf(1.f + __expf(-x));
}

__device__ __forceinline__ unsigned short f2bf(float x) {
    union { float f; unsigned u; } uf; uf.f = x;
    unsigned r = uf.u + 0x7FFFu + ((uf.u >> 16) & 1u);   // RNE
    return (unsigned short)(r >> 16);
}

// ---------------------------------------------------------------------------
// CSR build: count -> scan -> scatter   (receiver-sorted edge slots)
// ---------------------------------------------------------------------------
__global__ __launch_bounds__(256) void csr_count(
    const int* __restrict__ edge_index, int* __restrict__ counts)
{
    int e = blockIdx.x * 256 + threadIdx.x;
    atomicAdd(&counts[edge_index[EE + e]], 1);
}

__global__ __launch_bounds__(1024) void csr_scan(
    const int* __restrict__ counts, int* __restrict__ offs, int* __restrict__ cursor)
{
    __shared__ int sums[1024];
    const int t = threadIdx.x;
    int local[8];
    int s = 0;
#pragma unroll
    for (int k = 0; k < 8; ++k) { local[k] = s; s += counts[t * 8 + k]; }
    sums[t] = s;
    __syncthreads();
    for (int d = 1; d < 1024; d <<= 1) {
        int v = (t >= d) ? sums[t - d] : 0;
        __syncthreads();
        sums[t] += v;
        __syncthreads();
    }
    int base = (t > 0) ? sums[t - 1] : 0;
#pragma unroll
    for (int k = 0; k < 8; ++k) {
        offs[t * 8 + k] = base + local[k];
        cursor[t * 8 + k] = base + local[k];
    }
    if (t == 1023) offs[8192] = sums[1023];
}

__global__ __launch_bounds__(256) void csr_scatter(
    const int* __restrict__ edge_index, int* __restrict__ cursor, int* __restrict__ pos)
{
    int e = blockIdx.x * 256 + threadIdx.x;
    pos[e] = atomicAdd(&cursor[edge_index[EE + e]], 1);
}

// ---------------------------------------------------------------------------
// Edge weight pre-swizzle into MFMA B-fragment order (bf16, scales folded).
// ---------------------------------------------------------------------------
__global__ __launch_bounds__(256) void swizzle_weights(
    const float* __restrict__ Wr0, const float* __restrict__ Wd0,
    const float* __restrict__ Wr1, const float* __restrict__ Wr2,
    const float* __restrict__ Wr3, unsigned short* __restrict__ WBall)
{
    int fid = blockIdx.x * 256 + threadIdx.x;
    int lane = fid & 63;
    int frag = fid >> 6;
    int k0 = (lane >> 4) * 8;
    int n0 = lane & 15;
    unsigned short o[8];

    if (frag < 72) {
        int kt = frag >> 3, nt = frag & 7;
        int n = nt * 16 + n0;
#pragma unroll
        for (int j = 0; j < 8; ++j) {
            int k = kt * 32 + k0 + j;
            float v = 0.f;
            if (k < 264) v = ((n < 64) ? Wr0[k * 64 + n] : Wd0[k * 64 + (n - 64)]) * INV_SQRT264;
            o[j] = f2bf(v);
        }
    } else if (frag < 80) {
        int fl = frag - 72;
        int kt = fl >> 2, nt = fl & 3;
        int n = nt * 16 + n0;
#pragma unroll
        for (int j = 0; j < 8; ++j)
            o[j] = f2bf(Wr1[(kt * 32 + k0 + j) * 64 + n] * 0.125f);
    } else if (frag < 88) {
        int fl = frag - 80;
        int kt = fl >> 2, nt = fl & 3;
        int n = nt * 16 + n0;
#pragma unroll
        for (int j = 0; j < 8; ++j)
            o[j] = f2bf(Wr2[(kt * 32 + k0 + j) * 64 + n] * 0.125f);
    } else {
        int fl = frag - 88;
        int kt = fl >> 5, nt = fl & 31;
        int n = nt * 16 + n0;
        int q = n >> 6;
        float sc = (q < 2) ? 0.125f : 0.125f * INV_SQRT3;
#pragma unroll
        for (int j = 0; j < 8; ++j)
            o[j] = f2bf(Wr3[(kt * 32 + k0 + j) * 512 + n] * sc);
    }
    uint4 pk;
    pk.x = (unsigned)o[0] | ((unsigned)o[1] << 16);
    pk.y = (unsigned)o[2] | ((unsigned)o[3] << 16);
    pk.z = (unsigned)o[4] | ((unsigned)o[5] << 16);
    pk.w = (unsigned)o[6] | ((unsigned)o[7] << 16);
    *(uint4*)(WBall + (size_t)fid * 8) = pk;
}

// ---------------------------------------------------------------------------
// Post weight pre-swizzle (unchanged).
// ---------------------------------------------------------------------------
__global__ __launch_bounds__(256) void swizzle_post(
    const float* __restrict__ W1s, const float* __restrict__ W1v,
    const float* __restrict__ Wrs, const float* __restrict__ Wrv,
    const float* __restrict__ W2s, const float* __restrict__ W2v,
    unsigned short* __restrict__ WPall)
{
    int fid = blockIdx.x * 256 + threadIdx.x;
    int lane = fid & 63;
    int frag = fid >> 6;
    int k0 = (lane >> 4) * 8;
    int n0 = lane & 15;
    unsigned short o[8];

    if (frag < 192) {
        int kt = frag >> 4, nt = frag & 15;
        int n = nt * 16 + n0;
#pragma unroll
        for (int j = 0; j < 8; ++j) {
            int k = kt * 32 + k0 + j;
            float v = (k < 256) ? W1s[k * 256 + n] * 0.0625f
                                : Wrs[(k - 256) * 256 + n] * INV_SQRT128;
            o[j] = f2bf(v);
        }
    } else if (frag < 288) {
        int fl = frag - 192;
        int kt = fl >> 3, nt = fl & 7;
        int n = nt * 16 + n0;
#pragma unroll
        for (int j = 0; j < 8; ++j) {
            int k = kt * 32 + k0 + j;
            float v = (k < 256) ? W1v[k * 128 + n] * 0.0625f
                                : Wrv[(k - 256) * 128 + n] * INV_SQRT128;
            o[j] = f2bf(v);
        }
    } else if (frag < 320) {
        int fl = frag - 288;
        int kt = fl >> 3, nt = fl & 7;
        int n = nt * 16 + n0;
#pragma unroll
        for (int j = 0; j < 8; ++j)
            o[j] = f2bf(W2s[(kt * 32 + k0 + j) * 128 + n] * INV_SQRT128);
    } else {
        int fl = frag - 320;
        int kt = fl >> 3, nt = fl & 7;
        int n = nt * 16 + n0;
#pragma unroll
        for (int j = 0; j < 8; ++j)
            o[j] = f2bf(W2v[(kt * 32 + k0 + j) * 128 + n] * INV_SQRT128);
    }
    uint4 pk;
    pk.x = (unsigned)o[0] | ((unsigned)o[1] << 16);
    pk.y = (unsigned)o[2] | ((unsigned)o[3] << 16);
    pk.z = (unsigned)o[4] | ((unsigned)o[5] << 16);
    pk.w = (unsigned)o[6] | ((unsigned)o[7] << 16);
    *(uint4*)(WPall + (size_t)fid * 8) = pk;
}

// ---------------------------------------------------------------------------
// Node weight pre-swizzle (A-operand layout for the transposed node GEMM).
// ---------------------------------------------------------------------------
__global__ __launch_bounds__(256) void swizzle_node(
    const float* __restrict__ Wss, const float* __restrict__ Wus,
    const float* __restrict__ Wsv, const float* __restrict__ Wuv,
    const float* __restrict__ Wsrc, const float* __restrict__ Wtgt,
    unsigned short* __restrict__ WN)
{
    int fid = blockIdx.x * 256 + threadIdx.x;   // 144*64 = 9216 = 36*256
    int lane = fid & 63;
    int frag = fid >> 6;
    int k0 = (lane >> 4) * 8;
    int m0 = lane & 15;
    unsigned short o[8];

    if (frag < 128) {
        int g = frag >> 5;
        int fl = frag & 31;
        int kt = fl >> 3, mt = fl & 7;
        const float* W = (g == 0) ? Wss : (g == 1) ? Wus : (g == 2) ? Wsv : Wuv;
        int m = mt * 16 + m0;
#pragma unroll
        for (int j = 0; j < 8; ++j)
            o[j] = f2bf(W[(kt * 32 + k0 + j) * 128 + m] * INV_SQRT128);
    } else {
        int g = (frag - 128) >> 3;
        int mt = frag & 7;
        const float* W = g ? Wtgt : Wsrc;
        int m = mt * 16 + m0;
#pragma unroll
        for (int j = 0; j < 8; ++j) {
            int k = k0 + j;
            o[j] = f2bf((k < AA) ? W[k * 128 + m] * INV_SQRT10 : 0.f);
        }
    }
    uint4 pk;
    pk.x = (unsigned)o[0] | ((unsigned)o[1] << 16);
    pk.y = (unsigned)o[2] | ((unsigned)o[3] << 16);
    pk.z = (unsigned)o[4] | ((unsigned)o[5] << 16);
    pk.w = (unsigned)o[6] | ((unsigned)o[7] << 16);
    *(uint4*)(WN + (size_t)fid * 8) = pk;
}

// ---------------------------------------------------------------------------
// Kernel A: per-node precompute on MFMA (unchanged).
// ---------------------------------------------------------------------------
#define PNB 16
__global__ __launch_bounds__(256) void node_pre_mfma(
    const float* __restrict__ node_attrs, const float* __restrict__ node_feats,
    const unsigned short* __restrict__ WN,
    float* __restrict__ sc_out, uint2* __restrict__ xq,
    unsigned short* __restrict__ us_b, unsigned short* __restrict__ uv_b,
    unsigned short* __restrict__ srcEb, unsigned short* __restrict__ tgtEb)
{
    __shared__ __align__(16) unsigned short Xs[PNB][136];
    __shared__ __align__(16) unsigned short Xv[3][PNB][136];
    __shared__ __align__(16) unsigned short Xa[PNB][40];
    const int t = threadIdx.x;
    const int l = t & 63, w = t >> 6;
    const int quad = l >> 4, lr = l & 15;
    const int n0 = blockIdx.x * PNB;

    // ---- stage node_feats (f32 -> bf16): thread (r=t>>4, m=t&15)
    {
        const int r = t >> 4, m = t & 15;
        const float* src = node_feats + (size_t)(n0 + r) * 512;
        float4 s0 = *(const float4*)(src + 8 * m);
        float4 s1 = *(const float4*)(src + 8 * m + 4);
        uint4 sp;
        sp.x = (unsigned)f2bf(s0.x) | ((unsigned)f2bf(s0.y) << 16);
        sp.y = (unsigned)f2bf(s0.z) | ((unsigned)f2bf(s0.w) << 16);
        sp.z = (unsigned)f2bf(s1.x) | ((unsigned)f2bf(s1.y) << 16);
        sp.w = (unsigned)f2bf(s1.z) | ((unsigned)f2bf(s1.w) << 16);
        *(uint4*)&Xs[r][8 * m] = sp;

        float4 q[6];
#pragma unroll
        for (int jj = 0; jj < 6; ++jj)
            q[jj] = *(const float4*)(src + 128 + 24 * m + 4 * jj);
        const float* qf = &q[0].x;
        unsigned short vb[3][8];
#pragma unroll
        for (int u = 0; u < 8; ++u) {
#pragma unroll
            for (int c = 0; c < 3; ++c)
                vb[c][u] = f2bf(qf[u * 3 + c]);
        }
#pragma unroll
        for (int c = 0; c < 3; ++c) {
            uint4 vp;
            vp.x = (unsigned)vb[c][0] | ((unsigned)vb[c][1] << 16);
            vp.y = (unsigned)vb[c][2] | ((unsigned)vb[c][3] << 16);
            vp.z = (unsigned)vb[c][4] | ((unsigned)vb[c][5] << 16);
            vp.w = (unsigned)vb[c][6] | ((unsigned)vb[c][7] << 16);
            *(uint4*)&Xv[c][r][8 * m] = vp;
        }
    }
    // ---- stage attrs (padded K=32)
    for (int idx = t; idx < PNB * 32; idx += 256) {
        int r = idx >> 5, k = idx & 31;
        float v = (k < AA) ? node_attrs[(size_t)(n0 + r) * AA + k] : 0.f;
        Xa[r][k] = f2bf(v);
    }
    __syncthreads();

    const short8* WNf = (const short8*)WN;
    const int n = n0 + lr;

#pragma unroll
    for (int mi = 0; mi < 2; ++mi) {
        const int mt = w * 2 + mi;
        const int j0 = mt * 16 + quad * 4;

        // attr GEMM (K=32): srcE / tgtE
        floatx4 cSrc = (floatx4){0.f, 0.f, 0.f, 0.f};
        floatx4 cTgt = (floatx4){0.f, 0.f, 0.f, 0.f};
        {
            short8 ba = *(const short8*)&Xa[lr][quad * 8];
            cSrc = __builtin_amdgcn_mfma_f32_16x16x32_bf16(WNf[(size_t)(128 + mt) * 64 + l], ba, cSrc, 0, 0, 0);
            cTgt = __builtin_amdgcn_mfma_f32_16x16x32_bf16(WNf[(size_t)(136 + mt) * 64 + l], ba, cTgt, 0, 0, 0);
        }
        // s GEMMs (K=128): sc_s / us
        floatx4 cS = (floatx4){0.f, 0.f, 0.f, 0.f};
        floatx4 cU = (floatx4){0.f, 0.f, 0.f, 0.f};
#pragma unroll
        for (int kt = 0; kt < 4; ++kt) {
            short8 bs = *(const short8*)&Xs[lr][kt * 32 + quad * 8];
            cS = __builtin_amdgcn_mfma_f32_16x16x32_bf16(WNf[(size_t)(kt * 8 + mt) * 64 + l], bs, cS, 0, 0, 0);
            cU = __builtin_amdgcn_mfma_f32_16x16x32_bf16(WNf[(size_t)(32 + kt * 8 + mt) * 64 + l], bs, cU, 0, 0, 0);
        }
        // v GEMMs (K=128 x 3 channels): sc_v / uv
        floatx4 cSV[3], cUV[3];
#pragma unroll
        for (int c = 0; c < 3; ++c) {
            cSV[c] = (floatx4){0.f, 0.f, 0.f, 0.f};
            cUV[c] = (floatx4){0.f, 0.f, 0.f, 0.f};
#pragma unroll
            for (int kt = 0; kt < 4; ++kt) {
                short8 bv = *(const short8*)&Xv[c][lr][kt * 32 + quad * 8];
                cSV[c] = __builtin_amdgcn_mfma_f32_16x16x32_bf16(WNf[(size_t)(64 + kt * 8 + mt) * 64 + l], bv, cSV[c], 0, 0, 0);
                cUV[c] = __builtin_amdgcn_mfma_f32_16x16x32_bf16(WNf[(size_t)(96 + kt * 8 + mt) * 64 + l], bv, cUV[c], 0, 0, 0);
            }
        }

        // ---- epilogue: packed stores (node n, outputs j0..j0+3)
        {
            float4 o;
            o.x = cS[0]; o.y = cS[1]; o.z = cS[2]; o.w = cS[3];
            *(float4*)(sc_out + (size_t)n * 512 + j0) = o;
        }
        {
            float vv[12];
#pragma unroll
            for (int reg = 0; reg < 4; ++reg)
#pragma unroll
                for (int c = 0; c < 3; ++c) vv[reg * 3 + c] = cSV[c][reg];
            float* dst = sc_out + (size_t)n * 512 + 128 + j0 * 3;
#pragma unroll
            for (int qq = 0; qq < 3; ++qq) {
                float4 o;
                o.x = vv[qq * 4]; o.y = vv[qq * 4 + 1]; o.z = vv[qq * 4 + 2]; o.w = vv[qq * 4 + 3];
                *(float4*)(dst + qq * 4) = o;
            }
        }
        unsigned short ub[4], vxb[4], vyb[4], vzb[4];
#pragma unroll
        for (int reg = 0; reg < 4; ++reg) {
            ub[reg] = f2bf(cU[reg]);
            vxb[reg] = f2bf(cUV[0][reg]);
            vyb[reg] = f2bf(cUV[1][reg]);
            vzb[reg] = f2bf(cUV[2][reg]);
        }
        {
            uint2 p;
            p.x = (unsigned)ub[0] | ((unsigned)ub[1] << 16);
            p.y = (unsigned)ub[2] | ((unsigned)ub[3] << 16);
            *(uint2*)(us_b + (size_t)n * 128 + j0) = p;
        }
        {
            uint2 p;
            p.x = (unsigned)vxb[0] | ((unsigned)vxb[1] << 16);
            p.y = (unsigned)vxb[2] | ((unsigned)vxb[3] << 16);
            *(uint2*)(uv_b + ((size_t)0 * NN + n) * 128 + j0) = p;
            p.x = (unsigned)vyb[0] | ((unsigned)vyb[1] << 16);
            p.y = (unsigned)vyb[2] | ((unsigned)vyb[3] << 16);
            *(uint2*)(uv_b + ((size_t)1 * NN + n) * 128 + j0) = p;
            p.x = (unsigned)vzb[0] | ((unsigned)vzb[1] << 16);
            p.y = (unsigned)vzb[2] | ((unsigned)vzb[3] << 16);
            *(uint2*)(uv_b + ((size_t)2 * NN + n) * 128 + j0) = p;
        }
        {
            uint4 x0, x1;
            x0.x = (unsigned)ub[0] | ((unsigned)vxb[0] << 16);
            x0.y = (unsigned)vyb[0] | ((unsigned)vzb[0] << 16);
            x0.z = (unsigned)ub[1] | ((unsigned)vxb[1] << 16);
            x0.w = (unsigned)vyb[1] | ((unsigned)vzb[1] << 16);
            x1.x = (unsigned)ub[2] | ((unsigned)vxb[2] << 16);
            x1.y = (unsigned)vyb[2] | ((unsigned)vzb[2] << 16);
            x1.z = (unsigned)ub[3] | ((unsigned)vxb[3] << 16);
            x1.w = (unsigned)vyb[3] | ((unsigned)vzb[3] << 16);
            uint4* xp = (uint4*)(xq + (size_t)n * 128 + j0);
            xp[0] = x0; xp[1] = x1;
        }
        {
            uint2 p;
            p.x = (unsigned)f2bf(cSrc[0]) | ((unsigned)f2bf(cSrc[1]) << 16);
            p.y = (unsigned)f2bf(cSrc[2]) | ((unsigned)f2bf(cSrc[3]) << 16);
            *(uint2*)(srcEb + (size_t)n * 128 + j0) = p;
            p.x = (unsigned)f2bf(cTgt[0]) | ((unsigned)f2bf(cTgt[1]) << 16);
            p.y = (unsigned)f2bf(cTgt[2]) | ((unsigned)f2bf(cTgt[3]) << 16);
            *(uint2*)(tgtEb + (size_t)n * 128 + j0) = p;
        }
    }
}

// ---------------------------------------------------------------------------
// Kernel B: per-edge MLP on MFMA (round-7 verified version: (256,4), phase 3
// included). w=5 spilled (FETCH +14%, WRITE +17%, dur 80->101); w=4 is the
// confirmed operating point.
// ---------------------------------------------------------------------------
#define EBK 64
#define H1OFF 80
#define HLD 152   // LDS row stride (u16): 304B = odd multiple of 16B
__global__ __launch_bounds__(256, 4) void edge_mlp(
    const float* __restrict__ edge_attrs, const float* __restrict__ edge_feats,
    const int* __restrict__ edge_index,
    const unsigned short* __restrict__ srcEb, const unsigned short* __restrict__ tgtEb,
    const unsigned short* __restrict__ WB0, const unsigned short* __restrict__ WB1,
    const unsigned short* __restrict__ WB2, const unsigned short* __restrict__ WB3,
    const float* __restrict__ Wd1, const int* __restrict__ pos,
    unsigned short* __restrict__ tpwP, float* __restrict__ metaP)
{
    __shared__ __align__(16) unsigned short Hb[4][16][HLD];

    const int t = threadIdx.x;
    const int l = t & 63;
    const int w = t >> 6;
    const int quad = l >> 4;
    const int lr = l & 15;
    const int e0 = blockIdx.x * EBK + w * 16;   // this wave's 16 edges

    // Row-edge for this lane's A-fragments (A row = lane&15).
    const int eA = e0 + lr;
    const int sndA = edge_index[eA];
    const int rcvA = edge_index[EE + eA];
    const unsigned short* spp = srcEb + (size_t)sndA * 128;
    const unsigned short* tpp = tgtEb + (size_t)rcvA * 128;

    // meta m0: one lane per edge (quad 0 covers the wave's 16 edges)
    if (quad == 0) {
        float4 ya = *(const float4*)(edge_attrs + (size_t)eA * 4);
        float4 m;
        m.x = __int_as_float(sndA); m.y = ya.y; m.z = ya.z; m.w = ya.w;
        *(float4*)(metaP + (size_t)pos[eA] * 8) = m;
    }

    // ---- load all 9 A-fragments for ef row eA (cols kt*32 + quad*8 .. +8)
    short8 afr[9];
    {
        const int cq = quad * 8;
        if (quad == 0) {
            float4 f0 = *(const float4*)(edge_feats + (size_t)eA * 8);
            float4 f1 = *(const float4*)(edge_feats + (size_t)eA * 8 + 4);
            union { short8 v; unsigned u[4]; } pk;
            pk.u[0] = (unsigned)f2bf(f0.x) | ((unsigned)f2bf(f0.y) << 16);
            pk.u[1] = (unsigned)f2bf(f0.z) | ((unsigned)f2bf(f0.w) << 16);
            pk.u[2] = (unsigned)f2bf(f1.x) | ((unsigned)f2bf(f1.y) << 16);
            pk.u[3] = (unsigned)f2bf(f1.z) | ((unsigned)f2bf(f1.w) << 16);
            afr[0] = pk.v;
        } else {
            afr[0] = *(const short8*)(spp + (cq - 8));
        }
#pragma unroll
        for (int kt = 1; kt < 9; ++kt) {
            const int c = kt * 32 + cq;
            if (c < 136) {
                afr[kt] = *(const short8*)(spp + (c - 8));
            } else if (c < 264) {
                afr[kt] = *(const short8*)(tpp + (c - 136));
            } else {
                short8 z = {0, 0, 0, 0, 0, 0, 0, 0};
                afr[kt] = z;
            }
        }
    }

    unsigned short (*H)[HLD] = Hb[w];

    // ---- phase 0: first layer, r-path AND d-path in ONE K=288 pass
    {
        floatx4 c0[8];
#pragma unroll
        for (int nt = 0; nt < 8; ++nt) c0[nt] = (floatx4){0.f, 0.f, 0.f, 0.f};
#pragma unroll
        for (int kt = 0; kt < 9; ++kt) {
            const short8* bp = (const short8*)WB0 + (size_t)(kt * 8) * 64 + l;
#pragma unroll
            for (int nt = 0; nt < 8; ++nt)
                c0[nt] = __builtin_amdgcn_mfma_f32_16x16x32_bf16(afr[kt], bp[nt * 64], c0[nt], 0, 0, 0);
        }

        // r-path (nt 0..3): silu -> LDS h0
#pragma unroll
        for (int nt = 0; nt < 4; ++nt)
#pragma unroll
            for (int reg = 0; reg < 4; ++reg)
                H[quad * 4 + reg][nt * 16 + lr] = f2bf(silu_f(c0[nt][reg]));

        // d-path (nt 4..7): dot(Wd1) via shfl reduce -> meta
        float wd1v[4];
#pragma unroll
        for (int q2 = 0; q2 < 4; ++q2) wd1v[q2] = Wd1[q2 * 16 + lr] * 0.125f;
        float dp[4] = {0.f, 0.f, 0.f, 0.f};
#pragma unroll
        for (int nt = 0; nt < 4; ++nt)
#pragma unroll
            for (int reg = 0; reg < 4; ++reg)
                dp[reg] += silu_f(c0[nt + 4][reg]) * wd1v[nt];
#pragma unroll
        for (int m2 = 1; m2 < 16; m2 <<= 1) {
#pragma unroll
            for (int reg = 0; reg < 4; ++reg) dp[reg] += __shfl_xor(dp[reg], m2);
        }
        if (lr == 0) {
#pragma unroll
            for (int reg = 0; reg < 4; ++reg)
                metaP[(size_t)pos[e0 + quad * 4 + reg] * 8 + 4] = tanhf(dp[reg] * dp[reg]);
        }
    }

    const unsigned short* hrow0 = &H[lr][quad * 8];
    const unsigned short* hrow1 = &H[lr][H1OFF + quad * 8];

    // ---- phase 1: h0 -> h1 (64->64), silu -> LDS h1
    {
        floatx4 c1[4];
#pragma unroll
        for (int nt = 0; nt < 4; ++nt) c1[nt] = (floatx4){0.f, 0.f, 0.f, 0.f};
#pragma unroll
        for (int kt = 0; kt < 2; ++kt) {
            short8 af = *(const short8*)(hrow0 + kt * 32);
            const short8* bp = (const short8*)WB1 + (size_t)(kt * 4) * 64 + l;
#pragma unroll
            for (int nt = 0; nt < 4; ++nt)
                c1[nt] = __builtin_amdgcn_mfma_f32_16x16x32_bf16(af, bp[nt * 64], c1[nt], 0, 0, 0);
        }
#pragma unroll
        for (int nt = 0; nt < 4; ++nt)
#pragma unroll
            for (int reg = 0; reg < 4; ++reg)
                H[quad * 4 + reg][H1OFF + nt * 16 + lr] = f2bf(silu_f(c1[nt][reg]));
    }

    // ---- phase 2: h1 -> h2 (64->64), silu -> LDS h0 (overwrite)
    {
        floatx4 c2[4];
#pragma unroll
        for (int nt = 0; nt < 4; ++nt) c2[nt] = (floatx4){0.f, 0.f, 0.f, 0.f};
#pragma unroll
        for (int kt = 0; kt < 2; ++kt) {
            short8 af = *(const short8*)(hrow1 + kt * 32);
            const short8* bp = (const short8*)WB2 + (size_t)(kt * 4) * 64 + l;
#pragma unroll
            for (int nt = 0; nt < 4; ++nt)
                c2[nt] = __builtin_amdgcn_mfma_f32_16x16x32_bf16(af, bp[nt * 64], c2[nt], 0, 0, 0);
        }
#pragma unroll
        for (int nt = 0; nt < 4; ++nt)
#pragma unroll
            for (int reg = 0; reg < 4; ++reg)
                H[quad * 4 + reg][nt * 16 + lr] = f2bf(silu_f(c2[nt][reg]));
    }

    // ---- phase 3: h2 -> tpw (64 -> 512), fold y0, scatter by slot
    {
        int slotr[4];
        float y0r[4];
#pragma unroll
        for (int reg = 0; reg < 4; ++reg) {
            const int er = e0 + quad * 4 + reg;
            slotr[reg] = pos[er];
            y0r[reg] = edge_attrs[(size_t)er * 4];
        }
        short8 af0 = *(const short8*)(hrow0);
        short8 af1 = *(const short8*)(hrow0 + 32);
        uint2* tpw2 = (uint2*)tpwP;
#pragma unroll
        for (int j2 = 0; j2 < 8; ++j2) {
            floatx4 c3[4];
#pragma unroll
            for (int g = 0; g < 4; ++g) c3[g] = (floatx4){0.f, 0.f, 0.f, 0.f};
#pragma unroll
            for (int g = 0; g < 4; ++g) {
                const short8* b0 = (const short8*)WB3 + (size_t)(g * 8 + j2) * 64 + l;
                const short8* b1 = (const short8*)WB3 + (size_t)(32 + g * 8 + j2) * 64 + l;
                c3[g] = __builtin_amdgcn_mfma_f32_16x16x32_bf16(af0, *b0, c3[g], 0, 0, 0);
                c3[g] = __builtin_amdgcn_mfma_f32_16x16x32_bf16(af1, *b1, c3[g], 0, 0, 0);
            }
            const int u = j2 * 16 + lr;
#pragma unroll
            for (int reg = 0; reg < 4; ++reg) {
                float w1v = c3[0][reg] * y0r[reg];
                float w2v = c3[1][reg];
                float w3v = c3[2][reg] * y0r[reg];
                float w4v = c3[3][reg];
                uint2 p;
                p.x = (unsigned)f2bf(w1v) | ((unsigned)f2bf(w2v) << 16);
                p.y = (unsigned)f2bf(w3v) | ((unsigned)f2bf(w4v) << 16);
                tpw2[(size_t)slotr[reg] * 128 + u] = p;
            }
        }
    }
}

// ---------------------------------------------------------------------------
// Kernel C: per-node gather, unrolled x4 for memory-level parallelism.
// ---------------------------------------------------------------------------
__global__ __launch_bounds__(128) void node_gather(
    const unsigned short* __restrict__ tpwP, const float* __restrict__ metaP,
    const int* __restrict__ offs, const uint2* __restrict__ xq,
    const float* __restrict__ alpha_p, const float* __restrict__ beta_p,
    unsigned short* __restrict__ msgs_b, unsigned short* __restrict__ msgv_b)
{
    const int n = blockIdx.x;
    const int j = threadIdx.x;
    const int s0 = offs[n], s1 = offs[n + 1];
    const uint2* tpw2 = (const uint2*)tpwP;

    float as0 = 0.f, as1 = 0.f;
    float av0x = 0.f, av0y = 0.f, av0z = 0.f;
    float av1x = 0.f, av1y = 0.f, av1z = 0.f;
    float dsum = 0.f;

    int s = s0;
    for (; s + 4 <= s1; s += 4) {
        float4 ma[4]; float dn[4]; uint2 wv[4]; uint2 xv[4];
#pragma unroll
        for (int k = 0; k < 4; ++k) {
            ma[k] = *(const float4*)&metaP[(size_t)(s + k) * 8];
            dn[k] = metaP[(size_t)(s + k) * 8 + 4];
            wv[k] = tpw2[(size_t)(s + k) * 128 + j];
        }
#pragma unroll
        for (int k = 0; k < 4; ++k)
            xv[k] = xq[(size_t)__float_as_int(ma[k].x) * 128 + j];
#pragma unroll
        for (int k = 0; k < 4; ++k) {
            const float y1x = ma[k].y, y1y = ma[k].z, y1z = ma[k].w;
            dsum += dn[k];
            const float w1  = __uint_as_float(wv[k].x << 16);
            const float w2  = __uint_as_float(wv[k].x & 0xffff0000u);
            const float w3  = __uint_as_float(wv[k].y << 16);
            const float w4  = __uint_as_float(wv[k].y & 0xffff0000u);
            const float xs  = __uint_as_float(xv[k].x << 16);
            const float xvx = __uint_as_float(xv[k].x & 0xffff0000u);
            const float xvy = __uint_as_float(xv[k].y << 16);
            const float xvz = __uint_as_float(xv[k].y & 0xffff0000u);
            as0 += w1 * xs;
            as1 += w4 * (xvx * y1x + xvy * y1y + xvz * y1z);
            const float b2 = w2 * xs;
            av0x += b2 * y1x; av0y += b2 * y1y; av0z += b2 * y1z;
            av1x += w3 * xvx; av1y += w3 * xvy; av1z += w3 * xvz;
        }
    }
    for (; s < s1; ++s) {
        const float4 m0 = *(const float4*)&metaP[(size_t)s * 8];
        const float dns = metaP[(size_t)s * 8 + 4];
        const int snd = __float_as_int(m0.x);
        const float y1x = m0.y, y1y = m0.z, y1z = m0.w;
        dsum += dns;
        uint2 wv = tpw2[(size_t)s * 128 + j];
        uint2 xv = xq[(size_t)snd * 128 + j];
        const float w1  = __uint_as_float(wv.x << 16);
        const float w2  = __uint_as_float(wv.x & 0xffff0000u);
        const float w3  = __uint_as_float(wv.y << 16);
        const float w4  = __uint_as_float(wv.y & 0xffff0000u);
        const float xs  = __uint_as_float(xv.x << 16);
        const float xvx = __uint_as_float(xv.x & 0xffff0000u);
        const float xvy = __uint_as_float(xv.y << 16);
        const float xvz = __uint_as_float(xv.y & 0xffff0000u);
        as0 += w1 * xs;
        as1 += w4 * (xvx * y1x + xvy * y1y + xvz * y1z);
        const float b2 = w2 * xs;
        av0x += b2 * y1x; av0y += b2 * y1y; av0z += b2 * y1z;
        av1x += w3 * xvx; av1y += w3 * xvy; av1z += w3 * xvz;
    }

    const float invden = 1.f / (dsum * (*beta_p) + (*alpha_p));

    msgs_b[(size_t)n * 256 + j]       = f2bf(as0 * invden);
    msgs_b[(size_t)n * 256 + 128 + j] = f2bf(as1 * invden);
    msgv_b[((size_t)0 * NN + n) * 256 + j]       = f2bf(av0x * invden);
    msgv_b[((size_t)0 * NN + n) * 256 + 128 + j] = f2bf(av1x * invden);
    msgv_b[((size_t)1 * NN + n) * 256 + j]       = f2bf(av0y * invden);
    msgv_b[((size_t)1 * NN + n) * 256 + 128 + j] = f2bf(av1y * invden);
    msgv_b[((size_t)2 * NN + n) * 256 + j]       = f2bf(av0z * invden);
    msgv_b[((size_t)2 * NN + n) * 256 + 128 + j] = f2bf(av1z * invden);
}

// ---------------------------------------------------------------------------
// Kernel D: FUSED post epilogue (round-7 verified version, unchanged).
// ---------------------------------------------------------------------------
#define DNP 16
__global__ __launch_bounds__(256) void post_fused(
    const unsigned short* __restrict__ msgs_b, const unsigned short* __restrict__ us_b,
    const unsigned short* __restrict__ msgv_b, const unsigned short* __restrict__ uv_b,
    const unsigned short* __restrict__ WPs, const unsigned short* __restrict__ WPv,
    const unsigned short* __restrict__ W2ss, const unsigned short* __restrict__ W2vs,
    float* __restrict__ out)
{
    __shared__ __align__(16) unsigned short osb[DNP][136];
    __shared__ __align__(16) unsigned short ovb[3][DNP][136];
    __shared__ float gateL[DNP][128];

    const int t = threadIdx.x;
    const int l = t & 63, w = t >> 6;         // 4 waves
    const int quad = l >> 4, lr = l & 15;
    const int n0 = blockIdx.x * DNP;
    const int nh = w;                         // 0..3 N-quarter
    const int n = n0 + lr;                    // this lane's A-row node

    const int cLo = (nh * 6) >> 3;
    const int cHi = (nh * 6 + 5) >> 3;

    const unsigned short* sRow  = msgs_b + (size_t)n * 256;
    const unsigned short* uRow  = us_b   + (size_t)n * 128;
    const unsigned short* vRowL = msgv_b + ((size_t)cLo * NN + n) * 256;
    const unsigned short* uRowL = uv_b   + ((size_t)cLo * NN + n) * 128;
    const unsigned short* vRowH = msgv_b + ((size_t)cHi * NN + n) * 256;
    const unsigned short* uRowH = uv_b   + ((size_t)cHi * NN + n) * 128;

    // ---- first layer: K=384 (12 kt), s: 4 N-tiles, v: 6 N-tiles
    floatx4 accS[4], accV[6];
#pragma unroll
    for (int i = 0; i < 4; ++i) accS[i] = (floatx4){0.f, 0.f, 0.f, 0.f};
#pragma unroll
    for (int i = 0; i < 6; ++i) accV[i] = (floatx4){0.f, 0.f, 0.f, 0.f};

#pragma unroll
    for (int kt = 0; kt < 12; ++kt) {
        const int col = kt * 32 + quad * 8;
        short8 aS = (col < 256) ? *(const short8*)(sRow + col)
                                : *(const short8*)(uRow + col - 256);
        short8 aV0 = (col < 256) ? *(const short8*)(vRowL + col)
                                 : *(const short8*)(uRowL + col - 256);
        short8 aV1;
        if (cHi != cLo)
            aV1 = (col < 256) ? *(const short8*)(vRowH + col)
                              : *(const short8*)(uRowH + col - 256);
        else
            aV1 = aV0;

        const short8* bpS = (const short8*)WPs + (size_t)(kt * 16 + nh * 4) * 64 + l;
#pragma unroll
        for (int i = 0; i < 4; ++i)
            accS[i] = __builtin_amdgcn_mfma_f32_16x16x32_bf16(aS, bpS[i * 64], accS[i], 0, 0, 0);
#pragma unroll
        for (int i = 0; i < 6; ++i) {
            const int vt = nh * 6 + i;
            const short8* bpV = (const short8*)WPv + (size_t)(kt * 8 + (vt & 7)) * 64 + l;
            short8 a = ((vt >> 3) == cLo) ? aV0 : aV1;
            accV[i] = __builtin_amdgcn_mfma_f32_16x16x32_bf16(a, *bpV, accV[i], 0, 0, 0);
        }
    }

    // ---- s outputs: tiles 0..7 -> silu -> osb; 8..15 -> sigmoid -> gateL
#pragma unroll
    for (int i = 0; i < 4; ++i) {
        const int tile = nh * 4 + i;
#pragma unroll
        for (int reg = 0; reg < 4; ++reg) {
            const int row = quad * 4 + reg;
            const float v = accS[i][reg];
            if (tile < 8) osb[row][tile * 16 + lr] = f2bf(silu_f(v));
            else          gateL[row][(tile - 8) * 16 + lr] = sigm_f(v);
        }
    }
    __syncthreads();

    // ---- gate the v accumulators -> ovb
#pragma unroll
    for (int i = 0; i < 6; ++i) {
        const int vt = nh * 6 + i;
        const int c = vt >> 3;
        const int colv = (vt & 7) * 16 + lr;
#pragma unroll
        for (int reg = 0; reg < 4; ++reg) {
            const int row = quad * 4 + reg;
            ovb[c][row][colv] = f2bf(accV[i][reg] * gateL[row][colv]);
        }
    }
    __syncthreads();

    // ---- second layer: K=128 (4 kt); s: 2 N-tiles, v: 6 N-tiles
    floatx4 c2s[2], c2v[6];
#pragma unroll
    for (int i = 0; i < 2; ++i) c2s[i] = (floatx4){0.f, 0.f, 0.f, 0.f};
#pragma unroll
    for (int i = 0; i < 6; ++i) c2v[i] = (floatx4){0.f, 0.f, 0.f, 0.f};

    const unsigned short* arowS = &osb[lr][quad * 8];
#pragma unroll
    for (int kt = 0; kt < 4; ++kt) {
        short8 afS = *(const short8*)(arowS + kt * 32);
        const short8* bpS = (const short8*)W2ss + (size_t)(kt * 8 + nh * 2) * 64 + l;
#pragma unroll
        for (int i = 0; i < 2; ++i)
            c2s[i] = __builtin_amdgcn_mfma_f32_16x16x32_bf16(afS, bpS[i * 64], c2s[i], 0, 0, 0);
#pragma unroll
        for (int i = 0; i < 6; ++i) {
            const int vt = nh * 6 + i;
            const int c = vt >> 3;
            short8 afV = *(const short8*)(&ovb[c][lr][quad * 8] + kt * 32);
            const short8* bpV = (const short8*)W2vs + (size_t)(kt * 8 + (vt & 7)) * 64 + l;
            c2v[i] = __builtin_amdgcn_mfma_f32_16x16x32_bf16(afV, *bpV, c2v[i], 0, 0, 0);
        }
    }

    // ---- epilogue
#pragma unroll
    for (int i = 0; i < 2; ++i) {
        const int col = (nh * 2 + i) * 16 + lr;
#pragma unroll
        for (int reg = 0; reg < 4; ++reg)
            out[(size_t)(n0 + quad * 4 + reg) * 512 + col * 4] = c2s[i][reg];
    }
#pragma unroll
    for (int i = 0; i < 6; ++i) {
        const int vt = nh * 6 + i;
        const int c = vt >> 3;
        const int col = (vt & 7) * 16 + lr;
#pragma unroll
        for (int reg = 0; reg < 4; ++reg)
            out[(size_t)(n0 + quad * 4 + reg) * 512 + col * 4 + 1 + c] = c2v[i][reg];
    }
}

// ---------------------------------------------------------------------------
extern "C" void kernel_launch(void* const* d_in, const int* in_sizes, int n_in,
                              void* d_out, int out_size, void* d_ws, size_t ws_size,
                              hipStream_t stream)
{
    const float* node_attrs = (const float*)d_in[0];
    const float* node_feats = (const float*)d_in[1];
    const float* edge_attrs = (const float*)d_in[2];
    const float* edge_feats = (const float*)d_in[3];
    const int*   edge_index = (const int*)d_in[4];
    const float* W_skip_s = (const float*)d_in[5];
    const float* W_skip_v = (const float*)d_in[6];
    const float* W_up_s   = (const float*)d_in[7];
    const float* W_up_v   = (const float*)d_in[8];
    const float* W_src    = (const float*)d_in[9];
    const float* W_tgt    = (const float*)d_in[10];
    const float* W_r0     = (const float*)d_in[11];
    const float* W_r1     = (const float*)d_in[12];
    const float* W_r2     = (const float*)d_in[13];
    const float* W_r3     = (const float*)d_in[14];
    const float* W_d0     = (const float*)d_in[15];
    const float* W_d1     = (const float*)d_in[16];
    const float* W1_s     = (const float*)d_in[17];
    const float* W1_v     = (const float*)d_in[18];
    const float* Wres_s   = (const float*)d_in[19];
    const float* Wres_v   = (const float*)d_in[20];
    const float* W2_s     = (const float*)d_in[21];
    const float* W2_v     = (const float*)d_in[22];
    const float* alpha_p  = (const float*)d_in[23];
    const float* beta_p   = (const float*)d_in[24];

    float* out = (float*)d_out;
    float* sc_out = out + (size_t)NN * 512;
    float* ws = (float*)d_ws;

    uint2* xq = (uint2*)(ws + WS_XQ);
    unsigned short* us_b  = (unsigned short*)(ws + WS_USB);
    unsigned short* uv_b  = (unsigned short*)(ws + WS_UVB);
    unsigned short* srcEb = (unsigned short*)(ws + WS_SRC);
    unsigned short* tgtEb = (unsigned short*)(ws + WS_TGT);
    unsigned short* msgs_b = (unsigned short*)(ws + WS_MSGSB);
    unsigned short* msgv_b = (unsigned short*)(ws + WS_MSGVB);
    int*   counts = (int*)(ws + WS_COUNTS);
    int*   offs   = (int*)(ws + WS_OFFS);
    int*   cursor = (int*)(ws + WS_CURSOR);
    int*   pos    = (int*)(ws + WS_POS);
    float* metaP  = ws + WS_META;
    unsigned short* tpwP = (unsigned short*)(ws + WS_TPW);
    unsigned short* WBall = (unsigned short*)(ws + WS_WB);
    unsigned short* WB0 = WBall;
    unsigned short* WB1 = WB0 + (size_t)72 * 512;
    unsigned short* WB2 = WB1 + (size_t)8 * 512;
    unsigned short* WB3 = WB2 + (size_t)8 * 512;
    unsigned short* WPall = (unsigned short*)(ws + WS_WP);
    unsigned short* WPs  = WPall;
    unsigned short* WPv  = WPs + (size_t)192 * 512;
    unsigned short* W2ss = WPv + (size_t)96 * 512;
    unsigned short* W2vs = W2ss + (size_t)32 * 512;
    unsigned short* WN   = (unsigned short*)(ws + WS_WN);

    hipMemsetAsync(counts, 0, (size_t)NN * sizeof(int), stream);

    csr_count<<<EE / 256, 256, 0, stream>>>(edge_index, counts);
    csr_scan<<<1, 1024, 0, stream>>>(counts, offs, cursor);
    csr_scatter<<<EE / 256, 256, 0, stream>>>(edge_index, cursor, pos);

    swizzle_weights<<<38, 256, 0, stream>>>(W_r0, W_d0, W_r1, W_r2, W_r3, WBall);
    swizzle_post<<<88, 256, 0, stream>>>(W1_s, W1_v, Wres_s, Wres_v, W2_s, W2_v, WPall);
    swizzle_node<<<36, 256, 0, stream>>>(W_skip_s, W_up_s, W_skip_v, W_up_v,
                                         W_src, W_tgt, WN);

    node_pre_mfma<<<NN / PNB, 256, 0, stream>>>(
        node_attrs, node_feats, WN, sc_out, xq, us_b, uv_b, srcEb, tgtEb);

    edge_mlp<<<EE / EBK, 256, 0, stream>>>(
        edge_attrs, edge_feats, edge_index, srcEb, tgtEb,
        WB0, WB1, WB2, WB3, W_d1, pos, tpwP, metaP);

    node_gather<<<NN, 128, 0, stream>>>(
        tpwP, metaP, offs, xq, alpha_p, beta_p, msgs_b, msgv_b);

    post_fused<<<NN / DNP, 256, 0, stream>>>(
        msgs_b, us_b, msgv_b, uv_b, WPs, WPv, W2ss, W2vs, out);
}

// Round 11
// 298.558 us; speedup vs baseline: 3.3136x; 1.0113x over previous
//
#include <hip/hip_runtime.h>

// Problem constants (fixed by the reference)
#define NN 8192
#define EE 131072
#define MUL 128
#define AA 10
#define RB 8
#define DEF 264          // RB + 2*MUL
#define INV_SQRT3 0.5773502691896258f
#define INV_SQRT128 0.08838834764831845f
#define INV_SQRT10 0.31622776601683794f
#define INV_SQRT264 0.06154574548966636f

typedef __attribute__((ext_vector_type(8))) short short8;
typedef __attribute__((ext_vector_type(4))) float floatx4;

// ---------------------------------------------------------------------------
// Workspace layout (float offsets). ~182 MB total.
// ---------------------------------------------------------------------------
#define WS_XQ     ((size_t)0)                       // N*128 uint2 {us,uvx,uvy,uvz} bf16
#define WS_USB    (WS_XQ    + (size_t)NN*256)       // N*128 bf16
#define WS_UVB    (WS_USB   + (size_t)NN*64)        // 3*N*128 bf16 channel-major
#define WS_SRC    (WS_UVB   + (size_t)NN*192)       // N*128 bf16
#define WS_TGT    (WS_SRC   + (size_t)NN*64)        // N*128 bf16
#define WS_MSGSB  (WS_TGT   + (size_t)NN*64)        // N*256 bf16 (invden applied)
#define WS_MSGVB  (WS_MSGSB + (size_t)NN*128)       // 3*N*256 bf16 channel-major
#define WS_GATE   (WS_MSGVB + (size_t)NN*384)       // N*128 f32 (unused since post fusion)
#define WS_COUNTS (WS_GATE  + (size_t)NN*128)       // N ints
#define WS_OFFS   (WS_COUNTS+ (size_t)NN)           // N+4 ints
#define WS_CURSOR (WS_OFFS  + (size_t)(NN+4))       // N ints
#define WS_POS    (WS_CURSOR+ (size_t)NN)           // E ints
#define WS_META   (WS_POS   + (size_t)EE)           // E*8 f32
#define WS_TPW    (WS_META  + (size_t)EE*8)         // E*512 bf16, [slot][u][4] interleaved
#define WS_WB     (WS_TPW   + (size_t)EE*256)       // edge wfrags 152*512 bf16
#define WS_WP     (WS_WB    + (size_t)152*256)      // post wfrags 352*512 bf16
#define WS_WN     (WS_WP    + (size_t)352*256)      // node wfrags 144*512 bf16

__device__ __forceinline__ float silu_f(float x) {
    return x * __builtin_amdgcn_rcpf(1.f + __expf(-x));
}
__device__ __forceinline__ float sigm_f(float x) {
    return __builtin_amdgcn_rcpf(1.f + __expf(-x));
}

__device__ __forceinline__ unsigned short f2bf(float x) {
    union { float f; unsigned u; } uf; uf.f = x;
    unsigned r = uf.u + 0x7FFFu + ((uf.u >> 16) & 1u);   // RNE
    return (unsigned short)(r >> 16);
}

// ---------------------------------------------------------------------------
// CSR build: count -> scan -> scatter   (receiver-sorted edge slots)
// ---------------------------------------------------------------------------
__global__ __launch_bounds__(256) void csr_count(
    const int* __restrict__ edge_index, int* __restrict__ counts)
{
    int e = blockIdx.x * 256 + threadIdx.x;
    atomicAdd(&counts[edge_index[EE + e]], 1);
}

__global__ __launch_bounds__(1024) void csr_scan(
    const int* __restrict__ counts, int* __restrict__ offs, int* __restrict__ cursor)
{
    __shared__ int sums[1024];
    const int t = threadIdx.x;
    int local[8];
    int s = 0;
#pragma unroll
    for (int k = 0; k < 8; ++k) { local[k] = s; s += counts[t * 8 + k]; }
    sums[t] = s;
    __syncthreads();
    for (int d = 1; d < 1024; d <<= 1) {
        int v = (t >= d) ? sums[t - d] : 0;
        __syncthreads();
        sums[t] += v;
        __syncthreads();
    }
    int base = (t > 0) ? sums[t - 1] : 0;
#pragma unroll
    for (int k = 0; k < 8; ++k) {
        offs[t * 8 + k] = base + local[k];
        cursor[t * 8 + k] = base + local[k];
    }
    if (t == 1023) offs[8192] = sums[1023];
}

__global__ __launch_bounds__(256) void csr_scatter(
    const int* __restrict__ edge_index, int* __restrict__ cursor, int* __restrict__ pos)
{
    int e = blockIdx.x * 256 + threadIdx.x;
    pos[e] = atomicAdd(&cursor[edge_index[EE + e]], 1);
}

// ---------------------------------------------------------------------------
// MERGED weight pre-swizzle (round 18): the three independent swizzle kernels
// fused into one dispatch. Blocks [0,38): edge weights; [38,126): post
// weights; [126,162): node weights. Bodies identical to the verified
// separate kernels.
// ---------------------------------------------------------------------------
__global__ __launch_bounds__(256) void swizzle_all(
    const float* __restrict__ Wr0, const float* __restrict__ Wd0,
    const float* __restrict__ Wr1, const float* __restrict__ Wr2,
    const float* __restrict__ Wr3,
    const float* __restrict__ W1s, const float* __restrict__ W1v,
    const float* __restrict__ Wrs, const float* __restrict__ Wrv,
    const float* __restrict__ W2s, const float* __restrict__ W2v,
    const float* __restrict__ Wss, const float* __restrict__ Wus,
    const float* __restrict__ Wsv, const float* __restrict__ Wuv,
    const float* __restrict__ Wsrc, const float* __restrict__ Wtgt,
    unsigned short* __restrict__ WBall, unsigned short* __restrict__ WPall,
    unsigned short* __restrict__ WN)
{
    const int b = blockIdx.x;
    unsigned short o[8];

    if (b < 38) {
        // ---- edge weights (WBall), 152 frags
        int fid = b * 256 + threadIdx.x;
        int lane = fid & 63;
        int frag = fid >> 6;
        int k0 = (lane >> 4) * 8;
        int n0 = lane & 15;

        if (frag < 72) {
            int kt = frag >> 3, nt = frag & 7;
            int n = nt * 16 + n0;
#pragma unroll
            for (int j = 0; j < 8; ++j) {
                int k = kt * 32 + k0 + j;
                float v = 0.f;
                if (k < 264) v = ((n < 64) ? Wr0[k * 64 + n] : Wd0[k * 64 + (n - 64)]) * INV_SQRT264;
                o[j] = f2bf(v);
            }
        } else if (frag < 80) {
            int fl = frag - 72;
            int kt = fl >> 2, nt = fl & 3;
            int n = nt * 16 + n0;
#pragma unroll
            for (int j = 0; j < 8; ++j)
                o[j] = f2bf(Wr1[(kt * 32 + k0 + j) * 64 + n] * 0.125f);
        } else if (frag < 88) {
            int fl = frag - 80;
            int kt = fl >> 2, nt = fl & 3;
            int n = nt * 16 + n0;
#pragma unroll
            for (int j = 0; j < 8; ++j)
                o[j] = f2bf(Wr2[(kt * 32 + k0 + j) * 64 + n] * 0.125f);
        } else {
            int fl = frag - 88;
            int kt = fl >> 5, nt = fl & 31;
            int n = nt * 16 + n0;
            int q = n >> 6;
            float sc = (q < 2) ? 0.125f : 0.125f * INV_SQRT3;
#pragma unroll
            for (int j = 0; j < 8; ++j)
                o[j] = f2bf(Wr3[(kt * 32 + k0 + j) * 512 + n] * sc);
        }
        uint4 pk;
        pk.x = (unsigned)o[0] | ((unsigned)o[1] << 16);
        pk.y = (unsigned)o[2] | ((unsigned)o[3] << 16);
        pk.z = (unsigned)o[4] | ((unsigned)o[5] << 16);
        pk.w = (unsigned)o[6] | ((unsigned)o[7] << 16);
        *(uint4*)(WBall + (size_t)fid * 8) = pk;
    } else if (b < 126) {
        // ---- post weights (WPall), 352 frags
        int fid = (b - 38) * 256 + threadIdx.x;
        int lane = fid & 63;
        int frag = fid >> 6;
        int k0 = (lane >> 4) * 8;
        int n0 = lane & 15;

        if (frag < 192) {
            int kt = frag >> 4, nt = frag & 15;
            int n = nt * 16 + n0;
#pragma unroll
            for (int j = 0; j < 8; ++j) {
                int k = kt * 32 + k0 + j;
                float v = (k < 256) ? W1s[k * 256 + n] * 0.0625f
                                    : Wrs[(k - 256) * 256 + n] * INV_SQRT128;
                o[j] = f2bf(v);
            }
        } else if (frag < 288) {
            int fl = frag - 192;
            int kt = fl >> 3, nt = fl & 7;
            int n = nt * 16 + n0;
#pragma unroll
            for (int j = 0; j < 8; ++j) {
                int k = kt * 32 + k0 + j;
                float v = (k < 256) ? W1v[k * 128 + n] * 0.0625f
                                    : Wrv[(k - 256) * 128 + n] * INV_SQRT128;
                o[j] = f2bf(v);
            }
        } else if (frag < 320) {
            int fl = frag - 288;
            int kt = fl >> 3, nt = fl & 7;
            int n = nt * 16 + n0;
#pragma unroll
            for (int j = 0; j < 8; ++j)
                o[j] = f2bf(W2s[(kt * 32 + k0 + j) * 128 + n] * INV_SQRT128);
        } else {
            int fl = frag - 320;
            int kt = fl >> 3, nt = fl & 7;
            int n = nt * 16 + n0;
#pragma unroll
            for (int j = 0; j < 8; ++j)
                o[j] = f2bf(W2v[(kt * 32 + k0 + j) * 128 + n] * INV_SQRT128);
        }
        uint4 pk;
        pk.x = (unsigned)o[0] | ((unsigned)o[1] << 16);
        pk.y = (unsigned)o[2] | ((unsigned)o[3] << 16);
        pk.z = (unsigned)o[4] | ((unsigned)o[5] << 16);
        pk.w = (unsigned)o[6] | ((unsigned)o[7] << 16);
        *(uint4*)(WPall + (size_t)fid * 8) = pk;
    } else {
        // ---- node weights (WN), 144 frags
        int fid = (b - 126) * 256 + threadIdx.x;
        int lane = fid & 63;
        int frag = fid >> 6;
        int k0 = (lane >> 4) * 8;
        int m0 = lane & 15;

        if (frag < 128) {
            int g = frag >> 5;
            int fl = frag & 31;
            int kt = fl >> 3, mt = fl & 7;
            const float* W = (g == 0) ? Wss : (g == 1) ? Wus : (g == 2) ? Wsv : Wuv;
            int m = mt * 16 + m0;
#pragma unroll
            for (int j = 0; j < 8; ++j)
                o[j] = f2bf(W[(kt * 32 + k0 + j) * 128 + m] * INV_SQRT128);
        } else {
            int g = (frag - 128) >> 3;
            int mt = frag & 7;
            const float* W = g ? Wtgt : Wsrc;
            int m = mt * 16 + m0;
#pragma unroll
            for (int j = 0; j < 8; ++j) {
                int k = k0 + j;
                o[j] = f2bf((k < AA) ? W[k * 128 + m] * INV_SQRT10 : 0.f);
            }
        }
        uint4 pk;
        pk.x = (unsigned)o[0] | ((unsigned)o[1] << 16);
        pk.y = (unsigned)o[2] | ((unsigned)o[3] << 16);
        pk.z = (unsigned)o[4] | ((unsigned)o[5] << 16);
        pk.w = (unsigned)o[6] | ((unsigned)o[7] << 16);
        *(uint4*)(WN + (size_t)fid * 8) = pk;
    }
}

// ---------------------------------------------------------------------------
// Kernel A: per-node precompute on MFMA (unchanged).
// ---------------------------------------------------------------------------
#define PNB 16
__global__ __launch_bounds__(256) void node_pre_mfma(
    const float* __restrict__ node_attrs, const float* __restrict__ node_feats,
    const unsigned short* __restrict__ WN,
    float* __restrict__ sc_out, uint2* __restrict__ xq,
    unsigned short* __restrict__ us_b, unsigned short* __restrict__ uv_b,
    unsigned short* __restrict__ srcEb, unsigned short* __restrict__ tgtEb)
{
    __shared__ __align__(16) unsigned short Xs[PNB][136];
    __shared__ __align__(16) unsigned short Xv[3][PNB][136];
    __shared__ __align__(16) unsigned short Xa[PNB][40];
    const int t = threadIdx.x;
    const int l = t & 63, w = t >> 6;
    const int quad = l >> 4, lr = l & 15;
    const int n0 = blockIdx.x * PNB;

    // ---- stage node_feats (f32 -> bf16): thread (r=t>>4, m=t&15)
    {
        const int r = t >> 4, m = t & 15;
        const float* src = node_feats + (size_t)(n0 + r) * 512;
        float4 s0 = *(const float4*)(src + 8 * m);
        float4 s1 = *(const float4*)(src + 8 * m + 4);
        uint4 sp;
        sp.x = (unsigned)f2bf(s0.x) | ((unsigned)f2bf(s0.y) << 16);
        sp.y = (unsigned)f2bf(s0.z) | ((unsigned)f2bf(s0.w) << 16);
        sp.z = (unsigned)f2bf(s1.x) | ((unsigned)f2bf(s1.y) << 16);
        sp.w = (unsigned)f2bf(s1.z) | ((unsigned)f2bf(s1.w) << 16);
        *(uint4*)&Xs[r][8 * m] = sp;

        float4 q[6];
#pragma unroll
        for (int jj = 0; jj < 6; ++jj)
            q[jj] = *(const float4*)(src + 128 + 24 * m + 4 * jj);
        const float* qf = &q[0].x;
        unsigned short vb[3][8];
#pragma unroll
        for (int u = 0; u < 8; ++u) {
#pragma unroll
            for (int c = 0; c < 3; ++c)
                vb[c][u] = f2bf(qf[u * 3 + c]);
        }
#pragma unroll
        for (int c = 0; c < 3; ++c) {
            uint4 vp;
            vp.x = (unsigned)vb[c][0] | ((unsigned)vb[c][1] << 16);
            vp.y = (unsigned)vb[c][2] | ((unsigned)vb[c][3] << 16);
            vp.z = (unsigned)vb[c][4] | ((unsigned)vb[c][5] << 16);
            vp.w = (unsigned)vb[c][6] | ((unsigned)vb[c][7] << 16);
            *(uint4*)&Xv[c][r][8 * m] = vp;
        }
    }
    // ---- stage attrs (padded K=32)
    for (int idx = t; idx < PNB * 32; idx += 256) {
        int r = idx >> 5, k = idx & 31;
        float v = (k < AA) ? node_attrs[(size_t)(n0 + r) * AA + k] : 0.f;
        Xa[r][k] = f2bf(v);
    }
    __syncthreads();

    const short8* WNf = (const short8*)WN;
    const int n = n0 + lr;

#pragma unroll
    for (int mi = 0; mi < 2; ++mi) {
        const int mt = w * 2 + mi;
        const int j0 = mt * 16 + quad * 4;

        // attr GEMM (K=32): srcE / tgtE
        floatx4 cSrc = (floatx4){0.f, 0.f, 0.f, 0.f};
        floatx4 cTgt = (floatx4){0.f, 0.f, 0.f, 0.f};
        {
            short8 ba = *(const short8*)&Xa[lr][quad * 8];
            cSrc = __builtin_amdgcn_mfma_f32_16x16x32_bf16(WNf[(size_t)(128 + mt) * 64 + l], ba, cSrc, 0, 0, 0);
            cTgt = __builtin_amdgcn_mfma_f32_16x16x32_bf16(WNf[(size_t)(136 + mt) * 64 + l], ba, cTgt, 0, 0, 0);
        }
        // s GEMMs (K=128): sc_s / us
        floatx4 cS = (floatx4){0.f, 0.f, 0.f, 0.f};
        floatx4 cU = (floatx4){0.f, 0.f, 0.f, 0.f};
#pragma unroll
        for (int kt = 0; kt < 4; ++kt) {
            short8 bs = *(const short8*)&Xs[lr][kt * 32 + quad * 8];
            cS = __builtin_amdgcn_mfma_f32_16x16x32_bf16(WNf[(size_t)(kt * 8 + mt) * 64 + l], bs, cS, 0, 0, 0);
            cU = __builtin_amdgcn_mfma_f32_16x16x32_bf16(WNf[(size_t)(32 + kt * 8 + mt) * 64 + l], bs, cU, 0, 0, 0);
        }
        // v GEMMs (K=128 x 3 channels): sc_v / uv
        floatx4 cSV[3], cUV[3];
#pragma unroll
        for (int c = 0; c < 3; ++c) {
            cSV[c] = (floatx4){0.f, 0.f, 0.f, 0.f};
            cUV[c] = (floatx4){0.f, 0.f, 0.f, 0.f};
#pragma unroll
            for (int kt = 0; kt < 4; ++kt) {
                short8 bv = *(const short8*)&Xv[c][lr][kt * 32 + quad * 8];
                cSV[c] = __builtin_amdgcn_mfma_f32_16x16x32_bf16(WNf[(size_t)(64 + kt * 8 + mt) * 64 + l], bv, cSV[c], 0, 0, 0);
                cUV[c] = __builtin_amdgcn_mfma_f32_16x16x32_bf16(WNf[(size_t)(96 + kt * 8 + mt) * 64 + l], bv, cUV[c], 0, 0, 0);
            }
        }

        // ---- epilogue: packed stores (node n, outputs j0..j0+3)
        {
            float4 o;
            o.x = cS[0]; o.y = cS[1]; o.z = cS[2]; o.w = cS[3];
            *(float4*)(sc_out + (size_t)n * 512 + j0) = o;
        }
        {
            float vv[12];
#pragma unroll
            for (int reg = 0; reg < 4; ++reg)
#pragma unroll
                for (int c = 0; c < 3; ++c) vv[reg * 3 + c] = cSV[c][reg];
            float* dst = sc_out + (size_t)n * 512 + 128 + j0 * 3;
#pragma unroll
            for (int qq = 0; qq < 3; ++qq) {
                float4 o;
                o.x = vv[qq * 4]; o.y = vv[qq * 4 + 1]; o.z = vv[qq * 4 + 2]; o.w = vv[qq * 4 + 3];
                *(float4*)(dst + qq * 4) = o;
            }
        }
        unsigned short ub[4], vxb[4], vyb[4], vzb[4];
#pragma unroll
        for (int reg = 0; reg < 4; ++reg) {
            ub[reg] = f2bf(cU[reg]);
            vxb[reg] = f2bf(cUV[0][reg]);
            vyb[reg] = f2bf(cUV[1][reg]);
            vzb[reg] = f2bf(cUV[2][reg]);
        }
        {
            uint2 p;
            p.x = (unsigned)ub[0] | ((unsigned)ub[1] << 16);
            p.y = (unsigned)ub[2] | ((unsigned)ub[3] << 16);
            *(uint2*)(us_b + (size_t)n * 128 + j0) = p;
        }
        {
            uint2 p;
            p.x = (unsigned)vxb[0] | ((unsigned)vxb[1] << 16);
            p.y = (unsigned)vxb[2] | ((unsigned)vxb[3] << 16);
            *(uint2*)(uv_b + ((size_t)0 * NN + n) * 128 + j0) = p;
            p.x = (unsigned)vyb[0] | ((unsigned)vyb[1] << 16);
            p.y = (unsigned)vyb[2] | ((unsigned)vyb[3] << 16);
            *(uint2*)(uv_b + ((size_t)1 * NN + n) * 128 + j0) = p;
            p.x = (unsigned)vzb[0] | ((unsigned)vzb[1] << 16);
            p.y = (unsigned)vzb[2] | ((unsigned)vzb[3] << 16);
            *(uint2*)(uv_b + ((size_t)2 * NN + n) * 128 + j0) = p;
        }
        {
            uint4 x0, x1;
            x0.x = (unsigned)ub[0] | ((unsigned)vxb[0] << 16);
            x0.y = (unsigned)vyb[0] | ((unsigned)vzb[0] << 16);
            x0.z = (unsigned)ub[1] | ((unsigned)vxb[1] << 16);
            x0.w = (unsigned)vyb[1] | ((unsigned)vzb[1] << 16);
            x1.x = (unsigned)ub[2] | ((unsigned)vxb[2] << 16);
            x1.y = (unsigned)vyb[2] | ((unsigned)vzb[2] << 16);
            x1.z = (unsigned)ub[3] | ((unsigned)vxb[3] << 16);
            x1.w = (unsigned)vyb[3] | ((unsigned)vzb[3] << 16);
            uint4* xp = (uint4*)(xq + (size_t)n * 128 + j0);
            xp[0] = x0; xp[1] = x1;
        }
        {
            uint2 p;
            p.x = (unsigned)f2bf(cSrc[0]) | ((unsigned)f2bf(cSrc[1]) << 16);
            p.y = (unsigned)f2bf(cSrc[2]) | ((unsigned)f2bf(cSrc[3]) << 16);
            *(uint2*)(srcEb + (size_t)n * 128 + j0) = p;
            p.x = (unsigned)f2bf(cTgt[0]) | ((unsigned)f2bf(cTgt[1]) << 16);
            p.y = (unsigned)f2bf(cTgt[2]) | ((unsigned)f2bf(cTgt[3]) << 16);
            *(uint2*)(tgtEb + (size_t)n * 128 + j0) = p;
        }
    }
}

// ---------------------------------------------------------------------------
// Kernel B: per-edge MLP on MFMA (round-7 verified: (256,4), phase 3 incl).
// ---------------------------------------------------------------------------
#define EBK 64
#define H1OFF 80
#define HLD 152   // LDS row stride (u16): 304B = odd multiple of 16B
__global__ __launch_bounds__(256, 4) void edge_mlp(
    const float* __restrict__ edge_attrs, const float* __restrict__ edge_feats,
    const int* __restrict__ edge_index,
    const unsigned short* __restrict__ srcEb, const unsigned short* __restrict__ tgtEb,
    const unsigned short* __restrict__ WB0, const unsigned short* __restrict__ WB1,
    const unsigned short* __restrict__ WB2, const unsigned short* __restrict__ WB3,
    const float* __restrict__ Wd1, const int* __restrict__ pos,
    unsigned short* __restrict__ tpwP, float* __restrict__ metaP)
{
    __shared__ __align__(16) unsigned short Hb[4][16][HLD];

    const int t = threadIdx.x;
    const int l = t & 63;
    const int w = t >> 6;
    const int quad = l >> 4;
    const int lr = l & 15;
    const int e0 = blockIdx.x * EBK + w * 16;   // this wave's 16 edges

    // Row-edge for this lane's A-fragments (A row = lane&15).
    const int eA = e0 + lr;
    const int sndA = edge_index[eA];
    const int rcvA = edge_index[EE + eA];
    const unsigned short* spp = srcEb + (size_t)sndA * 128;
    const unsigned short* tpp = tgtEb + (size_t)rcvA * 128;

    // meta m0: one lane per edge (quad 0 covers the wave's 16 edges)
    if (quad == 0) {
        float4 ya = *(const float4*)(edge_attrs + (size_t)eA * 4);
        float4 m;
        m.x = __int_as_float(sndA); m.y = ya.y; m.z = ya.z; m.w = ya.w;
        *(float4*)(metaP + (size_t)pos[eA] * 8) = m;
    }

    // ---- load all 9 A-fragments for ef row eA (cols kt*32 + quad*8 .. +8)
    short8 afr[9];
    {
        const int cq = quad * 8;
        if (quad == 0) {
            float4 f0 = *(const float4*)(edge_feats + (size_t)eA * 8);
            float4 f1 = *(const float4*)(edge_feats + (size_t)eA * 8 + 4);
            union { short8 v; unsigned u[4]; } pk;
            pk.u[0] = (unsigned)f2bf(f0.x) | ((unsigned)f2bf(f0.y) << 16);
            pk.u[1] = (unsigned)f2bf(f0.z) | ((unsigned)f2bf(f0.w) << 16);
            pk.u[2] = (unsigned)f2bf(f1.x) | ((unsigned)f2bf(f1.y) << 16);
            pk.u[3] = (unsigned)f2bf(f1.z) | ((unsigned)f2bf(f1.w) << 16);
            afr[0] = pk.v;
        } else {
            afr[0] = *(const short8*)(spp + (cq - 8));
        }
#pragma unroll
        for (int kt = 1; kt < 9; ++kt) {
            const int c = kt * 32 + cq;
            if (c < 136) {
                afr[kt] = *(const short8*)(spp + (c - 8));
            } else if (c < 264) {
                afr[kt] = *(const short8*)(tpp + (c - 136));
            } else {
                short8 z = {0, 0, 0, 0, 0, 0, 0, 0};
                afr[kt] = z;
            }
        }
    }

    unsigned short (*H)[HLD] = Hb[w];

    // ---- phase 0: first layer, r-path AND d-path in ONE K=288 pass
    {
        floatx4 c0[8];
#pragma unroll
        for (int nt = 0; nt < 8; ++nt) c0[nt] = (floatx4){0.f, 0.f, 0.f, 0.f};
#pragma unroll
        for (int kt = 0; kt < 9; ++kt) {
            const short8* bp = (const short8*)WB0 + (size_t)(kt * 8) * 64 + l;
#pragma unroll
            for (int nt = 0; nt < 8; ++nt)
                c0[nt] = __builtin_amdgcn_mfma_f32_16x16x32_bf16(afr[kt], bp[nt * 64], c0[nt], 0, 0, 0);
        }

        // r-path (nt 0..3): silu -> LDS h0
#pragma unroll
        for (int nt = 0; nt < 4; ++nt)
#pragma unroll
            for (int reg = 0; reg < 4; ++reg)
                H[quad * 4 + reg][nt * 16 + lr] = f2bf(silu_f(c0[nt][reg]));

        // d-path (nt 4..7): dot(Wd1) via shfl reduce -> meta
        float wd1v[4];
#pragma unroll
        for (int q2 = 0; q2 < 4; ++q2) wd1v[q2] = Wd1[q2 * 16 + lr] * 0.125f;
        float dp[4] = {0.f, 0.f, 0.f, 0.f};
#pragma unroll
        for (int nt = 0; nt < 4; ++nt)
#pragma unroll
            for (int reg = 0; reg < 4; ++reg)
                dp[reg] += silu_f(c0[nt + 4][reg]) * wd1v[nt];
#pragma unroll
        for (int m2 = 1; m2 < 16; m2 <<= 1) {
#pragma unroll
            for (int reg = 0; reg < 4; ++reg) dp[reg] += __shfl_xor(dp[reg], m2);
        }
        if (lr == 0) {
#pragma unroll
            for (int reg = 0; reg < 4; ++reg)
                metaP[(size_t)pos[e0 + quad * 4 + reg] * 8 + 4] = tanhf(dp[reg] * dp[reg]);
        }
    }

    const unsigned short* hrow0 = &H[lr][quad * 8];
    const unsigned short* hrow1 = &H[lr][H1OFF + quad * 8];

    // ---- phase 1: h0 -> h1 (64->64), silu -> LDS h1
    {
        floatx4 c1[4];
#pragma unroll
        for (int nt = 0; nt < 4; ++nt) c1[nt] = (floatx4){0.f, 0.f, 0.f, 0.f};
#pragma unroll
        for (int kt = 0; kt < 2; ++kt) {
            short8 af = *(const short8*)(hrow0 + kt * 32);
            const short8* bp = (const short8*)WB1 + (size_t)(kt * 4) * 64 + l;
#pragma unroll
            for (int nt = 0; nt < 4; ++nt)
                c1[nt] = __builtin_amdgcn_mfma_f32_16x16x32_bf16(af, bp[nt * 64], c1[nt], 0, 0, 0);
        }
#pragma unroll
        for (int nt = 0; nt < 4; ++nt)
#pragma unroll
            for (int reg = 0; reg < 4; ++reg)
                H[quad * 4 + reg][H1OFF + nt * 16 + lr] = f2bf(silu_f(c1[nt][reg]));
    }

    // ---- phase 2: h1 -> h2 (64->64), silu -> LDS h0 (overwrite)
    {
        floatx4 c2[4];
#pragma unroll
        for (int nt = 0; nt < 4; ++nt) c2[nt] = (floatx4){0.f, 0.f, 0.f, 0.f};
#pragma unroll
        for (int kt = 0; kt < 2; ++kt) {
            short8 af = *(const short8*)(hrow1 + kt * 32);
            const short8* bp = (const short8*)WB2 + (size_t)(kt * 4) * 64 + l;
#pragma unroll
            for (int nt = 0; nt < 4; ++nt)
                c2[nt] = __builtin_amdgcn_mfma_f32_16x16x32_bf16(af, bp[nt * 64], c2[nt], 0, 0, 0);
        }
#pragma unroll
        for (int nt = 0; nt < 4; ++nt)
#pragma unroll
            for (int reg = 0; reg < 4; ++reg)
                H[quad * 4 + reg][nt * 16 + lr] = f2bf(silu_f(c2[nt][reg]));
    }

    // ---- phase 3: h2 -> tpw (64 -> 512), fold y0, scatter by slot
    {
        int slotr[4];
        float y0r[4];
#pragma unroll
        for (int reg = 0; reg < 4; ++reg) {
            const int er = e0 + quad * 4 + reg;
            slotr[reg] = pos[er];
            y0r[reg] = edge_attrs[(size_t)er * 4];
        }
        short8 af0 = *(const short8*)(hrow0);
        short8 af1 = *(const short8*)(hrow0 + 32);
        uint2* tpw2 = (uint2*)tpwP;
#pragma unroll
        for (int j2 = 0; j2 < 8; ++j2) {
            floatx4 c3[4];
#pragma unroll
            for (int g = 0; g < 4; ++g) c3[g] = (floatx4){0.f, 0.f, 0.f, 0.f};
#pragma unroll
            for (int g = 0; g < 4; ++g) {
                const short8* b0 = (const short8*)WB3 + (size_t)(g * 8 + j2) * 64 + l;
                const short8* b1 = (const short8*)WB3 + (size_t)(32 + g * 8 + j2) * 64 + l;
                c3[g] = __builtin_amdgcn_mfma_f32_16x16x32_bf16(af0, *b0, c3[g], 0, 0, 0);
                c3[g] = __builtin_amdgcn_mfma_f32_16x16x32_bf16(af1, *b1, c3[g], 0, 0, 0);
            }
            const int u = j2 * 16 + lr;
#pragma unroll
            for (int reg = 0; reg < 4; ++reg) {
                float w1v = c3[0][reg] * y0r[reg];
                float w2v = c3[1][reg];
                float w3v = c3[2][reg] * y0r[reg];
                float w4v = c3[3][reg];
                uint2 p;
                p.x = (unsigned)f2bf(w1v) | ((unsigned)f2bf(w2v) << 16);
                p.y = (unsigned)f2bf(w3v) | ((unsigned)f2bf(w4v) << 16);
                tpw2[(size_t)slotr[reg] * 128 + u] = p;
            }
        }
    }
}

// ---------------------------------------------------------------------------
// Kernel C: per-node gather — round 18: 8-wide MLP unroll (avg degree 16),
// then 4-wide, then scalar tail. Doubles outstanding loads per thread for
// the latency-critical random xq gathers. Math identical.
// ---------------------------------------------------------------------------
__global__ __launch_bounds__(128) void node_gather(
    const unsigned short* __restrict__ tpwP, const float* __restrict__ metaP,
    const int* __restrict__ offs, const uint2* __restrict__ xq,
    const float* __restrict__ alpha_p, const float* __restrict__ beta_p,
    unsigned short* __restrict__ msgs_b, unsigned short* __restrict__ msgv_b)
{
    const int n = blockIdx.x;
    const int j = threadIdx.x;
    const int s0 = offs[n], s1 = offs[n + 1];
    const uint2* tpw2 = (const uint2*)tpwP;

    float as0 = 0.f, as1 = 0.f;
    float av0x = 0.f, av0y = 0.f, av0z = 0.f;
    float av1x = 0.f, av1y = 0.f, av1z = 0.f;
    float dsum = 0.f;

    int s = s0;
    for (; s + 8 <= s1; s += 8) {
        float4 ma[8]; float dn[8]; uint2 wv[8]; uint2 xv[8];
#pragma unroll
        for (int k = 0; k < 8; ++k) {
            ma[k] = *(const float4*)&metaP[(size_t)(s + k) * 8];
            dn[k] = metaP[(size_t)(s + k) * 8 + 4];
            wv[k] = tpw2[(size_t)(s + k) * 128 + j];
        }
#pragma unroll
        for (int k = 0; k < 8; ++k)
            xv[k] = xq[(size_t)__float_as_int(ma[k].x) * 128 + j];
#pragma unroll
        for (int k = 0; k < 8; ++k) {
            const float y1x = ma[k].y, y1y = ma[k].z, y1z = ma[k].w;
            dsum += dn[k];
            const float w1  = __uint_as_float(wv[k].x << 16);
            const float w2  = __uint_as_float(wv[k].x & 0xffff0000u);
            const float w3  = __uint_as_float(wv[k].y << 16);
            const float w4  = __uint_as_float(wv[k].y & 0xffff0000u);
            const float xs  = __uint_as_float(xv[k].x << 16);
            const float xvx = __uint_as_float(xv[k].x & 0xffff0000u);
            const float xvy = __uint_as_float(xv[k].y << 16);
            const float xvz = __uint_as_float(xv[k].y & 0xffff0000u);
            as0 += w1 * xs;
            as1 += w4 * (xvx * y1x + xvy * y1y + xvz * y1z);
            const float b2 = w2 * xs;
            av0x += b2 * y1x; av0y += b2 * y1y; av0z += b2 * y1z;
            av1x += w3 * xvx; av1y += w3 * xvy; av1z += w3 * xvz;
        }
    }
    for (; s + 4 <= s1; s += 4) {
        float4 ma[4]; float dn[4]; uint2 wv[4]; uint2 xv[4];
#pragma unroll
        for (int k = 0; k < 4; ++k) {
            ma[k] = *(const float4*)&metaP[(size_t)(s + k) * 8];
            dn[k] = metaP[(size_t)(s + k) * 8 + 4];
            wv[k] = tpw2[(size_t)(s + k) * 128 + j];
        }
#pragma unroll
        for (int k = 0; k < 4; ++k)
            xv[k] = xq[(size_t)__float_as_int(ma[k].x) * 128 + j];
#pragma unroll
        for (int k = 0; k < 4; ++k) {
            const float y1x = ma[k].y, y1y = ma[k].z, y1z = ma[k].w;
            dsum += dn[k];
            const float w1  = __uint_as_float(wv[k].x << 16);
            const float w2  = __uint_as_float(wv[k].x & 0xffff0000u);
            const float w3  = __uint_as_float(wv[k].y << 16);
            const float w4  = __uint_as_float(wv[k].y & 0xffff0000u);
            const float xs  = __uint_as_float(xv[k].x << 16);
            const float xvx = __uint_as_float(xv[k].x & 0xffff0000u);
            const float xvy = __uint_as_float(xv[k].y << 16);
            const float xvz = __uint_as_float(xv[k].y & 0xffff0000u);
            as0 += w1 * xs;
            as1 += w4 * (xvx * y1x + xvy * y1y + xvz * y1z);
            const float b2 = w2 * xs;
            av0x += b2 * y1x; av0y += b2 * y1y; av0z += b2 * y1z;
            av1x += w3 * xvx; av1y += w3 * xvy; av1z += w3 * xvz;
        }
    }
    for (; s < s1; ++s) {
        const float4 m0 = *(const float4*)&metaP[(size_t)s * 8];
        const float dns = metaP[(size_t)s * 8 + 4];
        const int snd = __float_as_int(m0.x);
        const float y1x = m0.y, y1y = m0.z, y1z = m0.w;
        dsum += dns;
        uint2 wv = tpw2[(size_t)s * 128 + j];
        uint2 xv = xq[(size_t)snd * 128 + j];
        const float w1  = __uint_as_float(wv.x << 16);
        const float w2  = __uint_as_float(wv.x & 0xffff0000u);
        const float w3  = __uint_as_float(wv.y << 16);
        const float w4  = __uint_as_float(wv.y & 0xffff0000u);
        const float xs  = __uint_as_float(xv.x << 16);
        const float xvx = __uint_as_float(xv.x & 0xffff0000u);
        const float xvy = __uint_as_float(xv.y << 16);
        const float xvz = __uint_as_float(xv.y & 0xffff0000u);
        as0 += w1 * xs;
        as1 += w4 * (xvx * y1x + xvy * y1y + xvz * y1z);
        const float b2 = w2 * xs;
        av0x += b2 * y1x; av0y += b2 * y1y; av0z += b2 * y1z;
        av1x += w3 * xvx; av1y += w3 * xvy; av1z += w3 * xvz;
    }

    const float invden = 1.f / (dsum * (*beta_p) + (*alpha_p));

    msgs_b[(size_t)n * 256 + j]       = f2bf(as0 * invden);
    msgs_b[(size_t)n * 256 + 128 + j] = f2bf(as1 * invden);
    msgv_b[((size_t)0 * NN + n) * 256 + j]       = f2bf(av0x * invden);
    msgv_b[((size_t)0 * NN + n) * 256 + 128 + j] = f2bf(av1x * invden);
    msgv_b[((size_t)1 * NN + n) * 256 + j]       = f2bf(av0y * invden);
    msgv_b[((size_t)1 * NN + n) * 256 + 128 + j] = f2bf(av1y * invden);
    msgv_b[((size_t)2 * NN + n) * 256 + j]       = f2bf(av0z * invden);
    msgv_b[((size_t)2 * NN + n) * 256 + 128 + j] = f2bf(av1z * invden);
}

// ---------------------------------------------------------------------------
// Kernel D: FUSED post epilogue (round-7 verified version, unchanged).
// ---------------------------------------------------------------------------
#define DNP 16
__global__ __launch_bounds__(256) void post_fused(
    const unsigned short* __restrict__ msgs_b, const unsigned short* __restrict__ us_b,
    const unsigned short* __restrict__ msgv_b, const unsigned short* __restrict__ uv_b,
    const unsigned short* __restrict__ WPs, const unsigned short* __restrict__ WPv,
    const unsigned short* __restrict__ W2ss, const unsigned short* __restrict__ W2vs,
    float* __restrict__ out)
{
    __shared__ __align__(16) unsigned short osb[DNP][136];
    __shared__ __align__(16) unsigned short ovb[3][DNP][136];
    __shared__ float gateL[DNP][128];

    const int t = threadIdx.x;
    const int l = t & 63, w = t >> 6;         // 4 waves
    const int quad = l >> 4, lr = l & 15;
    const int n0 = blockIdx.x * DNP;
    const int nh = w;                         // 0..3 N-quarter
    const int n = n0 + lr;                    // this lane's A-row node

    const int cLo = (nh * 6) >> 3;
    const int cHi = (nh * 6 + 5) >> 3;

    const unsigned short* sRow  = msgs_b + (size_t)n * 256;
    const unsigned short* uRow  = us_b   + (size_t)n * 128;
    const unsigned short* vRowL = msgv_b + ((size_t)cLo * NN + n) * 256;
    const unsigned short* uRowL = uv_b   + ((size_t)cLo * NN + n) * 128;
    const unsigned short* vRowH = msgv_b + ((size_t)cHi * NN + n) * 256;
    const unsigned short* uRowH = uv_b   + ((size_t)cHi * NN + n) * 128;

    // ---- first layer: K=384 (12 kt), s: 4 N-tiles, v: 6 N-tiles
    floatx4 accS[4], accV[6];
#pragma unroll
    for (int i = 0; i < 4; ++i) accS[i] = (floatx4){0.f, 0.f, 0.f, 0.f};
#pragma unroll
    for (int i = 0; i < 6; ++i) accV[i] = (floatx4){0.f, 0.f, 0.f, 0.f};

#pragma unroll
    for (int kt = 0; kt < 12; ++kt) {
        const int col = kt * 32 + quad * 8;
        short8 aS = (col < 256) ? *(const short8*)(sRow + col)
                                : *(const short8*)(uRow + col - 256);
        short8 aV0 = (col < 256) ? *(const short8*)(vRowL + col)
                                 : *(const short8*)(uRowL + col - 256);
        short8 aV1;
        if (cHi != cLo)
            aV1 = (col < 256) ? *(const short8*)(vRowH + col)
                              : *(const short8*)(uRowH + col - 256);
        else
            aV1 = aV0;

        const short8* bpS = (const short8*)WPs + (size_t)(kt * 16 + nh * 4) * 64 + l;
#pragma unroll
        for (int i = 0; i < 4; ++i)
            accS[i] = __builtin_amdgcn_mfma_f32_16x16x32_bf16(aS, bpS[i * 64], accS[i], 0, 0, 0);
#pragma unroll
        for (int i = 0; i < 6; ++i) {
            const int vt = nh * 6 + i;
            const short8* bpV = (const short8*)WPv + (size_t)(kt * 8 + (vt & 7)) * 64 + l;
            short8 a = ((vt >> 3) == cLo) ? aV0 : aV1;
            accV[i] = __builtin_amdgcn_mfma_f32_16x16x32_bf16(a, *bpV, accV[i], 0, 0, 0);
        }
    }

    // ---- s outputs: tiles 0..7 -> silu -> osb; 8..15 -> sigmoid -> gateL
#pragma unroll
    for (int i = 0; i < 4; ++i) {
        const int tile = nh * 4 + i;
#pragma unroll
        for (int reg = 0; reg < 4; ++reg) {
            const int row = quad * 4 + reg;
            const float v = accS[i][reg];
            if (tile < 8) osb[row][tile * 16 + lr] = f2bf(silu_f(v));
            else          gateL[row][(tile - 8) * 16 + lr] = sigm_f(v);
        }
    }
    __syncthreads();

    // ---- gate the v accumulators -> ovb
#pragma unroll
    for (int i = 0; i < 6; ++i) {
        const int vt = nh * 6 + i;
        const int c = vt >> 3;
        const int colv = (vt & 7) * 16 + lr;
#pragma unroll
        for (int reg = 0; reg < 4; ++reg) {
            const int row = quad * 4 + reg;
            ovb[c][row][colv] = f2bf(accV[i][reg] * gateL[row][colv]);
        }
    }
    __syncthreads();

    // ---- second layer: K=128 (4 kt); s: 2 N-tiles, v: 6 N-tiles
    floatx4 c2s[2], c2v[6];
#pragma unroll
    for (int i = 0; i < 2; ++i) c2s[i] = (floatx4){0.f, 0.f, 0.f, 0.f};
#pragma unroll
    for (int i = 0; i < 6; ++i) c2v[i] = (floatx4){0.f, 0.f, 0.f, 0.f};

    const unsigned short* arowS = &osb[lr][quad * 8];
#pragma unroll
    for (int kt = 0; kt < 4; ++kt) {
        short8 afS = *(const short8*)(arowS + kt * 32);
        const short8* bpS = (const short8*)W2ss + (size_t)(kt * 8 + nh * 2) * 64 + l;
#pragma unroll
        for (int i = 0; i < 2; ++i)
            c2s[i] = __builtin_amdgcn_mfma_f32_16x16x32_bf16(afS, bpS[i * 64], c2s[i], 0, 0, 0);
#pragma unroll
        for (int i = 0; i < 6; ++i) {
            const int vt = nh * 6 + i;
            const int c = vt >> 3;
            short8 afV = *(const short8*)(&ovb[c][lr][quad * 8] + kt * 32);
            const short8* bpV = (const short8*)W2vs + (size_t)(kt * 8 + (vt & 7)) * 64 + l;
            c2v[i] = __builtin_amdgcn_mfma_f32_16x16x32_bf16(afV, *bpV, c2v[i], 0, 0, 0);
        }
    }

    // ---- epilogue
#pragma unroll
    for (int i = 0; i < 2; ++i) {
        const int col = (nh * 2 + i) * 16 + lr;
#pragma unroll
        for (int reg = 0; reg < 4; ++reg)
            out[(size_t)(n0 + quad * 4 + reg) * 512 + col * 4] = c2s[i][reg];
    }
#pragma unroll
    for (int i = 0; i < 6; ++i) {
        const int vt = nh * 6 + i;
        const int c = vt >> 3;
        const int col = (vt & 7) * 16 + lr;
#pragma unroll
        for (int reg = 0; reg < 4; ++reg)
            out[(size_t)(n0 + quad * 4 + reg) * 512 + col * 4 + 1 + c] = c2v[i][reg];
    }
}

// ---------------------------------------------------------------------------
extern "C" void kernel_launch(void* const* d_in, const int* in_sizes, int n_in,
                              void* d_out, int out_size, void* d_ws, size_t ws_size,
                              hipStream_t stream)
{
    const float* node_attrs = (const float*)d_in[0];
    const float* node_feats = (const float*)d_in[1];
    const float* edge_attrs = (const float*)d_in[2];
    const float* edge_feats = (const float*)d_in[3];
    const int*   edge_index = (const int*)d_in[4];
    const float* W_skip_s = (const float*)d_in[5];
    const float* W_skip_v = (const float*)d_in[6];
    const float* W_up_s   = (const float*)d_in[7];
    const float* W_up_v   = (const float*)d_in[8];
    const float* W_src    = (const float*)d_in[9];
    const float* W_tgt    = (const float*)d_in[10];
    const float* W_r0     = (const float*)d_in[11];
    const float* W_r1     = (const float*)d_in[12];
    const float* W_r2     = (const float*)d_in[13];
    const float* W_r3     = (const float*)d_in[14];
    const float* W_d0     = (const float*)d_in[15];
    const float* W_d1     = (const float*)d_in[16];
    const float* W1_s     = (const float*)d_in[17];
    const float* W1_v     = (const float*)d_in[18];
    const float* Wres_s   = (const float*)d_in[19];
    const float* Wres_v   = (const float*)d_in[20];
    const float* W2_s     = (const float*)d_in[21];
    const float* W2_v     = (const float*)d_in[22];
    const float* alpha_p  = (const float*)d_in[23];
    const float* beta_p   = (const float*)d_in[24];

    float* out = (float*)d_out;
    float* sc_out = out + (size_t)NN * 512;
    float* ws = (float*)d_ws;

    uint2* xq = (uint2*)(ws + WS_XQ);
    unsigned short* us_b  = (unsigned short*)(ws + WS_USB);
    unsigned short* uv_b  = (unsigned short*)(ws + WS_UVB);
    unsigned short* srcEb = (unsigned short*)(ws + WS_SRC);
    unsigned short* tgtEb = (unsigned short*)(ws + WS_TGT);
    unsigned short* msgs_b = (unsigned short*)(ws + WS_MSGSB);
    unsigned short* msgv_b = (unsigned short*)(ws + WS_MSGVB);
    int*   counts = (int*)(ws + WS_COUNTS);
    int*   offs   = (int*)(ws + WS_OFFS);
    int*   cursor = (int*)(ws + WS_CURSOR);
    int*   pos    = (int*)(ws + WS_POS);
    float* metaP  = ws + WS_META;
    unsigned short* tpwP = (unsigned short*)(ws + WS_TPW);
    unsigned short* WBall = (unsigned short*)(ws + WS_WB);
    unsigned short* WB0 = WBall;
    unsigned short* WB1 = WB0 + (size_t)72 * 512;
    unsigned short* WB2 = WB1 + (size_t)8 * 512;
    unsigned short* WB3 = WB2 + (size_t)8 * 512;
    unsigned short* WPall = (unsigned short*)(ws + WS_WP);
    unsigned short* WPs  = WPall;
    unsigned short* WPv  = WPs + (size_t)192 * 512;
    unsigned short* W2ss = WPv + (size_t)96 * 512;
    unsigned short* W2vs = W2ss + (size_t)32 * 512;
    unsigned short* WN   = (unsigned short*)(ws + WS_WN);

    hipMemsetAsync(counts, 0, (size_t)NN * sizeof(int), stream);

    csr_count<<<EE / 256, 256, 0, stream>>>(edge_index, counts);
    csr_scan<<<1, 1024, 0, stream>>>(counts, offs, cursor);
    csr_scatter<<<EE / 256, 256, 0, stream>>>(edge_index, cursor, pos);

    swizzle_all<<<162, 256, 0, stream>>>(
        W_r0, W_d0, W_r1, W_r2, W_r3,
        W1_s, W1_v, Wres_s, Wres_v, W2_s, W2_v,
        W_skip_s, W_up_s, W_skip_v, W_up_v, W_src, W_tgt,
        WBall, WPall, WN);

    node_pre_mfma<<<NN / PNB, 256, 0, stream>>>(
        node_attrs, node_feats, WN, sc_out, xq, us_b, uv_b, srcEb, tgtEb);

    edge_mlp<<<EE / EBK, 256, 0, stream>>>(
        edge_attrs, edge_feats, edge_index, srcEb, tgtEb,
        WB0, WB1, WB2, WB3, W_d1, pos, tpwP, metaP);

    node_gather<<<NN, 128, 0, stream>>>(
        tpwP, metaP, offs, xq, alpha_p, beta_p, msgs_b, msgv_b);

    post_fused<<<NN / DNP, 256, 0, stream>>>(
        msgs_b, us_b, msgv_b, uv_b, WPs, WPv, W2ss, W2vs, out);
}

// Round 12
// 296.043 us; speedup vs baseline: 3.3417x; 1.0085x over previous
//
#include <hip/hip_runtime.h>

// Problem constants (fixed by the reference)
#define NN 8192
#define EE 131072
#define MUL 128
#define AA 10
#define RB 8
#define DEF 264          // RB + 2*MUL
#define INV_SQRT3 0.5773502691896258f
#define INV_SQRT128 0.08838834764831845f
#define INV_SQRT10 0.31622776601683794f
#define INV_SQRT264 0.06154574548966636f

typedef __attribute__((ext_vector_type(8))) short short8;
typedef __attribute__((ext_vector_type(4))) float floatx4;

// ---------------------------------------------------------------------------
// Workspace layout (float offsets). ~182 MB total.
// ---------------------------------------------------------------------------
#define WS_XQ     ((size_t)0)                       // N*128 uint2 {us,uvx,uvy,uvz} bf16
#define WS_USB    (WS_XQ    + (size_t)NN*256)       // N*128 bf16
#define WS_UVB    (WS_USB   + (size_t)NN*64)        // 3*N*128 bf16 channel-major
#define WS_SRC    (WS_UVB   + (size_t)NN*192)       // N*128 bf16
#define WS_TGT    (WS_SRC   + (size_t)NN*64)        // N*128 bf16
#define WS_MSGSB  (WS_TGT   + (size_t)NN*64)        // N*256 bf16 (invden applied)
#define WS_MSGVB  (WS_MSGSB + (size_t)NN*128)       // 3*N*256 bf16 channel-major
#define WS_GATE   (WS_MSGVB + (size_t)NN*384)       // N*128 f32 (unused since post fusion)
#define WS_COUNTS (WS_GATE  + (size_t)NN*128)       // N ints
#define WS_OFFS   (WS_COUNTS+ (size_t)NN)           // N+4 ints
#define WS_CURSOR (WS_OFFS  + (size_t)(NN+4))       // N ints
#define WS_POS    (WS_CURSOR+ (size_t)NN)           // E ints
#define WS_META   (WS_POS   + (size_t)EE)           // E*8 f32
#define WS_TPW    (WS_META  + (size_t)EE*8)         // E*512 bf16, [slot][u][4] interleaved
#define WS_WB     (WS_TPW   + (size_t)EE*256)       // edge wfrags 152*512 bf16
#define WS_WP     (WS_WB    + (size_t)152*256)      // post wfrags 352*512 bf16
#define WS_WN     (WS_WP    + (size_t)352*256)      // node wfrags 144*512 bf16

__device__ __forceinline__ float silu_f(float x) {
    return x * __builtin_amdgcn_rcpf(1.f + __expf(-x));
}
__device__ __forceinline__ float sigm_f(float x) {
    return __builtin_amdgcn_rcpf(1.f + __expf(-x));
}

__device__ __forceinline__ unsigned short f2bf(float x) {
    union { float f; unsigned u; } uf; uf.f = x;
    unsigned r = uf.u + 0x7FFFu + ((uf.u >> 16) & 1u);   // RNE
    return (unsigned short)(r >> 16);
}

// ---------------------------------------------------------------------------
// CSR build: count -> scan -> scatter   (receiver-sorted edge slots)
// ---------------------------------------------------------------------------
__global__ __launch_bounds__(256) void csr_count(
    const int* __restrict__ edge_index, int* __restrict__ counts)
{
    int e = blockIdx.x * 256 + threadIdx.x;
    atomicAdd(&counts[edge_index[EE + e]], 1);
}

__global__ __launch_bounds__(1024) void csr_scan(
    const int* __restrict__ counts, int* __restrict__ offs, int* __restrict__ cursor)
{
    __shared__ int sums[1024];
    const int t = threadIdx.x;
    int local[8];
    int s = 0;
#pragma unroll
    for (int k = 0; k < 8; ++k) { local[k] = s; s += counts[t * 8 + k]; }
    sums[t] = s;
    __syncthreads();
    for (int d = 1; d < 1024; d <<= 1) {
        int v = (t >= d) ? sums[t - d] : 0;
        __syncthreads();
        sums[t] += v;
        __syncthreads();
    }
    int base = (t > 0) ? sums[t - 1] : 0;
#pragma unroll
    for (int k = 0; k < 8; ++k) {
        offs[t * 8 + k] = base + local[k];
        cursor[t * 8 + k] = base + local[k];
    }
    if (t == 1023) offs[8192] = sums[1023];
}

__global__ __launch_bounds__(256) void csr_scatter(
    const int* __restrict__ edge_index, int* __restrict__ cursor, int* __restrict__ pos)
{
    int e = blockIdx.x * 256 + threadIdx.x;
    pos[e] = atomicAdd(&cursor[edge_index[EE + e]], 1);
}

// ---------------------------------------------------------------------------
// MERGED weight pre-swizzle (verified round 11): one dispatch, three ranges.
// ---------------------------------------------------------------------------
__global__ __launch_bounds__(256) void swizzle_all(
    const float* __restrict__ Wr0, const float* __restrict__ Wd0,
    const float* __restrict__ Wr1, const float* __restrict__ Wr2,
    const float* __restrict__ Wr3,
    const float* __restrict__ W1s, const float* __restrict__ W1v,
    const float* __restrict__ Wrs, const float* __restrict__ Wrv,
    const float* __restrict__ W2s, const float* __restrict__ W2v,
    const float* __restrict__ Wss, const float* __restrict__ Wus,
    const float* __restrict__ Wsv, const float* __restrict__ Wuv,
    const float* __restrict__ Wsrc, const float* __restrict__ Wtgt,
    unsigned short* __restrict__ WBall, unsigned short* __restrict__ WPall,
    unsigned short* __restrict__ WN)
{
    const int b = blockIdx.x;
    unsigned short o[8];

    if (b < 38) {
        // ---- edge weights (WBall), 152 frags
        int fid = b * 256 + threadIdx.x;
        int lane = fid & 63;
        int frag = fid >> 6;
        int k0 = (lane >> 4) * 8;
        int n0 = lane & 15;

        if (frag < 72) {
            int kt = frag >> 3, nt = frag & 7;
            int n = nt * 16 + n0;
#pragma unroll
            for (int j = 0; j < 8; ++j) {
                int k = kt * 32 + k0 + j;
                float v = 0.f;
                if (k < 264) v = ((n < 64) ? Wr0[k * 64 + n] : Wd0[k * 64 + (n - 64)]) * INV_SQRT264;
                o[j] = f2bf(v);
            }
        } else if (frag < 80) {
            int fl = frag - 72;
            int kt = fl >> 2, nt = fl & 3;
            int n = nt * 16 + n0;
#pragma unroll
            for (int j = 0; j < 8; ++j)
                o[j] = f2bf(Wr1[(kt * 32 + k0 + j) * 64 + n] * 0.125f);
        } else if (frag < 88) {
            int fl = frag - 80;
            int kt = fl >> 2, nt = fl & 3;
            int n = nt * 16 + n0;
#pragma unroll
            for (int j = 0; j < 8; ++j)
                o[j] = f2bf(Wr2[(kt * 32 + k0 + j) * 64 + n] * 0.125f);
        } else {
            int fl = frag - 88;
            int kt = fl >> 5, nt = fl & 31;
            int n = nt * 16 + n0;
            int q = n >> 6;
            float sc = (q < 2) ? 0.125f : 0.125f * INV_SQRT3;
#pragma unroll
            for (int j = 0; j < 8; ++j)
                o[j] = f2bf(Wr3[(kt * 32 + k0 + j) * 512 + n] * sc);
        }
        uint4 pk;
        pk.x = (unsigned)o[0] | ((unsigned)o[1] << 16);
        pk.y = (unsigned)o[2] | ((unsigned)o[3] << 16);
        pk.z = (unsigned)o[4] | ((unsigned)o[5] << 16);
        pk.w = (unsigned)o[6] | ((unsigned)o[7] << 16);
        *(uint4*)(WBall + (size_t)fid * 8) = pk;
    } else if (b < 126) {
        // ---- post weights (WPall), 352 frags
        int fid = (b - 38) * 256 + threadIdx.x;
        int lane = fid & 63;
        int frag = fid >> 6;
        int k0 = (lane >> 4) * 8;
        int n0 = lane & 15;

        if (frag < 192) {
            int kt = frag >> 4, nt = frag & 15;
            int n = nt * 16 + n0;
#pragma unroll
            for (int j = 0; j < 8; ++j) {
                int k = kt * 32 + k0 + j;
                float v = (k < 256) ? W1s[k * 256 + n] * 0.0625f
                                    : Wrs[(k - 256) * 256 + n] * INV_SQRT128;
                o[j] = f2bf(v);
            }
        } else if (frag < 288) {
            int fl = frag - 192;
            int kt = fl >> 3, nt = fl & 7;
            int n = nt * 16 + n0;
#pragma unroll
            for (int j = 0; j < 8; ++j) {
                int k = kt * 32 + k0 + j;
                float v = (k < 256) ? W1v[k * 128 + n] * 0.0625f
                                    : Wrv[(k - 256) * 128 + n] * INV_SQRT128;
                o[j] = f2bf(v);
            }
        } else if (frag < 320) {
            int fl = frag - 288;
            int kt = fl >> 3, nt = fl & 7;
            int n = nt * 16 + n0;
#pragma unroll
            for (int j = 0; j < 8; ++j)
                o[j] = f2bf(W2s[(kt * 32 + k0 + j) * 128 + n] * INV_SQRT128);
        } else {
            int fl = frag - 320;
            int kt = fl >> 3, nt = fl & 7;
            int n = nt * 16 + n0;
#pragma unroll
            for (int j = 0; j < 8; ++j)
                o[j] = f2bf(W2v[(kt * 32 + k0 + j) * 128 + n] * INV_SQRT128);
        }
        uint4 pk;
        pk.x = (unsigned)o[0] | ((unsigned)o[1] << 16);
        pk.y = (unsigned)o[2] | ((unsigned)o[3] << 16);
        pk.z = (unsigned)o[4] | ((unsigned)o[5] << 16);
        pk.w = (unsigned)o[6] | ((unsigned)o[7] << 16);
        *(uint4*)(WPall + (size_t)fid * 8) = pk;
    } else {
        // ---- node weights (WN), 144 frags
        int fid = (b - 126) * 256 + threadIdx.x;
        int lane = fid & 63;
        int frag = fid >> 6;
        int k0 = (lane >> 4) * 8;
        int m0 = lane & 15;

        if (frag < 128) {
            int g = frag >> 5;
            int fl = frag & 31;
            int kt = fl >> 3, mt = fl & 7;
            const float* W = (g == 0) ? Wss : (g == 1) ? Wus : (g == 2) ? Wsv : Wuv;
            int m = mt * 16 + m0;
#pragma unroll
            for (int j = 0; j < 8; ++j)
                o[j] = f2bf(W[(kt * 32 + k0 + j) * 128 + m] * INV_SQRT128);
        } else {
            int g = (frag - 128) >> 3;
            int mt = frag & 7;
            const float* W = g ? Wtgt : Wsrc;
            int m = mt * 16 + m0;
#pragma unroll
            for (int j = 0; j < 8; ++j) {
                int k = k0 + j;
                o[j] = f2bf((k < AA) ? W[k * 128 + m] * INV_SQRT10 : 0.f);
            }
        }
        uint4 pk;
        pk.x = (unsigned)o[0] | ((unsigned)o[1] << 16);
        pk.y = (unsigned)o[2] | ((unsigned)o[3] << 16);
        pk.z = (unsigned)o[4] | ((unsigned)o[5] << 16);
        pk.w = (unsigned)o[6] | ((unsigned)o[7] << 16);
        *(uint4*)(WN + (size_t)fid * 8) = pk;
    }
}

// ---------------------------------------------------------------------------
// Kernel A: per-node precompute on MFMA (unchanged).
// ---------------------------------------------------------------------------
#define PNB 16
__global__ __launch_bounds__(256) void node_pre_mfma(
    const float* __restrict__ node_attrs, const float* __restrict__ node_feats,
    const unsigned short* __restrict__ WN,
    float* __restrict__ sc_out, uint2* __restrict__ xq,
    unsigned short* __restrict__ us_b, unsigned short* __restrict__ uv_b,
    unsigned short* __restrict__ srcEb, unsigned short* __restrict__ tgtEb)
{
    __shared__ __align__(16) unsigned short Xs[PNB][136];
    __shared__ __align__(16) unsigned short Xv[3][PNB][136];
    __shared__ __align__(16) unsigned short Xa[PNB][40];
    const int t = threadIdx.x;
    const int l = t & 63, w = t >> 6;
    const int quad = l >> 4, lr = l & 15;
    const int n0 = blockIdx.x * PNB;

    // ---- stage node_feats (f32 -> bf16): thread (r=t>>4, m=t&15)
    {
        const int r = t >> 4, m = t & 15;
        const float* src = node_feats + (size_t)(n0 + r) * 512;
        float4 s0 = *(const float4*)(src + 8 * m);
        float4 s1 = *(const float4*)(src + 8 * m + 4);
        uint4 sp;
        sp.x = (unsigned)f2bf(s0.x) | ((unsigned)f2bf(s0.y) << 16);
        sp.y = (unsigned)f2bf(s0.z) | ((unsigned)f2bf(s0.w) << 16);
        sp.z = (unsigned)f2bf(s1.x) | ((unsigned)f2bf(s1.y) << 16);
        sp.w = (unsigned)f2bf(s1.z) | ((unsigned)f2bf(s1.w) << 16);
        *(uint4*)&Xs[r][8 * m] = sp;

        float4 q[6];
#pragma unroll
        for (int jj = 0; jj < 6; ++jj)
            q[jj] = *(const float4*)(src + 128 + 24 * m + 4 * jj);
        const float* qf = &q[0].x;
        unsigned short vb[3][8];
#pragma unroll
        for (int u = 0; u < 8; ++u) {
#pragma unroll
            for (int c = 0; c < 3; ++c)
                vb[c][u] = f2bf(qf[u * 3 + c]);
        }
#pragma unroll
        for (int c = 0; c < 3; ++c) {
            uint4 vp;
            vp.x = (unsigned)vb[c][0] | ((unsigned)vb[c][1] << 16);
            vp.y = (unsigned)vb[c][2] | ((unsigned)vb[c][3] << 16);
            vp.z = (unsigned)vb[c][4] | ((unsigned)vb[c][5] << 16);
            vp.w = (unsigned)vb[c][6] | ((unsigned)vb[c][7] << 16);
            *(uint4*)&Xv[c][r][8 * m] = vp;
        }
    }
    // ---- stage attrs (padded K=32)
    for (int idx = t; idx < PNB * 32; idx += 256) {
        int r = idx >> 5, k = idx & 31;
        float v = (k < AA) ? node_attrs[(size_t)(n0 + r) * AA + k] : 0.f;
        Xa[r][k] = f2bf(v);
    }
    __syncthreads();

    const short8* WNf = (const short8*)WN;
    const int n = n0 + lr;

#pragma unroll
    for (int mi = 0; mi < 2; ++mi) {
        const int mt = w * 2 + mi;
        const int j0 = mt * 16 + quad * 4;

        // attr GEMM (K=32): srcE / tgtE
        floatx4 cSrc = (floatx4){0.f, 0.f, 0.f, 0.f};
        floatx4 cTgt = (floatx4){0.f, 0.f, 0.f, 0.f};
        {
            short8 ba = *(const short8*)&Xa[lr][quad * 8];
            cSrc = __builtin_amdgcn_mfma_f32_16x16x32_bf16(WNf[(size_t)(128 + mt) * 64 + l], ba, cSrc, 0, 0, 0);
            cTgt = __builtin_amdgcn_mfma_f32_16x16x32_bf16(WNf[(size_t)(136 + mt) * 64 + l], ba, cTgt, 0, 0, 0);
        }
        // s GEMMs (K=128): sc_s / us
        floatx4 cS = (floatx4){0.f, 0.f, 0.f, 0.f};
        floatx4 cU = (floatx4){0.f, 0.f, 0.f, 0.f};
#pragma unroll
        for (int kt = 0; kt < 4; ++kt) {
            short8 bs = *(const short8*)&Xs[lr][kt * 32 + quad * 8];
            cS = __builtin_amdgcn_mfma_f32_16x16x32_bf16(WNf[(size_t)(kt * 8 + mt) * 64 + l], bs, cS, 0, 0, 0);
            cU = __builtin_amdgcn_mfma_f32_16x16x32_bf16(WNf[(size_t)(32 + kt * 8 + mt) * 64 + l], bs, cU, 0, 0, 0);
        }
        // v GEMMs (K=128 x 3 channels): sc_v / uv
        floatx4 cSV[3], cUV[3];
#pragma unroll
        for (int c = 0; c < 3; ++c) {
            cSV[c] = (floatx4){0.f, 0.f, 0.f, 0.f};
            cUV[c] = (floatx4){0.f, 0.f, 0.f, 0.f};
#pragma unroll
            for (int kt = 0; kt < 4; ++kt) {
                short8 bv = *(const short8*)&Xv[c][lr][kt * 32 + quad * 8];
                cSV[c] = __builtin_amdgcn_mfma_f32_16x16x32_bf16(WNf[(size_t)(64 + kt * 8 + mt) * 64 + l], bv, cSV[c], 0, 0, 0);
                cUV[c] = __builtin_amdgcn_mfma_f32_16x16x32_bf16(WNf[(size_t)(96 + kt * 8 + mt) * 64 + l], bv, cUV[c], 0, 0, 0);
            }
        }

        // ---- epilogue: packed stores (node n, outputs j0..j0+3)
        {
            float4 o;
            o.x = cS[0]; o.y = cS[1]; o.z = cS[2]; o.w = cS[3];
            *(float4*)(sc_out + (size_t)n * 512 + j0) = o;
        }
        {
            float vv[12];
#pragma unroll
            for (int reg = 0; reg < 4; ++reg)
#pragma unroll
                for (int c = 0; c < 3; ++c) vv[reg * 3 + c] = cSV[c][reg];
            float* dst = sc_out + (size_t)n * 512 + 128 + j0 * 3;
#pragma unroll
            for (int qq = 0; qq < 3; ++qq) {
                float4 o;
                o.x = vv[qq * 4]; o.y = vv[qq * 4 + 1]; o.z = vv[qq * 4 + 2]; o.w = vv[qq * 4 + 3];
                *(float4*)(dst + qq * 4) = o;
            }
        }
        unsigned short ub[4], vxb[4], vyb[4], vzb[4];
#pragma unroll
        for (int reg = 0; reg < 4; ++reg) {
            ub[reg] = f2bf(cU[reg]);
            vxb[reg] = f2bf(cUV[0][reg]);
            vyb[reg] = f2bf(cUV[1][reg]);
            vzb[reg] = f2bf(cUV[2][reg]);
        }
        {
            uint2 p;
            p.x = (unsigned)ub[0] | ((unsigned)ub[1] << 16);
            p.y = (unsigned)ub[2] | ((unsigned)ub[3] << 16);
            *(uint2*)(us_b + (size_t)n * 128 + j0) = p;
        }
        {
            uint2 p;
            p.x = (unsigned)vxb[0] | ((unsigned)vxb[1] << 16);
            p.y = (unsigned)vxb[2] | ((unsigned)vxb[3] << 16);
            *(uint2*)(uv_b + ((size_t)0 * NN + n) * 128 + j0) = p;
            p.x = (unsigned)vyb[0] | ((unsigned)vyb[1] << 16);
            p.y = (unsigned)vyb[2] | ((unsigned)vyb[3] << 16);
            *(uint2*)(uv_b + ((size_t)1 * NN + n) * 128 + j0) = p;
            p.x = (unsigned)vzb[0] | ((unsigned)vzb[1] << 16);
            p.y = (unsigned)vzb[2] | ((unsigned)vzb[3] << 16);
            *(uint2*)(uv_b + ((size_t)2 * NN + n) * 128 + j0) = p;
        }
        {
            uint4 x0, x1;
            x0.x = (unsigned)ub[0] | ((unsigned)vxb[0] << 16);
            x0.y = (unsigned)vyb[0] | ((unsigned)vzb[0] << 16);
            x0.z = (unsigned)ub[1] | ((unsigned)vxb[1] << 16);
            x0.w = (unsigned)vyb[1] | ((unsigned)vzb[1] << 16);
            x1.x = (unsigned)ub[2] | ((unsigned)vxb[2] << 16);
            x1.y = (unsigned)vyb[2] | ((unsigned)vzb[2] << 16);
            x1.z = (unsigned)ub[3] | ((unsigned)vxb[3] << 16);
            x1.w = (unsigned)vyb[3] | ((unsigned)vzb[3] << 16);
            uint4* xp = (uint4*)(xq + (size_t)n * 128 + j0);
            xp[0] = x0; xp[1] = x1;
        }
        {
            uint2 p;
            p.x = (unsigned)f2bf(cSrc[0]) | ((unsigned)f2bf(cSrc[1]) << 16);
            p.y = (unsigned)f2bf(cSrc[2]) | ((unsigned)f2bf(cSrc[3]) << 16);
            *(uint2*)(srcEb + (size_t)n * 128 + j0) = p;
            p.x = (unsigned)f2bf(cTgt[0]) | ((unsigned)f2bf(cTgt[1]) << 16);
            p.y = (unsigned)f2bf(cTgt[2]) | ((unsigned)f2bf(cTgt[3]) << 16);
            *(uint2*)(tgtEb + (size_t)n * 128 + j0) = p;
        }
    }
}

// ---------------------------------------------------------------------------
// Kernel B: per-edge MLP on MFMA — round 19: WB1+WB2 staged in LDS (16 KB),
// shared by the block's 4 waves. Phases 1/2 are short dependent chains where
// the ~200cy L2 B-read latency was exposed; LDS reads are ~12cy. One
// __syncthreads at kernel start (all waves arrive together; phase 0's
// 72-MFMA span follows, so the barrier is free). LDS 19.4->35.8 KB, still
// 4 blocks/CU at (256,4). Indexing unchanged.
// ---------------------------------------------------------------------------
#define EBK 64
#define H1OFF 80
#define HLD 152   // LDS row stride (u16): 304B = odd multiple of 16B
__global__ __launch_bounds__(256, 4) void edge_mlp(
    const float* __restrict__ edge_attrs, const float* __restrict__ edge_feats,
    const int* __restrict__ edge_index,
    const unsigned short* __restrict__ srcEb, const unsigned short* __restrict__ tgtEb,
    const unsigned short* __restrict__ WB0, const unsigned short* __restrict__ WB1,
    const unsigned short* __restrict__ WB2, const unsigned short* __restrict__ WB3,
    const float* __restrict__ Wd1, const int* __restrict__ pos,
    unsigned short* __restrict__ tpwP, float* __restrict__ metaP)
{
    __shared__ __align__(16) unsigned short Hb[4][16][HLD];
    __shared__ __align__(16) unsigned short WB1s[8 * 512];
    __shared__ __align__(16) unsigned short WB2s[8 * 512];

    const int t = threadIdx.x;
    const int l = t & 63;
    const int w = t >> 6;
    const int quad = l >> 4;
    const int lr = l & 15;
    const int e0 = blockIdx.x * EBK + w * 16;   // this wave's 16 edges

    // ---- stage WB1/WB2 into LDS (block-shared; 512 uint4 each)
    {
        const uint4* s1 = (const uint4*)WB1;
        const uint4* s2 = (const uint4*)WB2;
        uint4* d1 = (uint4*)WB1s;
        uint4* d2 = (uint4*)WB2s;
#pragma unroll
        for (int i = 0; i < 2; ++i) {
            d1[t + i * 256] = s1[t + i * 256];
            d2[t + i * 256] = s2[t + i * 256];
        }
    }
    __syncthreads();

    // Row-edge for this lane's A-fragments (A row = lane&15).
    const int eA = e0 + lr;
    const int sndA = edge_index[eA];
    const int rcvA = edge_index[EE + eA];
    const unsigned short* spp = srcEb + (size_t)sndA * 128;
    const unsigned short* tpp = tgtEb + (size_t)rcvA * 128;

    // meta m0: one lane per edge (quad 0 covers the wave's 16 edges)
    if (quad == 0) {
        float4 ya = *(const float4*)(edge_attrs + (size_t)eA * 4);
        float4 m;
        m.x = __int_as_float(sndA); m.y = ya.y; m.z = ya.z; m.w = ya.w;
        *(float4*)(metaP + (size_t)pos[eA] * 8) = m;
    }

    // ---- load all 9 A-fragments for ef row eA (cols kt*32 + quad*8 .. +8)
    short8 afr[9];
    {
        const int cq = quad * 8;
        if (quad == 0) {
            float4 f0 = *(const float4*)(edge_feats + (size_t)eA * 8);
            float4 f1 = *(const float4*)(edge_feats + (size_t)eA * 8 + 4);
            union { short8 v; unsigned u[4]; } pk;
            pk.u[0] = (unsigned)f2bf(f0.x) | ((unsigned)f2bf(f0.y) << 16);
            pk.u[1] = (unsigned)f2bf(f0.z) | ((unsigned)f2bf(f0.w) << 16);
            pk.u[2] = (unsigned)f2bf(f1.x) | ((unsigned)f2bf(f1.y) << 16);
            pk.u[3] = (unsigned)f2bf(f1.z) | ((unsigned)f2bf(f1.w) << 16);
            afr[0] = pk.v;
        } else {
            afr[0] = *(const short8*)(spp + (cq - 8));
        }
#pragma unroll
        for (int kt = 1; kt < 9; ++kt) {
            const int c = kt * 32 + cq;
            if (c < 136) {
                afr[kt] = *(const short8*)(spp + (c - 8));
            } else if (c < 264) {
                afr[kt] = *(const short8*)(tpp + (c - 136));
            } else {
                short8 z = {0, 0, 0, 0, 0, 0, 0, 0};
                afr[kt] = z;
            }
        }
    }

    unsigned short (*H)[HLD] = Hb[w];

    // ---- phase 0: first layer, r-path AND d-path in ONE K=288 pass
    {
        floatx4 c0[8];
#pragma unroll
        for (int nt = 0; nt < 8; ++nt) c0[nt] = (floatx4){0.f, 0.f, 0.f, 0.f};
#pragma unroll
        for (int kt = 0; kt < 9; ++kt) {
            const short8* bp = (const short8*)WB0 + (size_t)(kt * 8) * 64 + l;
#pragma unroll
            for (int nt = 0; nt < 8; ++nt)
                c0[nt] = __builtin_amdgcn_mfma_f32_16x16x32_bf16(afr[kt], bp[nt * 64], c0[nt], 0, 0, 0);
        }

        // r-path (nt 0..3): silu -> LDS h0
#pragma unroll
        for (int nt = 0; nt < 4; ++nt)
#pragma unroll
            for (int reg = 0; reg < 4; ++reg)
                H[quad * 4 + reg][nt * 16 + lr] = f2bf(silu_f(c0[nt][reg]));

        // d-path (nt 4..7): dot(Wd1) via shfl reduce -> meta
        float wd1v[4];
#pragma unroll
        for (int q2 = 0; q2 < 4; ++q2) wd1v[q2] = Wd1[q2 * 16 + lr] * 0.125f;
        float dp[4] = {0.f, 0.f, 0.f, 0.f};
#pragma unroll
        for (int nt = 0; nt < 4; ++nt)
#pragma unroll
            for (int reg = 0; reg < 4; ++reg)
                dp[reg] += silu_f(c0[nt + 4][reg]) * wd1v[nt];
#pragma unroll
        for (int m2 = 1; m2 < 16; m2 <<= 1) {
#pragma unroll
            for (int reg = 0; reg < 4; ++reg) dp[reg] += __shfl_xor(dp[reg], m2);
        }
        if (lr == 0) {
#pragma unroll
            for (int reg = 0; reg < 4; ++reg)
                metaP[(size_t)pos[e0 + quad * 4 + reg] * 8 + 4] = tanhf(dp[reg] * dp[reg]);
        }
    }

    const unsigned short* hrow0 = &H[lr][quad * 8];
    const unsigned short* hrow1 = &H[lr][H1OFF + quad * 8];

    // ---- phase 1: h0 -> h1 (64->64), silu -> LDS h1 (B from LDS)
    {
        floatx4 c1[4];
#pragma unroll
        for (int nt = 0; nt < 4; ++nt) c1[nt] = (floatx4){0.f, 0.f, 0.f, 0.f};
#pragma unroll
        for (int kt = 0; kt < 2; ++kt) {
            short8 af = *(const short8*)(hrow0 + kt * 32);
            const short8* bp = (const short8*)WB1s + (size_t)(kt * 4) * 64 + l;
#pragma unroll
            for (int nt = 0; nt < 4; ++nt)
                c1[nt] = __builtin_amdgcn_mfma_f32_16x16x32_bf16(af, bp[nt * 64], c1[nt], 0, 0, 0);
        }
#pragma unroll
        for (int nt = 0; nt < 4; ++nt)
#pragma unroll
            for (int reg = 0; reg < 4; ++reg)
                H[quad * 4 + reg][H1OFF + nt * 16 + lr] = f2bf(silu_f(c1[nt][reg]));
    }

    // ---- phase 2: h1 -> h2 (64->64), silu -> LDS h0 (overwrite; B from LDS)
    {
        floatx4 c2[4];
#pragma unroll
        for (int nt = 0; nt < 4; ++nt) c2[nt] = (floatx4){0.f, 0.f, 0.f, 0.f};
#pragma unroll
        for (int kt = 0; kt < 2; ++kt) {
            short8 af = *(const short8*)(hrow1 + kt * 32);
            const short8* bp = (const short8*)WB2s + (size_t)(kt * 4) * 64 + l;
#pragma unroll
            for (int nt = 0; nt < 4; ++nt)
                c2[nt] = __builtin_amdgcn_mfma_f32_16x16x32_bf16(af, bp[nt * 64], c2[nt], 0, 0, 0);
        }
#pragma unroll
        for (int nt = 0; nt < 4; ++nt)
#pragma unroll
            for (int reg = 0; reg < 4; ++reg)
                H[quad * 4 + reg][nt * 16 + lr] = f2bf(silu_f(c2[nt][reg]));
    }

    // ---- phase 3: h2 -> tpw (64 -> 512), fold y0, scatter by slot
    {
        int slotr[4];
        float y0r[4];
#pragma unroll
        for (int reg = 0; reg < 4; ++reg) {
            const int er = e0 + quad * 4 + reg;
            slotr[reg] = pos[er];
            y0r[reg] = edge_attrs[(size_t)er * 4];
        }
        short8 af0 = *(const short8*)(hrow0);
        short8 af1 = *(const short8*)(hrow0 + 32);
        uint2* tpw2 = (uint2*)tpwP;
#pragma unroll
        for (int j2 = 0; j2 < 8; ++j2) {
            floatx4 c3[4];
#pragma unroll
            for (int g = 0; g < 4; ++g) c3[g] = (floatx4){0.f, 0.f, 0.f, 0.f};
#pragma unroll
            for (int g = 0; g < 4; ++g) {
                const short8* b0 = (const short8*)WB3 + (size_t)(g * 8 + j2) * 64 + l;
                const short8* b1 = (const short8*)WB3 + (size_t)(32 + g * 8 + j2) * 64 + l;
                c3[g] = __builtin_amdgcn_mfma_f32_16x16x32_bf16(af0, *b0, c3[g], 0, 0, 0);
                c3[g] = __builtin_amdgcn_mfma_f32_16x16x32_bf16(af1, *b1, c3[g], 0, 0, 0);
            }
            const int u = j2 * 16 + lr;
#pragma unroll
            for (int reg = 0; reg < 4; ++reg) {
                float w1v = c3[0][reg] * y0r[reg];
                float w2v = c3[1][reg];
                float w3v = c3[2][reg] * y0r[reg];
                float w4v = c3[3][reg];
                uint2 p;
                p.x = (unsigned)f2bf(w1v) | ((unsigned)f2bf(w2v) << 16);
                p.y = (unsigned)f2bf(w3v) | ((unsigned)f2bf(w4v) << 16);
                tpw2[(size_t)slotr[reg] * 128 + u] = p;
            }
        }
    }
}

// ---------------------------------------------------------------------------
// Kernel C: per-node gather (verified round 11: 8/4/1 unroll).
// ---------------------------------------------------------------------------
__global__ __launch_bounds__(128) void node_gather(
    const unsigned short* __restrict__ tpwP, const float* __restrict__ metaP,
    const int* __restrict__ offs, const uint2* __restrict__ xq,
    const float* __restrict__ alpha_p, const float* __restrict__ beta_p,
    unsigned short* __restrict__ msgs_b, unsigned short* __restrict__ msgv_b)
{
    const int n = blockIdx.x;
    const int j = threadIdx.x;
    const int s0 = offs[n], s1 = offs[n + 1];
    const uint2* tpw2 = (const uint2*)tpwP;

    float as0 = 0.f, as1 = 0.f;
    float av0x = 0.f, av0y = 0.f, av0z = 0.f;
    float av1x = 0.f, av1y = 0.f, av1z = 0.f;
    float dsum = 0.f;

    int s = s0;
    for (; s + 8 <= s1; s += 8) {
        float4 ma[8]; float dn[8]; uint2 wv[8]; uint2 xv[8];
#pragma unroll
        for (int k = 0; k < 8; ++k) {
            ma[k] = *(const float4*)&metaP[(size_t)(s + k) * 8];
            dn[k] = metaP[(size_t)(s + k) * 8 + 4];
            wv[k] = tpw2[(size_t)(s + k) * 128 + j];
        }
#pragma unroll
        for (int k = 0; k < 8; ++k)
            xv[k] = xq[(size_t)__float_as_int(ma[k].x) * 128 + j];
#pragma unroll
        for (int k = 0; k < 8; ++k) {
            const float y1x = ma[k].y, y1y = ma[k].z, y1z = ma[k].w;
            dsum += dn[k];
            const float w1  = __uint_as_float(wv[k].x << 16);
            const float w2  = __uint_as_float(wv[k].x & 0xffff0000u);
            const float w3  = __uint_as_float(wv[k].y << 16);
            const float w4  = __uint_as_float(wv[k].y & 0xffff0000u);
            const float xs  = __uint_as_float(xv[k].x << 16);
            const float xvx = __uint_as_float(xv[k].x & 0xffff0000u);
            const float xvy = __uint_as_float(xv[k].y << 16);
            const float xvz = __uint_as_float(xv[k].y & 0xffff0000u);
            as0 += w1 * xs;
            as1 += w4 * (xvx * y1x + xvy * y1y + xvz * y1z);
            const float b2 = w2 * xs;
            av0x += b2 * y1x; av0y += b2 * y1y; av0z += b2 * y1z;
            av1x += w3 * xvx; av1y += w3 * xvy; av1z += w3 * xvz;
        }
    }
    for (; s + 4 <= s1; s += 4) {
        float4 ma[4]; float dn[4]; uint2 wv[4]; uint2 xv[4];
#pragma unroll
        for (int k = 0; k < 4; ++k) {
            ma[k] = *(const float4*)&metaP[(size_t)(s + k) * 8];
            dn[k] = metaP[(size_t)(s + k) * 8 + 4];
            wv[k] = tpw2[(size_t)(s + k) * 128 + j];
        }
#pragma unroll
        for (int k = 0; k < 4; ++k)
            xv[k] = xq[(size_t)__float_as_int(ma[k].x) * 128 + j];
#pragma unroll
        for (int k = 0; k < 4; ++k) {
            const float y1x = ma[k].y, y1y = ma[k].z, y1z = ma[k].w;
            dsum += dn[k];
            const float w1  = __uint_as_float(wv[k].x << 16);
            const float w2  = __uint_as_float(wv[k].x & 0xffff0000u);
            const float w3  = __uint_as_float(wv[k].y << 16);
            const float w4  = __uint_as_float(wv[k].y & 0xffff0000u);
            const float xs  = __uint_as_float(xv[k].x << 16);
            const float xvx = __uint_as_float(xv[k].x & 0xffff0000u);
            const float xvy = __uint_as_float(xv[k].y << 16);
            const float xvz = __uint_as_float(xv[k].y & 0xffff0000u);
            as0 += w1 * xs;
            as1 += w4 * (xvx * y1x + xvy * y1y + xvz * y1z);
            const float b2 = w2 * xs;
            av0x += b2 * y1x; av0y += b2 * y1y; av0z += b2 * y1z;
            av1x += w3 * xvx; av1y += w3 * xvy; av1z += w3 * xvz;
        }
    }
    for (; s < s1; ++s) {
        const float4 m0 = *(const float4*)&metaP[(size_t)s * 8];
        const float dns = metaP[(size_t)s * 8 + 4];
        const int snd = __float_as_int(m0.x);
        const float y1x = m0.y, y1y = m0.z, y1z = m0.w;
        dsum += dns;
        uint2 wv = tpw2[(size_t)s * 128 + j];
        uint2 xv = xq[(size_t)snd * 128 + j];
        const float w1  = __uint_as_float(wv.x << 16);
        const float w2  = __uint_as_float(wv.x & 0xffff0000u);
        const float w3  = __uint_as_float(wv.y << 16);
        const float w4  = __uint_as_float(wv.y & 0xffff0000u);
        const float xs  = __uint_as_float(xv.x << 16);
        const float xvx = __uint_as_float(xv.x & 0xffff0000u);
        const float xvy = __uint_as_float(xv.y << 16);
        const float xvz = __uint_as_float(xv.y & 0xffff0000u);
        as0 += w1 * xs;
        as1 += w4 * (xvx * y1x + xvy * y1y + xvz * y1z);
        const float b2 = w2 * xs;
        av0x += b2 * y1x; av0y += b2 * y1y; av0z += b2 * y1z;
        av1x += w3 * xvx; av1y += w3 * xvy; av1z += w3 * xvz;
    }

    const float invden = 1.f / (dsum * (*beta_p) + (*alpha_p));

    msgs_b[(size_t)n * 256 + j]       = f2bf(as0 * invden);
    msgs_b[(size_t)n * 256 + 128 + j] = f2bf(as1 * invden);
    msgv_b[((size_t)0 * NN + n) * 256 + j]       = f2bf(av0x * invden);
    msgv_b[((size_t)0 * NN + n) * 256 + 128 + j] = f2bf(av1x * invden);
    msgv_b[((size_t)1 * NN + n) * 256 + j]       = f2bf(av0y * invden);
    msgv_b[((size_t)1 * NN + n) * 256 + 128 + j] = f2bf(av1y * invden);
    msgv_b[((size_t)2 * NN + n) * 256 + j]       = f2bf(av0z * invden);
    msgv_b[((size_t)2 * NN + n) * 256 + 128 + j] = f2bf(av1z * invden);
}

// ---------------------------------------------------------------------------
// Kernel D: FUSED post epilogue (verified, unchanged).
// ---------------------------------------------------------------------------
#define DNP 16
__global__ __launch_bounds__(256) void post_fused(
    const unsigned short* __restrict__ msgs_b, const unsigned short* __restrict__ us_b,
    const unsigned short* __restrict__ msgv_b, const unsigned short* __restrict__ uv_b,
    const unsigned short* __restrict__ WPs, const unsigned short* __restrict__ WPv,
    const unsigned short* __restrict__ W2ss, const unsigned short* __restrict__ W2vs,
    float* __restrict__ out)
{
    __shared__ __align__(16) unsigned short osb[DNP][136];
    __shared__ __align__(16) unsigned short ovb[3][DNP][136];
    __shared__ float gateL[DNP][128];

    const int t = threadIdx.x;
    const int l = t & 63, w = t >> 6;         // 4 waves
    const int quad = l >> 4, lr = l & 15;
    const int n0 = blockIdx.x * DNP;
    const int nh = w;                         // 0..3 N-quarter
    const int n = n0 + lr;                    // this lane's A-row node

    const int cLo = (nh * 6) >> 3;
    const int cHi = (nh * 6 + 5) >> 3;

    const unsigned short* sRow  = msgs_b + (size_t)n * 256;
    const unsigned short* uRow  = us_b   + (size_t)n * 128;
    const unsigned short* vRowL = msgv_b + ((size_t)cLo * NN + n) * 256;
    const unsigned short* uRowL = uv_b   + ((size_t)cLo * NN + n) * 128;
    const unsigned short* vRowH = msgv_b + ((size_t)cHi * NN + n) * 256;
    const unsigned short* uRowH = uv_b   + ((size_t)cHi * NN + n) * 128;

    // ---- first layer: K=384 (12 kt), s: 4 N-tiles, v: 6 N-tiles
    floatx4 accS[4], accV[6];
#pragma unroll
    for (int i = 0; i < 4; ++i) accS[i] = (floatx4){0.f, 0.f, 0.f, 0.f};
#pragma unroll
    for (int i = 0; i < 6; ++i) accV[i] = (floatx4){0.f, 0.f, 0.f, 0.f};

#pragma unroll
    for (int kt = 0; kt < 12; ++kt) {
        const int col = kt * 32 + quad * 8;
        short8 aS = (col < 256) ? *(const short8*)(sRow + col)
                                : *(const short8*)(uRow + col - 256);
        short8 aV0 = (col < 256) ? *(const short8*)(vRowL + col)
                                 : *(const short8*)(uRowL + col - 256);
        short8 aV1;
        if (cHi != cLo)
            aV1 = (col < 256) ? *(const short8*)(vRowH + col)
                              : *(const short8*)(uRowH + col - 256);
        else
            aV1 = aV0;

        const short8* bpS = (const short8*)WPs + (size_t)(kt * 16 + nh * 4) * 64 + l;
#pragma unroll
        for (int i = 0; i < 4; ++i)
            accS[i] = __builtin_amdgcn_mfma_f32_16x16x32_bf16(aS, bpS[i * 64], accS[i], 0, 0, 0);
#pragma unroll
        for (int i = 0; i < 6; ++i) {
            const int vt = nh * 6 + i;
            const short8* bpV = (const short8*)WPv + (size_t)(kt * 8 + (vt & 7)) * 64 + l;
            short8 a = ((vt >> 3) == cLo) ? aV0 : aV1;
            accV[i] = __builtin_amdgcn_mfma_f32_16x16x32_bf16(a, *bpV, accV[i], 0, 0, 0);
        }
    }

    // ---- s outputs: tiles 0..7 -> silu -> osb; 8..15 -> sigmoid -> gateL
#pragma unroll
    for (int i = 0; i < 4; ++i) {
        const int tile = nh * 4 + i;
#pragma unroll
        for (int reg = 0; reg < 4; ++reg) {
            const int row = quad * 4 + reg;
            const float v = accS[i][reg];
            if (tile < 8) osb[row][tile * 16 + lr] = f2bf(silu_f(v));
            else          gateL[row][(tile - 8) * 16 + lr] = sigm_f(v);
        }
    }
    __syncthreads();

    // ---- gate the v accumulators -> ovb
#pragma unroll
    for (int i = 0; i < 6; ++i) {
        const int vt = nh * 6 + i;
        const int c = vt >> 3;
        const int colv = (vt & 7) * 16 + lr;
#pragma unroll
        for (int reg = 0; reg < 4; ++reg) {
            const int row = quad * 4 + reg;
            ovb[c][row][colv] = f2bf(accV[i][reg] * gateL[row][colv]);
        }
    }
    __syncthreads();

    // ---- second layer: K=128 (4 kt); s: 2 N-tiles, v: 6 N-tiles
    floatx4 c2s[2], c2v[6];
#pragma unroll
    for (int i = 0; i < 2; ++i) c2s[i] = (floatx4){0.f, 0.f, 0.f, 0.f};
#pragma unroll
    for (int i = 0; i < 6; ++i) c2v[i] = (floatx4){0.f, 0.f, 0.f, 0.f};

    const unsigned short* arowS = &osb[lr][quad * 8];
#pragma unroll
    for (int kt = 0; kt < 4; ++kt) {
        short8 afS = *(const short8*)(arowS + kt * 32);
        const short8* bpS = (const short8*)W2ss + (size_t)(kt * 8 + nh * 2) * 64 + l;
#pragma unroll
        for (int i = 0; i < 2; ++i)
            c2s[i] = __builtin_amdgcn_mfma_f32_16x16x32_bf16(afS, bpS[i * 64], c2s[i], 0, 0, 0);
#pragma unroll
        for (int i = 0; i < 6; ++i) {
            const int vt = nh * 6 + i;
            const int c = vt >> 3;
            short8 afV = *(const short8*)(&ovb[c][lr][quad * 8] + kt * 32);
            const short8* bpV = (const short8*)W2vs + (size_t)(kt * 8 + (vt & 7)) * 64 + l;
            c2v[i] = __builtin_amdgcn_mfma_f32_16x16x32_bf16(afV, *bpV, c2v[i], 0, 0, 0);
        }
    }

    // ---- epilogue
#pragma unroll
    for (int i = 0; i < 2; ++i) {
        const int col = (nh * 2 + i) * 16 + lr;
#pragma unroll
        for (int reg = 0; reg < 4; ++reg)
            out[(size_t)(n0 + quad * 4 + reg) * 512 + col * 4] = c2s[i][reg];
    }
#pragma unroll
    for (int i = 0; i < 6; ++i) {
        const int vt = nh * 6 + i;
        const int c = vt >> 3;
        const int col = (vt & 7) * 16 + lr;
#pragma unroll
        for (int reg = 0; reg < 4; ++reg)
            out[(size_t)(n0 + quad * 4 + reg) * 512 + col * 4 + 1 + c] = c2v[i][reg];
    }
}

// ---------------------------------------------------------------------------
extern "C" void kernel_launch(void* const* d_in, const int* in_sizes, int n_in,
                              void* d_out, int out_size, void* d_ws, size_t ws_size,
                              hipStream_t stream)
{
    const float* node_attrs = (const float*)d_in[0];
    const float* node_feats = (const float*)d_in[1];
    const float* edge_attrs = (const float*)d_in[2];
    const float* edge_feats = (const float*)d_in[3];
    const int*   edge_index = (const int*)d_in[4];
    const float* W_skip_s = (const float*)d_in[5];
    const float* W_skip_v = (const float*)d_in[6];
    const float* W_up_s   = (const float*)d_in[7];
    const float* W_up_v   = (const float*)d_in[8];
    const float* W_src    = (const float*)d_in[9];
    const float* W_tgt    = (const float*)d_in[10];
    const float* W_r0     = (const float*)d_in[11];
    const float* W_r1     = (const float*)d_in[12];
    const float* W_r2     = (const float*)d_in[13];
    const float* W_r3     = (const float*)d_in[14];
    const float* W_d0     = (const float*)d_in[15];
    const float* W_d1     = (const float*)d_in[16];
    const float* W1_s     = (const float*)d_in[17];
    const float* W1_v     = (const float*)d_in[18];
    const float* Wres_s   = (const float*)d_in[19];
    const float* Wres_v   = (const float*)d_in[20];
    const float* W2_s     = (const float*)d_in[21];
    const float* W2_v     = (const float*)d_in[22];
    const float* alpha_p  = (const float*)d_in[23];
    const float* beta_p   = (const float*)d_in[24];

    float* out = (float*)d_out;
    float* sc_out = out + (size_t)NN * 512;
    float* ws = (float*)d_ws;

    uint2* xq = (uint2*)(ws + WS_XQ);
    unsigned short* us_b  = (unsigned short*)(ws + WS_USB);
    unsigned short* uv_b  = (unsigned short*)(ws + WS_UVB);
    unsigned short* srcEb = (unsigned short*)(ws + WS_SRC);
    unsigned short* tgtEb = (unsigned short*)(ws + WS_TGT);
    unsigned short* msgs_b = (unsigned short*)(ws + WS_MSGSB);
    unsigned short* msgv_b = (unsigned short*)(ws + WS_MSGVB);
    int*   counts = (int*)(ws + WS_COUNTS);
    int*   offs   = (int*)(ws + WS_OFFS);
    int*   cursor = (int*)(ws + WS_CURSOR);
    int*   pos    = (int*)(ws + WS_POS);
    float* metaP  = ws + WS_META;
    unsigned short* tpwP = (unsigned short*)(ws + WS_TPW);
    unsigned short* WBall = (unsigned short*)(ws + WS_WB);
    unsigned short* WB0 = WBall;
    unsigned short* WB1 = WB0 + (size_t)72 * 512;
    unsigned short* WB2 = WB1 + (size_t)8 * 512;
    unsigned short* WB3 = WB2 + (size_t)8 * 512;
    unsigned short* WPall = (unsigned short*)(ws + WS_WP);
    unsigned short* WPs  = WPall;
    unsigned short* WPv  = WPs + (size_t)192 * 512;
    unsigned short* W2ss = WPv + (size_t)96 * 512;
    unsigned short* W2vs = W2ss + (size_t)32 * 512;
    unsigned short* WN   = (unsigned short*)(ws + WS_WN);

    hipMemsetAsync(counts, 0, (size_t)NN * sizeof(int), stream);

    csr_count<<<EE / 256, 256, 0, stream>>>(edge_index, counts);
    csr_scan<<<1, 1024, 0, stream>>>(counts, offs, cursor);
    csr_scatter<<<EE / 256, 256, 0, stream>>>(edge_index, cursor, pos);

    swizzle_all<<<162, 256, 0, stream>>>(
        W_r0, W_d0, W_r1, W_r2, W_r3,
        W1_s, W1_v, Wres_s, Wres_v, W2_s, W2_v,
        W_skip_s, W_up_s, W_skip_v, W_up_v, W_src, W_tgt,
        WBall, WPall, WN);

    node_pre_mfma<<<NN / PNB, 256, 0, stream>>>(
        node_attrs, node_feats, WN, sc_out, xq, us_b, uv_b, srcEb, tgtEb);

    edge_mlp<<<EE / EBK, 256, 0, stream>>>(
        edge_attrs, edge_feats, edge_index, srcEb, tgtEb,
        WB0, WB1, WB2, WB3, W_d1, pos, tpwP, metaP);

    node_gather<<<NN, 128, 0, stream>>>(
        tpwP, metaP, offs, xq, alpha_p, beta_p, msgs_b, msgv_b);

    post_fused<<<NN / DNP, 256, 0, stream>>>(
        msgs_b, us_b, msgv_b, uv_b, WPs, WPv, W2ss, W2vs, out);
}

// Round 13
// 284.404 us; speedup vs baseline: 3.4785x; 1.0409x over previous
//
#include <hip/hip_runtime.h>

// Problem constants (fixed by the reference)
#define NN 8192
#define EE 131072
#define MUL 128
#define AA 10
#define RB 8
#define DEF 264          // RB + 2*MUL
#define INV_SQRT3 0.5773502691896258f
#define INV_SQRT128 0.08838834764831845f
#define INV_SQRT10 0.31622776601683794f
#define INV_SQRT264 0.06154574548966636f

typedef __attribute__((ext_vector_type(8))) short short8;
typedef __attribute__((ext_vector_type(4))) float floatx4;

// ---------------------------------------------------------------------------
// Workspace layout (float offsets). ~182 MB total.
// ---------------------------------------------------------------------------
#define WS_XQ     ((size_t)0)                       // N*128 uint2 {us,uvx,uvy,uvz} bf16
#define WS_USB    (WS_XQ    + (size_t)NN*256)       // N*128 bf16
#define WS_UVB    (WS_USB   + (size_t)NN*64)        // 3*N*128 bf16 channel-major
#define WS_SRC    (WS_UVB   + (size_t)NN*192)       // N*128 bf16
#define WS_TGT    (WS_SRC   + (size_t)NN*64)        // N*128 bf16
#define WS_MSGSB  (WS_TGT   + (size_t)NN*64)        // N*256 bf16 (invden applied)
#define WS_MSGVB  (WS_MSGSB + (size_t)NN*128)       // 3*N*256 bf16 channel-major
#define WS_GATE   (WS_MSGVB + (size_t)NN*384)       // N*128 f32 (unused since post fusion)
#define WS_COUNTS (WS_GATE  + (size_t)NN*128)       // N ints
#define WS_OFFS   (WS_COUNTS+ (size_t)NN)           // N+4 ints
#define WS_CURSOR (WS_OFFS  + (size_t)(NN+4))       // N ints
#define WS_POS    (WS_CURSOR+ (size_t)NN)           // E ints
#define WS_META   (WS_POS   + (size_t)EE)           // E*8 f32
#define WS_TPW    (WS_META  + (size_t)EE*8)         // E*512 bf16, [slot][u][4] interleaved
#define WS_WB     (WS_TPW   + (size_t)EE*256)       // edge wfrags 152*512 bf16
#define WS_WP     (WS_WB    + (size_t)152*256)      // post wfrags 352*512 bf16
#define WS_WN     (WS_WP    + (size_t)352*256)      // node wfrags 144*512 bf16

__device__ __forceinline__ float silu_f(float x) {
    return x * __builtin_amdgcn_rcpf(1.f + __expf(-x));
}
__device__ __forceinline__ float sigm_f(float x) {
    return __builtin_amdgcn_rcpf(1.f + __expf(-x));
}

__device__ __forceinline__ unsigned short f2bf(float x) {
    union { float f; unsigned u; } uf; uf.f = x;
    unsigned r = uf.u + 0x7FFFu + ((uf.u >> 16) & 1u);   // RNE
    return (unsigned short)(r >> 16);
}

// ---------------------------------------------------------------------------
// CSR build: count -> scan -> scatter   (receiver-sorted edge slots)
// ---------------------------------------------------------------------------
__global__ __launch_bounds__(256) void csr_count(
    const int* __restrict__ edge_index, int* __restrict__ counts)
{
    int e = blockIdx.x * 256 + threadIdx.x;
    atomicAdd(&counts[edge_index[EE + e]], 1);
}

__global__ __launch_bounds__(1024) void csr_scan(
    const int* __restrict__ counts, int* __restrict__ offs, int* __restrict__ cursor)
{
    __shared__ int sums[1024];
    const int t = threadIdx.x;
    int local[8];
    int s = 0;
#pragma unroll
    for (int k = 0; k < 8; ++k) { local[k] = s; s += counts[t * 8 + k]; }
    sums[t] = s;
    __syncthreads();
    for (int d = 1; d < 1024; d <<= 1) {
        int v = (t >= d) ? sums[t - d] : 0;
        __syncthreads();
        sums[t] += v;
        __syncthreads();
    }
    int base = (t > 0) ? sums[t - 1] : 0;
#pragma unroll
    for (int k = 0; k < 8; ++k) {
        offs[t * 8 + k] = base + local[k];
        cursor[t * 8 + k] = base + local[k];
    }
    if (t == 1023) offs[8192] = sums[1023];
}

__global__ __launch_bounds__(256) void csr_scatter(
    const int* __restrict__ edge_index, int* __restrict__ cursor, int* __restrict__ pos)
{
    int e = blockIdx.x * 256 + threadIdx.x;
    pos[e] = atomicAdd(&cursor[edge_index[EE + e]], 1);
}

// ---------------------------------------------------------------------------
// MERGED weight pre-swizzle (verified round 11): one dispatch, three ranges.
// ---------------------------------------------------------------------------
__global__ __launch_bounds__(256) void swizzle_all(
    const float* __restrict__ Wr0, const float* __restrict__ Wd0,
    const float* __restrict__ Wr1, const float* __restrict__ Wr2,
    const float* __restrict__ Wr3,
    const float* __restrict__ W1s, const float* __restrict__ W1v,
    const float* __restrict__ Wrs, const float* __restrict__ Wrv,
    const float* __restrict__ W2s, const float* __restrict__ W2v,
    const float* __restrict__ Wss, const float* __restrict__ Wus,
    const float* __restrict__ Wsv, const float* __restrict__ Wuv,
    const float* __restrict__ Wsrc, const float* __restrict__ Wtgt,
    unsigned short* __restrict__ WBall, unsigned short* __restrict__ WPall,
    unsigned short* __restrict__ WN)
{
    const int b = blockIdx.x;
    unsigned short o[8];

    if (b < 38) {
        // ---- edge weights (WBall), 152 frags
        int fid = b * 256 + threadIdx.x;
        int lane = fid & 63;
        int frag = fid >> 6;
        int k0 = (lane >> 4) * 8;
        int n0 = lane & 15;

        if (frag < 72) {
            int kt = frag >> 3, nt = frag & 7;
            int n = nt * 16 + n0;
#pragma unroll
            for (int j = 0; j < 8; ++j) {
                int k = kt * 32 + k0 + j;
                float v = 0.f;
                if (k < 264) v = ((n < 64) ? Wr0[k * 64 + n] : Wd0[k * 64 + (n - 64)]) * INV_SQRT264;
                o[j] = f2bf(v);
            }
        } else if (frag < 80) {
            int fl = frag - 72;
            int kt = fl >> 2, nt = fl & 3;
            int n = nt * 16 + n0;
#pragma unroll
            for (int j = 0; j < 8; ++j)
                o[j] = f2bf(Wr1[(kt * 32 + k0 + j) * 64 + n] * 0.125f);
        } else if (frag < 88) {
            int fl = frag - 80;
            int kt = fl >> 2, nt = fl & 3;
            int n = nt * 16 + n0;
#pragma unroll
            for (int j = 0; j < 8; ++j)
                o[j] = f2bf(Wr2[(kt * 32 + k0 + j) * 64 + n] * 0.125f);
        } else {
            int fl = frag - 88;
            int kt = fl >> 5, nt = fl & 31;
            int n = nt * 16 + n0;
            int q = n >> 6;
            float sc = (q < 2) ? 0.125f : 0.125f * INV_SQRT3;
#pragma unroll
            for (int j = 0; j < 8; ++j)
                o[j] = f2bf(Wr3[(kt * 32 + k0 + j) * 512 + n] * sc);
        }
        uint4 pk;
        pk.x = (unsigned)o[0] | ((unsigned)o[1] << 16);
        pk.y = (unsigned)o[2] | ((unsigned)o[3] << 16);
        pk.z = (unsigned)o[4] | ((unsigned)o[5] << 16);
        pk.w = (unsigned)o[6] | ((unsigned)o[7] << 16);
        *(uint4*)(WBall + (size_t)fid * 8) = pk;
    } else if (b < 126) {
        // ---- post weights (WPall), 352 frags
        int fid = (b - 38) * 256 + threadIdx.x;
        int lane = fid & 63;
        int frag = fid >> 6;
        int k0 = (lane >> 4) * 8;
        int n0 = lane & 15;

        if (frag < 192) {
            int kt = frag >> 4, nt = frag & 15;
            int n = nt * 16 + n0;
#pragma unroll
            for (int j = 0; j < 8; ++j) {
                int k = kt * 32 + k0 + j;
                float v = (k < 256) ? W1s[k * 256 + n] * 0.0625f
                                    : Wrs[(k - 256) * 256 + n] * INV_SQRT128;
                o[j] = f2bf(v);
            }
        } else if (frag < 288) {
            int fl = frag - 192;
            int kt = fl >> 3, nt = fl & 7;
            int n = nt * 16 + n0;
#pragma unroll
            for (int j = 0; j < 8; ++j) {
                int k = kt * 32 + k0 + j;
                float v = (k < 256) ? W1v[k * 128 + n] * 0.0625f
                                    : Wrv[(k - 256) * 128 + n] * INV_SQRT128;
                o[j] = f2bf(v);
            }
        } else if (frag < 320) {
            int fl = frag - 288;
            int kt = fl >> 3, nt = fl & 7;
            int n = nt * 16 + n0;
#pragma unroll
            for (int j = 0; j < 8; ++j)
                o[j] = f2bf(W2s[(kt * 32 + k0 + j) * 128 + n] * INV_SQRT128);
        } else {
            int fl = frag - 320;
            int kt = fl >> 3, nt = fl & 7;
            int n = nt * 16 + n0;
#pragma unroll
            for (int j = 0; j < 8; ++j)
                o[j] = f2bf(W2v[(kt * 32 + k0 + j) * 128 + n] * INV_SQRT128);
        }
        uint4 pk;
        pk.x = (unsigned)o[0] | ((unsigned)o[1] << 16);
        pk.y = (unsigned)o[2] | ((unsigned)o[3] << 16);
        pk.z = (unsigned)o[4] | ((unsigned)o[5] << 16);
        pk.w = (unsigned)o[6] | ((unsigned)o[7] << 16);
        *(uint4*)(WPall + (size_t)fid * 8) = pk;
    } else {
        // ---- node weights (WN), 144 frags
        int fid = (b - 126) * 256 + threadIdx.x;
        int lane = fid & 63;
        int frag = fid >> 6;
        int k0 = (lane >> 4) * 8;
        int m0 = lane & 15;

        if (frag < 128) {
            int g = frag >> 5;
            int fl = frag & 31;
            int kt = fl >> 3, mt = fl & 7;
            const float* W = (g == 0) ? Wss : (g == 1) ? Wus : (g == 2) ? Wsv : Wuv;
            int m = mt * 16 + m0;
#pragma unroll
            for (int j = 0; j < 8; ++j)
                o[j] = f2bf(W[(kt * 32 + k0 + j) * 128 + m] * INV_SQRT128);
        } else {
            int g = (frag - 128) >> 3;
            int mt = frag & 7;
            const float* W = g ? Wtgt : Wsrc;
            int m = mt * 16 + m0;
#pragma unroll
            for (int j = 0; j < 8; ++j) {
                int k = k0 + j;
                o[j] = f2bf((k < AA) ? W[k * 128 + m] * INV_SQRT10 : 0.f);
            }
        }
        uint4 pk;
        pk.x = (unsigned)o[0] | ((unsigned)o[1] << 16);
        pk.y = (unsigned)o[2] | ((unsigned)o[3] << 16);
        pk.z = (unsigned)o[4] | ((unsigned)o[5] << 16);
        pk.w = (unsigned)o[6] | ((unsigned)o[7] << 16);
        *(uint4*)(WN + (size_t)fid * 8) = pk;
    }
}

// ---------------------------------------------------------------------------
// Kernel A: per-node precompute on MFMA (unchanged, verified).
// ---------------------------------------------------------------------------
#define PNB 16
__global__ __launch_bounds__(256) void node_pre_mfma(
    const float* __restrict__ node_attrs, const float* __restrict__ node_feats,
    const unsigned short* __restrict__ WN,
    float* __restrict__ sc_out, uint2* __restrict__ xq,
    unsigned short* __restrict__ us_b, unsigned short* __restrict__ uv_b,
    unsigned short* __restrict__ srcEb, unsigned short* __restrict__ tgtEb)
{
    __shared__ __align__(16) unsigned short Xs[PNB][136];
    __shared__ __align__(16) unsigned short Xv[3][PNB][136];
    __shared__ __align__(16) unsigned short Xa[PNB][40];
    const int t = threadIdx.x;
    const int l = t & 63, w = t >> 6;
    const int quad = l >> 4, lr = l & 15;
    const int n0 = blockIdx.x * PNB;

    // ---- stage node_feats (f32 -> bf16): thread (r=t>>4, m=t&15)
    {
        const int r = t >> 4, m = t & 15;
        const float* src = node_feats + (size_t)(n0 + r) * 512;
        float4 s0 = *(const float4*)(src + 8 * m);
        float4 s1 = *(const float4*)(src + 8 * m + 4);
        uint4 sp;
        sp.x = (unsigned)f2bf(s0.x) | ((unsigned)f2bf(s0.y) << 16);
        sp.y = (unsigned)f2bf(s0.z) | ((unsigned)f2bf(s0.w) << 16);
        sp.z = (unsigned)f2bf(s1.x) | ((unsigned)f2bf(s1.y) << 16);
        sp.w = (unsigned)f2bf(s1.z) | ((unsigned)f2bf(s1.w) << 16);
        *(uint4*)&Xs[r][8 * m] = sp;

        float4 q[6];
#pragma unroll
        for (int jj = 0; jj < 6; ++jj)
            q[jj] = *(const float4*)(src + 128 + 24 * m + 4 * jj);
        const float* qf = &q[0].x;
        unsigned short vb[3][8];
#pragma unroll
        for (int u = 0; u < 8; ++u) {
#pragma unroll
            for (int c = 0; c < 3; ++c)
                vb[c][u] = f2bf(qf[u * 3 + c]);
        }
#pragma unroll
        for (int c = 0; c < 3; ++c) {
            uint4 vp;
            vp.x = (unsigned)vb[c][0] | ((unsigned)vb[c][1] << 16);
            vp.y = (unsigned)vb[c][2] | ((unsigned)vb[c][3] << 16);
            vp.z = (unsigned)vb[c][4] | ((unsigned)vb[c][5] << 16);
            vp.w = (unsigned)vb[c][6] | ((unsigned)vb[c][7] << 16);
            *(uint4*)&Xv[c][r][8 * m] = vp;
        }
    }
    // ---- stage attrs (padded K=32)
    for (int idx = t; idx < PNB * 32; idx += 256) {
        int r = idx >> 5, k = idx & 31;
        float v = (k < AA) ? node_attrs[(size_t)(n0 + r) * AA + k] : 0.f;
        Xa[r][k] = f2bf(v);
    }
    __syncthreads();

    const short8* WNf = (const short8*)WN;
    const int n = n0 + lr;

#pragma unroll
    for (int mi = 0; mi < 2; ++mi) {
        const int mt = w * 2 + mi;
        const int j0 = mt * 16 + quad * 4;

        // attr GEMM (K=32): srcE / tgtE
        floatx4 cSrc = (floatx4){0.f, 0.f, 0.f, 0.f};
        floatx4 cTgt = (floatx4){0.f, 0.f, 0.f, 0.f};
        {
            short8 ba = *(const short8*)&Xa[lr][quad * 8];
            cSrc = __builtin_amdgcn_mfma_f32_16x16x32_bf16(WNf[(size_t)(128 + mt) * 64 + l], ba, cSrc, 0, 0, 0);
            cTgt = __builtin_amdgcn_mfma_f32_16x16x32_bf16(WNf[(size_t)(136 + mt) * 64 + l], ba, cTgt, 0, 0, 0);
        }
        // s GEMMs (K=128): sc_s / us
        floatx4 cS = (floatx4){0.f, 0.f, 0.f, 0.f};
        floatx4 cU = (floatx4){0.f, 0.f, 0.f, 0.f};
#pragma unroll
        for (int kt = 0; kt < 4; ++kt) {
            short8 bs = *(const short8*)&Xs[lr][kt * 32 + quad * 8];
            cS = __builtin_amdgcn_mfma_f32_16x16x32_bf16(WNf[(size_t)(kt * 8 + mt) * 64 + l], bs, cS, 0, 0, 0);
            cU = __builtin_amdgcn_mfma_f32_16x16x32_bf16(WNf[(size_t)(32 + kt * 8 + mt) * 64 + l], bs, cU, 0, 0, 0);
        }
        // v GEMMs (K=128 x 3 channels): sc_v / uv
        floatx4 cSV[3], cUV[3];
#pragma unroll
        for (int c = 0; c < 3; ++c) {
            cSV[c] = (floatx4){0.f, 0.f, 0.f, 0.f};
            cUV[c] = (floatx4){0.f, 0.f, 0.f, 0.f};
#pragma unroll
            for (int kt = 0; kt < 4; ++kt) {
                short8 bv = *(const short8*)&Xv[c][lr][kt * 32 + quad * 8];
                cSV[c] = __builtin_amdgcn_mfma_f32_16x16x32_bf16(WNf[(size_t)(64 + kt * 8 + mt) * 64 + l], bv, cSV[c], 0, 0, 0);
                cUV[c] = __builtin_amdgcn_mfma_f32_16x16x32_bf16(WNf[(size_t)(96 + kt * 8 + mt) * 64 + l], bv, cUV[c], 0, 0, 0);
            }
        }

        // ---- epilogue: packed stores (node n, outputs j0..j0+3)
        {
            float4 o;
            o.x = cS[0]; o.y = cS[1]; o.z = cS[2]; o.w = cS[3];
            *(float4*)(sc_out + (size_t)n * 512 + j0) = o;
        }
        {
            float vv[12];
#pragma unroll
            for (int reg = 0; reg < 4; ++reg)
#pragma unroll
                for (int c = 0; c < 3; ++c) vv[reg * 3 + c] = cSV[c][reg];
            float* dst = sc_out + (size_t)n * 512 + 128 + j0 * 3;
#pragma unroll
            for (int qq = 0; qq < 3; ++qq) {
                float4 o;
                o.x = vv[qq * 4]; o.y = vv[qq * 4 + 1]; o.z = vv[qq * 4 + 2]; o.w = vv[qq * 4 + 3];
                *(float4*)(dst + qq * 4) = o;
            }
        }
        unsigned short ub[4], vxb[4], vyb[4], vzb[4];
#pragma unroll
        for (int reg = 0; reg < 4; ++reg) {
            ub[reg] = f2bf(cU[reg]);
            vxb[reg] = f2bf(cUV[0][reg]);
            vyb[reg] = f2bf(cUV[1][reg]);
            vzb[reg] = f2bf(cUV[2][reg]);
        }
        {
            uint2 p;
            p.x = (unsigned)ub[0] | ((unsigned)ub[1] << 16);
            p.y = (unsigned)ub[2] | ((unsigned)ub[3] << 16);
            *(uint2*)(us_b + (size_t)n * 128 + j0) = p;
        }
        {
            uint2 p;
            p.x = (unsigned)vxb[0] | ((unsigned)vxb[1] << 16);
            p.y = (unsigned)vxb[2] | ((unsigned)vxb[3] << 16);
            *(uint2*)(uv_b + ((size_t)0 * NN + n) * 128 + j0) = p;
            p.x = (unsigned)vyb[0] | ((unsigned)vyb[1] << 16);
            p.y = (unsigned)vyb[2] | ((unsigned)vyb[3] << 16);
            *(uint2*)(uv_b + ((size_t)1 * NN + n) * 128 + j0) = p;
            p.x = (unsigned)vzb[0] | ((unsigned)vzb[1] << 16);
            p.y = (unsigned)vzb[2] | ((unsigned)vzb[3] << 16);
            *(uint2*)(uv_b + ((size_t)2 * NN + n) * 128 + j0) = p;
        }
        {
            uint4 x0, x1;
            x0.x = (unsigned)ub[0] | ((unsigned)vxb[0] << 16);
            x0.y = (unsigned)vyb[0] | ((unsigned)vzb[0] << 16);
            x0.z = (unsigned)ub[1] | ((unsigned)vxb[1] << 16);
            x0.w = (unsigned)vyb[1] | ((unsigned)vzb[1] << 16);
            x1.x = (unsigned)ub[2] | ((unsigned)vxb[2] << 16);
            x1.y = (unsigned)vyb[2] | ((unsigned)vzb[2] << 16);
            x1.z = (unsigned)ub[3] | ((unsigned)vxb[3] << 16);
            x1.w = (unsigned)vyb[3] | ((unsigned)vzb[3] << 16);
            uint4* xp = (uint4*)(xq + (size_t)n * 128 + j0);
            xp[0] = x0; xp[1] = x1;
        }
        {
            uint2 p;
            p.x = (unsigned)f2bf(cSrc[0]) | ((unsigned)f2bf(cSrc[1]) << 16);
            p.y = (unsigned)f2bf(cSrc[2]) | ((unsigned)f2bf(cSrc[3]) << 16);
            *(uint2*)(srcEb + (size_t)n * 128 + j0) = p;
            p.x = (unsigned)f2bf(cTgt[0]) | ((unsigned)f2bf(cTgt[1]) << 16);
            p.y = (unsigned)f2bf(cTgt[2]) | ((unsigned)f2bf(cTgt[3]) << 16);
            *(uint2*)(tgtEb + (size_t)n * 128 + j0) = p;
        }
    }
}

// ---------------------------------------------------------------------------
// Kernel B: per-edge MLP on MFMA (round-11 verified best: (256,4), phase 3
// incl, B-frags from L2 — WB1/2 LDS staging reverted: it cost +13% FETCH,
// +12 VGPR, +3µs).
// ---------------------------------------------------------------------------
#define EBK 64
#define H1OFF 80
#define HLD 152   // LDS row stride (u16): 304B = odd multiple of 16B
__global__ __launch_bounds__(256, 4) void edge_mlp(
    const float* __restrict__ edge_attrs, const float* __restrict__ edge_feats,
    const int* __restrict__ edge_index,
    const unsigned short* __restrict__ srcEb, const unsigned short* __restrict__ tgtEb,
    const unsigned short* __restrict__ WB0, const unsigned short* __restrict__ WB1,
    const unsigned short* __restrict__ WB2, const unsigned short* __restrict__ WB3,
    const float* __restrict__ Wd1, const int* __restrict__ pos,
    unsigned short* __restrict__ tpwP, float* __restrict__ metaP)
{
    __shared__ __align__(16) unsigned short Hb[4][16][HLD];

    const int t = threadIdx.x;
    const int l = t & 63;
    const int w = t >> 6;
    const int quad = l >> 4;
    const int lr = l & 15;
    const int e0 = blockIdx.x * EBK + w * 16;   // this wave's 16 edges

    // Row-edge for this lane's A-fragments (A row = lane&15).
    const int eA = e0 + lr;
    const int sndA = edge_index[eA];
    const int rcvA = edge_index[EE + eA];
    const unsigned short* spp = srcEb + (size_t)sndA * 128;
    const unsigned short* tpp = tgtEb + (size_t)rcvA * 128;

    // meta m0: one lane per edge (quad 0 covers the wave's 16 edges)
    if (quad == 0) {
        float4 ya = *(const float4*)(edge_attrs + (size_t)eA * 4);
        float4 m;
        m.x = __int_as_float(sndA); m.y = ya.y; m.z = ya.z; m.w = ya.w;
        *(float4*)(metaP + (size_t)pos[eA] * 8) = m;
    }

    // ---- load all 9 A-fragments for ef row eA (cols kt*32 + quad*8 .. +8)
    short8 afr[9];
    {
        const int cq = quad * 8;
        if (quad == 0) {
            float4 f0 = *(const float4*)(edge_feats + (size_t)eA * 8);
            float4 f1 = *(const float4*)(edge_feats + (size_t)eA * 8 + 4);
            union { short8 v; unsigned u[4]; } pk;
            pk.u[0] = (unsigned)f2bf(f0.x) | ((unsigned)f2bf(f0.y) << 16);
            pk.u[1] = (unsigned)f2bf(f0.z) | ((unsigned)f2bf(f0.w) << 16);
            pk.u[2] = (unsigned)f2bf(f1.x) | ((unsigned)f2bf(f1.y) << 16);
            pk.u[3] = (unsigned)f2bf(f1.z) | ((unsigned)f2bf(f1.w) << 16);
            afr[0] = pk.v;
        } else {
            afr[0] = *(const short8*)(spp + (cq - 8));
        }
#pragma unroll
        for (int kt = 1; kt < 9; ++kt) {
            const int c = kt * 32 + cq;
            if (c < 136) {
                afr[kt] = *(const short8*)(spp + (c - 8));
            } else if (c < 264) {
                afr[kt] = *(const short8*)(tpp + (c - 136));
            } else {
                short8 z = {0, 0, 0, 0, 0, 0, 0, 0};
                afr[kt] = z;
            }
        }
    }

    unsigned short (*H)[HLD] = Hb[w];

    // ---- phase 0: first layer, r-path AND d-path in ONE K=288 pass
    {
        floatx4 c0[8];
#pragma unroll
        for (int nt = 0; nt < 8; ++nt) c0[nt] = (floatx4){0.f, 0.f, 0.f, 0.f};
#pragma unroll
        for (int kt = 0; kt < 9; ++kt) {
            const short8* bp = (const short8*)WB0 + (size_t)(kt * 8) * 64 + l;
#pragma unroll
            for (int nt = 0; nt < 8; ++nt)
                c0[nt] = __builtin_amdgcn_mfma_f32_16x16x32_bf16(afr[kt], bp[nt * 64], c0[nt], 0, 0, 0);
        }

        // r-path (nt 0..3): silu -> LDS h0
#pragma unroll
        for (int nt = 0; nt < 4; ++nt)
#pragma unroll
            for (int reg = 0; reg < 4; ++reg)
                H[quad * 4 + reg][nt * 16 + lr] = f2bf(silu_f(c0[nt][reg]));

        // d-path (nt 4..7): dot(Wd1) via shfl reduce -> meta
        float wd1v[4];
#pragma unroll
        for (int q2 = 0; q2 < 4; ++q2) wd1v[q2] = Wd1[q2 * 16 + lr] * 0.125f;
        float dp[4] = {0.f, 0.f, 0.f, 0.f};
#pragma unroll
        for (int nt = 0; nt < 4; ++nt)
#pragma unroll
            for (int reg = 0; reg < 4; ++reg)
                dp[reg] += silu_f(c0[nt + 4][reg]) * wd1v[nt];
#pragma unroll
        for (int m2 = 1; m2 < 16; m2 <<= 1) {
#pragma unroll
            for (int reg = 0; reg < 4; ++reg) dp[reg] += __shfl_xor(dp[reg], m2);
        }
        if (lr == 0) {
#pragma unroll
            for (int reg = 0; reg < 4; ++reg)
                metaP[(size_t)pos[e0 + quad * 4 + reg] * 8 + 4] = tanhf(dp[reg] * dp[reg]);
        }
    }

    const unsigned short* hrow0 = &H[lr][quad * 8];
    const unsigned short* hrow1 = &H[lr][H1OFF + quad * 8];

    // ---- phase 1: h0 -> h1 (64->64), silu -> LDS h1
    {
        floatx4 c1[4];
#pragma unroll
        for (int nt = 0; nt < 4; ++nt) c1[nt] = (floatx4){0.f, 0.f, 0.f, 0.f};
#pragma unroll
        for (int kt = 0; kt < 2; ++kt) {
            short8 af = *(const short8*)(hrow0 + kt * 32);
            const short8* bp = (const short8*)WB1 + (size_t)(kt * 4) * 64 + l;
#pragma unroll
            for (int nt = 0; nt < 4; ++nt)
                c1[nt] = __builtin_amdgcn_mfma_f32_16x16x32_bf16(af, bp[nt * 64], c1[nt], 0, 0, 0);
        }
#pragma unroll
        for (int nt = 0; nt < 4; ++nt)
#pragma unroll
            for (int reg = 0; reg < 4; ++reg)
                H[quad * 4 + reg][H1OFF + nt * 16 + lr] = f2bf(silu_f(c1[nt][reg]));
    }

    // ---- phase 2: h1 -> h2 (64->64), silu -> LDS h0 (overwrite)
    {
        floatx4 c2[4];
#pragma unroll
        for (int nt = 0; nt < 4; ++nt) c2[nt] = (floatx4){0.f, 0.f, 0.f, 0.f};
#pragma unroll
        for (int kt = 0; kt < 2; ++kt) {
            short8 af = *(const short8*)(hrow1 + kt * 32);
            const short8* bp = (const short8*)WB2 + (size_t)(kt * 4) * 64 + l;
#pragma unroll
            for (int nt = 0; nt < 4; ++nt)
                c2[nt] = __builtin_amdgcn_mfma_f32_16x16x32_bf16(af, bp[nt * 64], c2[nt], 0, 0, 0);
        }
#pragma unroll
        for (int nt = 0; nt < 4; ++nt)
#pragma unroll
            for (int reg = 0; reg < 4; ++reg)
                H[quad * 4 + reg][nt * 16 + lr] = f2bf(silu_f(c2[nt][reg]));
    }

    // ---- phase 3: h2 -> tpw (64 -> 512), fold y0, scatter by slot
    {
        int slotr[4];
        float y0r[4];
#pragma unroll
        for (int reg = 0; reg < 4; ++reg) {
            const int er = e0 + quad * 4 + reg;
            slotr[reg] = pos[er];
            y0r[reg] = edge_attrs[(size_t)er * 4];
        }
        short8 af0 = *(const short8*)(hrow0);
        short8 af1 = *(const short8*)(hrow0 + 32);
        uint2* tpw2 = (uint2*)tpwP;
#pragma unroll
        for (int j2 = 0; j2 < 8; ++j2) {
            floatx4 c3[4];
#pragma unroll
            for (int g = 0; g < 4; ++g) c3[g] = (floatx4){0.f, 0.f, 0.f, 0.f};
#pragma unroll
            for (int g = 0; g < 4; ++g) {
                const short8* b0 = (const short8*)WB3 + (size_t)(g * 8 + j2) * 64 + l;
                const short8* b1 = (const short8*)WB3 + (size_t)(32 + g * 8 + j2) * 64 + l;
                c3[g] = __builtin_amdgcn_mfma_f32_16x16x32_bf16(af0, *b0, c3[g], 0, 0, 0);
                c3[g] = __builtin_amdgcn_mfma_f32_16x16x32_bf16(af1, *b1, c3[g], 0, 0, 0);
            }
            const int u = j2 * 16 + lr;
#pragma unroll
            for (int reg = 0; reg < 4; ++reg) {
                float w1v = c3[0][reg] * y0r[reg];
                float w2v = c3[1][reg];
                float w3v = c3[2][reg] * y0r[reg];
                float w4v = c3[3][reg];
                uint2 p;
                p.x = (unsigned)f2bf(w1v) | ((unsigned)f2bf(w2v) << 16);
                p.y = (unsigned)f2bf(w3v) | ((unsigned)f2bf(w4v) << 16);
                tpw2[(size_t)slotr[reg] * 128 + u] = p;
            }
        }
    }
}

// ---------------------------------------------------------------------------
// Kernel C: per-node gather (verified round 11: 8/4/1 unroll).
// ---------------------------------------------------------------------------
__global__ __launch_bounds__(128) void node_gather(
    const unsigned short* __restrict__ tpwP, const float* __restrict__ metaP,
    const int* __restrict__ offs, const uint2* __restrict__ xq,
    const float* __restrict__ alpha_p, const float* __restrict__ beta_p,
    unsigned short* __restrict__ msgs_b, unsigned short* __restrict__ msgv_b)
{
    const int n = blockIdx.x;
    const int j = threadIdx.x;
    const int s0 = offs[n], s1 = offs[n + 1];
    const uint2* tpw2 = (const uint2*)tpwP;

    float as0 = 0.f, as1 = 0.f;
    float av0x = 0.f, av0y = 0.f, av0z = 0.f;
    float av1x = 0.f, av1y = 0.f, av1z = 0.f;
    float dsum = 0.f;

    int s = s0;
    for (; s + 8 <= s1; s += 8) {
        float4 ma[8]; float dn[8]; uint2 wv[8]; uint2 xv[8];
#pragma unroll
        for (int k = 0; k < 8; ++k) {
            ma[k] = *(const float4*)&metaP[(size_t)(s + k) * 8];
            dn[k] = metaP[(size_t)(s + k) * 8 + 4];
            wv[k] = tpw2[(size_t)(s + k) * 128 + j];
        }
#pragma unroll
        for (int k = 0; k < 8; ++k)
            xv[k] = xq[(size_t)__float_as_int(ma[k].x) * 128 + j];
#pragma unroll
        for (int k = 0; k < 8; ++k) {
            const float y1x = ma[k].y, y1y = ma[k].z, y1z = ma[k].w;
            dsum += dn[k];
            const float w1  = __uint_as_float(wv[k].x << 16);
            const float w2  = __uint_as_float(wv[k].x & 0xffff0000u);
            const float w3  = __uint_as_float(wv[k].y << 16);
            const float w4  = __uint_as_float(wv[k].y & 0xffff0000u);
            const float xs  = __uint_as_float(xv[k].x << 16);
            const float xvx = __uint_as_float(xv[k].x & 0xffff0000u);
            const float xvy = __uint_as_float(xv[k].y << 16);
            const float xvz = __uint_as_float(xv[k].y & 0xffff0000u);
            as0 += w1 * xs;
            as1 += w4 * (xvx * y1x + xvy * y1y + xvz * y1z);
            const float b2 = w2 * xs;
            av0x += b2 * y1x; av0y += b2 * y1y; av0z += b2 * y1z;
            av1x += w3 * xvx; av1y += w3 * xvy; av1z += w3 * xvz;
        }
    }
    for (; s + 4 <= s1; s += 4) {
        float4 ma[4]; float dn[4]; uint2 wv[4]; uint2 xv[4];
#pragma unroll
        for (int k = 0; k < 4; ++k) {
            ma[k] = *(const float4*)&metaP[(size_t)(s + k) * 8];
            dn[k] = metaP[(size_t)(s + k) * 8 + 4];
            wv[k] = tpw2[(size_t)(s + k) * 128 + j];
        }
#pragma unroll
        for (int k = 0; k < 4; ++k)
            xv[k] = xq[(size_t)__float_as_int(ma[k].x) * 128 + j];
#pragma unroll
        for (int k = 0; k < 4; ++k) {
            const float y1x = ma[k].y, y1y = ma[k].z, y1z = ma[k].w;
            dsum += dn[k];
            const float w1  = __uint_as_float(wv[k].x << 16);
            const float w2  = __uint_as_float(wv[k].x & 0xffff0000u);
            const float w3  = __uint_as_float(wv[k].y << 16);
            const float w4  = __uint_as_float(wv[k].y & 0xffff0000u);
            const float xs  = __uint_as_float(xv[k].x << 16);
            const float xvx = __uint_as_float(xv[k].x & 0xffff0000u);
            const float xvy = __uint_as_float(xv[k].y << 16);
            const float xvz = __uint_as_float(xv[k].y & 0xffff0000u);
            as0 += w1 * xs;
            as1 += w4 * (xvx * y1x + xvy * y1y + xvz * y1z);
            const float b2 = w2 * xs;
            av0x += b2 * y1x; av0y += b2 * y1y; av0z += b2 * y1z;
            av1x += w3 * xvx; av1y += w3 * xvy; av1z += w3 * xvz;
        }
    }
    for (; s < s1; ++s) {
        const float4 m0 = *(const float4*)&metaP[(size_t)s * 8];
        const float dns = metaP[(size_t)s * 8 + 4];
        const int snd = __float_as_int(m0.x);
        const float y1x = m0.y, y1y = m0.z, y1z = m0.w;
        dsum += dns;
        uint2 wv = tpw2[(size_t)s * 128 + j];
        uint2 xv = xq[(size_t)snd * 128 + j];
        const float w1  = __uint_as_float(wv.x << 16);
        const float w2  = __uint_as_float(wv.x & 0xffff0000u);
        const float w3  = __uint_as_float(wv.y << 16);
        const float w4  = __uint_as_float(wv.y & 0xffff0000u);
        const float xs  = __uint_as_float(xv.x << 16);
        const float xvx = __uint_as_float(xv.x & 0xffff0000u);
        const float xvy = __uint_as_float(xv.y << 16);
        const float xvz = __uint_as_float(xv.y & 0xffff0000u);
        as0 += w1 * xs;
        as1 += w4 * (xvx * y1x + xvy * y1y + xvz * y1z);
        const float b2 = w2 * xs;
        av0x += b2 * y1x; av0y += b2 * y1y; av0z += b2 * y1z;
        av1x += w3 * xvx; av1y += w3 * xvy; av1z += w3 * xvz;
    }

    const float invden = 1.f / (dsum * (*beta_p) + (*alpha_p));

    msgs_b[(size_t)n * 256 + j]       = f2bf(as0 * invden);
    msgs_b[(size_t)n * 256 + 128 + j] = f2bf(as1 * invden);
    msgv_b[((size_t)0 * NN + n) * 256 + j]       = f2bf(av0x * invden);
    msgv_b[((size_t)0 * NN + n) * 256 + 128 + j] = f2bf(av1x * invden);
    msgv_b[((size_t)1 * NN + n) * 256 + j]       = f2bf(av0y * invden);
    msgv_b[((size_t)1 * NN + n) * 256 + 128 + j] = f2bf(av1y * invden);
    msgv_b[((size_t)2 * NN + n) * 256 + j]       = f2bf(av0z * invden);
    msgv_b[((size_t)2 * NN + n) * 256 + 128 + j] = f2bf(av1z * invden);
}

// ---------------------------------------------------------------------------
// Kernel D: FUSED post epilogue (verified, unchanged).
// ---------------------------------------------------------------------------
#define DNP 16
__global__ __launch_bounds__(256) void post_fused(
    const unsigned short* __restrict__ msgs_b, const unsigned short* __restrict__ us_b,
    const unsigned short* __restrict__ msgv_b, const unsigned short* __restrict__ uv_b,
    const unsigned short* __restrict__ WPs, const unsigned short* __restrict__ WPv,
    const unsigned short* __restrict__ W2ss, const unsigned short* __restrict__ W2vs,
    float* __restrict__ out)
{
    __shared__ __align__(16) unsigned short osb[DNP][136];
    __shared__ __align__(16) unsigned short ovb[3][DNP][136];
    __shared__ float gateL[DNP][128];

    const int t = threadIdx.x;
    const int l = t & 63, w = t >> 6;         // 4 waves
    const int quad = l >> 4, lr = l & 15;
    const int n0 = blockIdx.x * DNP;
    const int nh = w;                         // 0..3 N-quarter
    const int n = n0 + lr;                    // this lane's A-row node

    const int cLo = (nh * 6) >> 3;
    const int cHi = (nh * 6 + 5) >> 3;

    const unsigned short* sRow  = msgs_b + (size_t)n * 256;
    const unsigned short* uRow  = us_b   + (size_t)n * 128;
    const unsigned short* vRowL = msgv_b + ((size_t)cLo * NN + n) * 256;
    const unsigned short* uRowL = uv_b   + ((size_t)cLo * NN + n) * 128;
    const unsigned short* vRowH = msgv_b + ((size_t)cHi * NN + n) * 256;
    const unsigned short* uRowH = uv_b   + ((size_t)cHi * NN + n) * 128;

    // ---- first layer: K=384 (12 kt), s: 4 N-tiles, v: 6 N-tiles
    floatx4 accS[4], accV[6];
#pragma unroll
    for (int i = 0; i < 4; ++i) accS[i] = (floatx4){0.f, 0.f, 0.f, 0.f};
#pragma unroll
    for (int i = 0; i < 6; ++i) accV[i] = (floatx4){0.f, 0.f, 0.f, 0.f};

#pragma unroll
    for (int kt = 0; kt < 12; ++kt) {
        const int col = kt * 32 + quad * 8;
        short8 aS = (col < 256) ? *(const short8*)(sRow + col)
                                : *(const short8*)(uRow + col - 256);
        short8 aV0 = (col < 256) ? *(const short8*)(vRowL + col)
                                 : *(const short8*)(uRowL + col - 256);
        short8 aV1;
        if (cHi != cLo)
            aV1 = (col < 256) ? *(const short8*)(vRowH + col)
                              : *(const short8*)(uRowH + col - 256);
        else
            aV1 = aV0;

        const short8* bpS = (const short8*)WPs + (size_t)(kt * 16 + nh * 4) * 64 + l;
#pragma unroll
        for (int i = 0; i < 4; ++i)
            accS[i] = __builtin_amdgcn_mfma_f32_16x16x32_bf16(aS, bpS[i * 64], accS[i], 0, 0, 0);
#pragma unroll
        for (int i = 0; i < 6; ++i) {
            const int vt = nh * 6 + i;
            const short8* bpV = (const short8*)WPv + (size_t)(kt * 8 + (vt & 7)) * 64 + l;
            short8 a = ((vt >> 3) == cLo) ? aV0 : aV1;
            accV[i] = __builtin_amdgcn_mfma_f32_16x16x32_bf16(a, *bpV, accV[i], 0, 0, 0);
        }
    }

    // ---- s outputs: tiles 0..7 -> silu -> osb; 8..15 -> sigmoid -> gateL
#pragma unroll
    for (int i = 0; i < 4; ++i) {
        const int tile = nh * 4 + i;
#pragma unroll
        for (int reg = 0; reg < 4; ++reg) {
            const int row = quad * 4 + reg;
            const float v = accS[i][reg];
            if (tile < 8) osb[row][tile * 16 + lr] = f2bf(silu_f(v));
            else          gateL[row][(tile - 8) * 16 + lr] = sigm_f(v);
        }
    }
    __syncthreads();

    // ---- gate the v accumulators -> ovb
#pragma unroll
    for (int i = 0; i < 6; ++i) {
        const int vt = nh * 6 + i;
        const int c = vt >> 3;
        const int colv = (vt & 7) * 16 + lr;
#pragma unroll
        for (int reg = 0; reg < 4; ++reg) {
            const int row = quad * 4 + reg;
            ovb[c][row][colv] = f2bf(accV[i][reg] * gateL[row][colv]);
        }
    }
    __syncthreads();

    // ---- second layer: K=128 (4 kt); s: 2 N-tiles, v: 6 N-tiles
    floatx4 c2s[2], c2v[6];
#pragma unroll
    for (int i = 0; i < 2; ++i) c2s[i] = (floatx4){0.f, 0.f, 0.f, 0.f};
#pragma unroll
    for (int i = 0; i < 6; ++i) c2v[i] = (floatx4){0.f, 0.f, 0.f, 0.f};

    const unsigned short* arowS = &osb[lr][quad * 8];
#pragma unroll
    for (int kt = 0; kt < 4; ++kt) {
        short8 afS = *(const short8*)(arowS + kt * 32);
        const short8* bpS = (const short8*)W2ss + (size_t)(kt * 8 + nh * 2) * 64 + l;
#pragma unroll
        for (int i = 0; i < 2; ++i)
            c2s[i] = __builtin_amdgcn_mfma_f32_16x16x32_bf16(afS, bpS[i * 64], c2s[i], 0, 0, 0);
#pragma unroll
        for (int i = 0; i < 6; ++i) {
            const int vt = nh * 6 + i;
            const int c = vt >> 3;
            short8 afV = *(const short8*)(&ovb[c][lr][quad * 8] + kt * 32);
            const short8* bpV = (const short8*)W2vs + (size_t)(kt * 8 + (vt & 7)) * 64 + l;
            c2v[i] = __builtin_amdgcn_mfma_f32_16x16x32_bf16(afV, *bpV, c2v[i], 0, 0, 0);
        }
    }

    // ---- epilogue
#pragma unroll
    for (int i = 0; i < 2; ++i) {
        const int col = (nh * 2 + i) * 16 + lr;
#pragma unroll
        for (int reg = 0; reg < 4; ++reg)
            out[(size_t)(n0 + quad * 4 + reg) * 512 + col * 4] = c2s[i][reg];
    }
#pragma unroll
    for (int i = 0; i < 6; ++i) {
        const int vt = nh * 6 + i;
        const int c = vt >> 3;
        const int col = (vt & 7) * 16 + lr;
#pragma unroll
        for (int reg = 0; reg < 4; ++reg)
            out[(size_t)(n0 + quad * 4 + reg) * 512 + col * 4 + 1 + c] = c2v[i][reg];
    }
}

// ---------------------------------------------------------------------------
extern "C" void kernel_launch(void* const* d_in, const int* in_sizes, int n_in,
                              void* d_out, int out_size, void* d_ws, size_t ws_size,
                              hipStream_t stream)
{
    const float* node_attrs = (const float*)d_in[0];
    const float* node_feats = (const float*)d_in[1];
    const float* edge_attrs = (const float*)d_in[2];
    const float* edge_feats = (const float*)d_in[3];
    const int*   edge_index = (const int*)d_in[4];
    const float* W_skip_s = (const float*)d_in[5];
    const float* W_skip_v = (const float*)d_in[6];
    const float* W_up_s   = (const float*)d_in[7];
    const float* W_up_v   = (const float*)d_in[8];
    const float* W_src    = (const float*)d_in[9];
    const float* W_tgt    = (const float*)d_in[10];
    const float* W_r0     = (const float*)d_in[11];
    const float* W_r1     = (const float*)d_in[12];
    const float* W_r2     = (const float*)d_in[13];
    const float* W_r3     = (const float*)d_in[14];
    const float* W_d0     = (const float*)d_in[15];
    const float* W_d1     = (const float*)d_in[16];
    const float* W1_s     = (const float*)d_in[17];
    const float* W1_v     = (const float*)d_in[18];
    const float* Wres_s   = (const float*)d_in[19];
    const float* Wres_v   = (const float*)d_in[20];
    const float* W2_s     = (const float*)d_in[21];
    const float* W2_v     = (const float*)d_in[22];
    const float* alpha_p  = (const float*)d_in[23];
    const float* beta_p   = (const float*)d_in[24];

    float* out = (float*)d_out;
    float* sc_out = out + (size_t)NN * 512;
    float* ws = (float*)d_ws;

    uint2* xq = (uint2*)(ws + WS_XQ);
    unsigned short* us_b  = (unsigned short*)(ws + WS_USB);
    unsigned short* uv_b  = (unsigned short*)(ws + WS_UVB);
    unsigned short* srcEb = (unsigned short*)(ws + WS_SRC);
    unsigned short* tgtEb = (unsigned short*)(ws + WS_TGT);
    unsigned short* msgs_b = (unsigned short*)(ws + WS_MSGSB);
    unsigned short* msgv_b = (unsigned short*)(ws + WS_MSGVB);
    int*   counts = (int*)(ws + WS_COUNTS);
    int*   offs   = (int*)(ws + WS_OFFS);
    int*   cursor = (int*)(ws + WS_CURSOR);
    int*   pos    = (int*)(ws + WS_POS);
    float* metaP  = ws + WS_META;
    unsigned short* tpwP = (unsigned short*)(ws + WS_TPW);
    unsigned short* WBall = (unsigned short*)(ws + WS_WB);
    unsigned short* WB0 = WBall;
    unsigned short* WB1 = WB0 + (size_t)72 * 512;
    unsigned short* WB2 = WB1 + (size_t)8 * 512;
    unsigned short* WB3 = WB2 + (size_t)8 * 512;
    unsigned short* WPall = (unsigned short*)(ws + WS_WP);
    unsigned short* WPs  = WPall;
    unsigned short* WPv  = WPs + (size_t)192 * 512;
    unsigned short* W2ss = WPv + (size_t)96 * 512;
    unsigned short* W2vs = W2ss + (size_t)32 * 512;
    unsigned short* WN   = (unsigned short*)(ws + WS_WN);

    hipMemsetAsync(counts, 0, (size_t)NN * sizeof(int), stream);

    csr_count<<<EE / 256, 256, 0, stream>>>(edge_index, counts);
    csr_scan<<<1, 1024, 0, stream>>>(counts, offs, cursor);
    csr_scatter<<<EE / 256, 256, 0, stream>>>(edge_index, cursor, pos);

    swizzle_all<<<162, 256, 0, stream>>>(
        W_r0, W_d0, W_r1, W_r2, W_r3,
        W1_s, W1_v, Wres_s, Wres_v, W2_s, W2_v,
        W_skip_s, W_up_s, W_skip_v, W_up_v, W_src, W_tgt,
        WBall, WPall, WN);

    node_pre_mfma<<<NN / PNB, 256, 0, stream>>>(
        node_attrs, node_feats, WN, sc_out, xq, us_b, uv_b, srcEb, tgtEb);

    edge_mlp<<<EE / EBK, 256, 0, stream>>>(
        edge_attrs, edge_feats, edge_index, srcEb, tgtEb,
        WB0, WB1, WB2, WB3, W_d1, pos, tpwP, metaP);

    node_gather<<<NN, 128, 0, stream>>>(
        tpwP, metaP, offs, xq, alpha_p, beta_p, msgs_b, msgv_b);

    post_fused<<<NN / DNP, 256, 0, stream>>>(
        msgs_b, us_b, msgv_b, uv_b, WPs, WPv, W2ss, W2vs, out);
}